// Round 6
// baseline (476.726 us; speedup 1.0000x reference)
//
#include <hip/hip_runtime.h>
#include <hip/hip_bf16.h>

typedef unsigned short u16;
typedef __attribute__((ext_vector_type(8))) short bhalf8;   // 8 bf16 = 16 B
typedef __attribute__((ext_vector_type(4))) float f32x4;
typedef __attribute__((address_space(3))) const char* LDSP;

#define DEV __device__ __forceinline__

DEV float bf2f(u16 u) { union { unsigned int i; float f; } c; c.i = ((unsigned int)u) << 16; return c.f; }
DEV u16 f2bf(float f) {
  union { float f; unsigned int i; } c; c.f = f;
  unsigned int x = c.i;
  x += 0x7fffu + ((x >> 16) & 1u);   // RNE
  return (u16)(x >> 16);
}

// async 16B global->LDS (wave-uniform LDS base + lane*16)
DEV void async16(const void* g, void* l) {
  __builtin_amdgcn_global_load_lds((__attribute__((address_space(1))) void*)g,
                                   (__attribute__((address_space(3))) void*)l, 16, 0, 0);
}

// opaque ds_read_b128 (no IR-visible LDS read -> no auto waits on it)
#define LDSRD(dst, base, off) \
  asm volatile("ds_read_b128 %0, %1" : "=v"(dst) : "v"((LDSP)((const char*)(base) + (off))))

// RAW barrier, invisible to SIInsertWaitcnts' barrier handling. The builtin
// barrier gets a forced vmcnt flush when LDS-DMA writes are pending; the raw
// asm barrier avoids that. A/B-proven: R0 vs R5 = -21 us on FF1.
#define BARRIER() asm volatile("s_barrier" ::: "memory")

// packed bf16x2 atomic add (gfx940+/gfx950: global_atomic_pk_add_bf16)
DEV void atom_pk_bf16(void* p, unsigned int v) {
  asm volatile("global_atomic_pk_add_bf16 %0, %1, off" :: "v"(p), "v"(v) : "memory");
}

struct Ptr11 { const void* p[11]; };
struct TC4 { const void* in[4]; u16* out[4]; };

// ---------------------------------------------------------------------------
// dtype detector: bf16 -> low u16 of word is plausible bf16; fp32 -> mantissa.
// ---------------------------------------------------------------------------
__global__ void detect_kernel(const unsigned int* __restrict__ x, int* __restrict__ flag) {
  int t = threadIdx.x;
  int cnt = 0;
  for (int i = t; i < 256; i += 64) {
    unsigned int w = x[i];
    int e = (w >> 7) & 0xFF;
    if (e >= 96 && e <= 134) cnt++;
  }
#pragma unroll
  for (int o = 1; o < 64; o <<= 1) cnt += __shfl_xor(cnt, o, 64);
  if (t == 0) *flag = (cnt >= 192) ? 1 : 0;
}

DEV bhalf8 load8B(const void* base, size_t e, int isbf) {
  if (isbf) return *(const bhalf8*)((const u16*)base + e);
  const float* f = (const float*)base + e;
  float4 a = *(const float4*)f;
  float4 b = *(const float4*)(f + 4);
  bhalf8 r;
  r[0] = (short)f2bf(a.x); r[1] = (short)f2bf(a.y); r[2] = (short)f2bf(a.z); r[3] = (short)f2bf(a.w);
  r[4] = (short)f2bf(b.x); r[5] = (short)f2bf(b.y); r[6] = (short)f2bf(b.z); r[7] = (short)f2bf(b.w);
  return r;
}

__global__ __launch_bounds__(256) void convert_x(const void* __restrict__ x,
                                                 u16* __restrict__ dst,
                                                 const int* __restrict__ flag) {
  int c = blockIdx.x * 256 + threadIdx.x;
  u16* d = dst + (size_t)c * 4;
  if (*flag) {
    *(ushort4*)d = ((const ushort4*)x)[c];
  } else {
    float4 v = ((const float4*)x)[c];
    d[0] = f2bf(v.x); d[1] = f2bf(v.y); d[2] = f2bf(v.z); d[3] = f2bf(v.w);
  }
}

__global__ __launch_bounds__(256) void convert_small(Ptr11 s, float* __restrict__ dst,
                                                     const int* __restrict__ flag) {
  const int isbf = *flag;
  const int SZ[11] = {1024,1024,1024,1024,512,1024,1024,4096,1024,1024,1024};
  for (int i = threadIdx.x; i < 13824; i += 256) {
    int acc = 0, seg = -1, off = 0;
#pragma unroll
    for (int s2 = 0; s2 < 11; ++s2) {
      if (seg < 0 && i < acc + SZ[s2]) { seg = s2; off = i - acc; }
      acc += SZ[s2];
    }
    dst[i] = isbf ? bf2f(((const u16*)s.p[seg])[off]) : ((const float*)s.p[seg])[off];
  }
}

// ---------------------------------------------------------------------------
// bias broadcast init (bf16) for atomic split-K accumulation (N=1024 rows)
// ---------------------------------------------------------------------------
__global__ __launch_bounds__(256) void bias_init(const float* __restrict__ bias,
                                                 u16* __restrict__ out) {
  const int row = blockIdx.x, t = threadIdx.x;
  float4 bv = *(const float4*)(bias + t * 4);
  ushort4 ov; ov.x = f2bf(bv.x); ov.y = f2bf(bv.y); ov.z = f2bf(bv.z); ov.w = f2bf(bv.w);
  *(ushort4*)(out + (size_t)row * 1024 + t * 4) = ov;
}

// ---------------------------------------------------------------------------
// transpose+convert: out[C,R] (bf16) = in[R,C]^T (raw dtype per flag)
// ---------------------------------------------------------------------------
DEV void tconv_tile(const void* in, u16* out, int R, int C, int isbf) {
  __shared__ __align__(16) u16 tile[64][72];
  const int t = threadIdx.x;
  const int c0 = blockIdx.x * 64, r0 = blockIdx.y * 64;
#pragma unroll
  for (int r = 0; r < 2; ++r) {
    int idx = r * 256 + t;
    int ri = idx >> 3, cc = (idx & 7) * 8;
    bhalf8 v = load8B(in, (size_t)(r0 + ri) * C + c0 + cc, isbf);
    *(bhalf8*)(&tile[ri][cc]) = v;
  }
  __syncthreads();
#pragma unroll
  for (int r = 0; r < 2; ++r) {
    int idx = r * 256 + t;
    int co = idx >> 3, rc = (idx & 7) * 8;
    bhalf8 v;
#pragma unroll
    for (int ii = 0; ii < 8; ++ii) v[ii] = (short)tile[rc + ii][co];
    *(bhalf8*)(out + (size_t)(c0 + co) * R + r0 + rc) = v;
  }
}

__global__ __launch_bounds__(256) void tconv_w4(TC4 p, const int* __restrict__ flag) {
  int z = blockIdx.z;
  tconv_tile(p.in[z], p.out[z], 1024, 1024, *flag);
}

__global__ __launch_bounds__(256) void tconv_generic(const void* in, u16* out, int R, int C,
                                                     const int* __restrict__ flag) {
  tconv_tile(in, out, R, C, *flag);
}

__global__ __launch_bounds__(256) void transpose_generic(const u16* in, u16* out, int R, int C) {
  __shared__ __align__(16) u16 tile[64][72];
  const int t = threadIdx.x;
  const int c0 = blockIdx.x * 64, r0 = blockIdx.y * 64;
  size_t bs = (size_t)R * C * blockIdx.z;
#pragma unroll
  for (int r = 0; r < 2; ++r) {
    int idx = r * 256 + t;
    int ri = idx >> 3, cc = (idx & 7) * 8;
    *(bhalf8*)(&tile[ri][cc]) = *(const bhalf8*)(in + bs + (size_t)(r0 + ri) * C + c0 + cc);
  }
  __syncthreads();
#pragma unroll
  for (int r = 0; r < 2; ++r) {
    int idx = r * 256 + t;
    int co = idx >> 3, rc = (idx & 7) * 8;
    bhalf8 v;
#pragma unroll
    for (int ii = 0; ii < 8; ++ii) v[ii] = (short)tile[rc + ii][co];
    *(bhalf8*)(out + bs + (size_t)(c0 + co) * R + r0 + rc) = v;
  }
}

// ---------------------------------------------------------------------------
// 8-phase 256x256 GEMM (B^T input), asm-barrier variant (R0-vs-R5 A/B:
// -21 us vs gemm_bt on FF1). See R5 notes for the manual wait discipline.
// ATOMIC=0: blockIdx.z selects (BT,bias,C) triple; bf16 store epilogue.
// ATOMIC=1: blockIdx.z = split-K index; C pre-filled with bias by bias_init;
//           epilogue packed-bf16 atomics (lane-paired via shfl) — numerics
//           validated R2/R3 (absmax unchanged), cost ~0 (R2: 84.3 vs 84.2).
// ---------------------------------------------------------------------------
#define MFMA_BF16(a, b, c) __builtin_amdgcn_mfma_f32_16x16x32_bf16(a, b, c, 0, 0, 0)

template<int RELU, int ATOMIC>
__global__ __launch_bounds__(512) void gemm256(
    const u16* __restrict__ A, const u16* __restrict__ BT0,
    const float* __restrict__ b0, const float* __restrict__ b1, const float* __restrict__ b2,
    u16* __restrict__ C0, int M, int N, int ldk, int kext, long sBT, long sC)
{
  __shared__ __align__(16) u16 A0h0[8192], A0h1[8192], A1h0[8192], A1h1[8192];
  __shared__ __align__(16) u16 B0h0[8192], B0h1[8192], B1h0[8192], B1h1[8192];
  (void)M;

  const int t = threadIdx.x;
  const int wv = t >> 6, l = t & 63;
  const int wm = wv >> 2, wn = wv & 3;
  const int m0 = blockIdx.y * 256, n0 = blockIdx.x * 256;
  const int z = blockIdx.z;

  const u16* BT; const float* bias; u16* C; int koff;
  if (ATOMIC) {
    BT = BT0; bias = b0; C = C0; koff = z * kext;
  } else {
    BT = BT0 + (long)z * sBT;
    bias = (z == 0) ? b0 : (z == 1 ? b1 : b2);
    C = C0 + (long)z * sC;
    koff = 0;
  }

  const int ri = t >> 3;
  const int slc8 = (((t & 7) ^ (ri & 7)) << 3);
  const u16* agp = A + (size_t)(m0 + ri) * ldk + koff + slc8;
  const int rB = ((ri >> 5) << 6) | (ri & 31);
  const u16* bgp = BT + (size_t)(n0 + rB) * ldk + koff + slc8;

#define STGA(ARR, h, j, kt) async16(agp + (size_t)((j) * 128 + (h) * 64) * ldk + (size_t)(kt) * 64, \
                                    (char*)(ARR) + (j) * 8192 + wv * 1024)
#define STGB(ARR, h, j, kt) async16(bgp + (size_t)((j) * 128 + (h) * 32) * ldk + (size_t)(kt) * 64, \
                                    (char*)(ARR) + (j) * 8192 + wv * 1024)

  int offA[4][2], offB[2][2];
#pragma unroll
  for (int mi = 0; mi < 4; ++mi)
#pragma unroll
    for (int s = 0; s < 2; ++s)
      offA[mi][s] = wm * 8192 + (mi * 16 + (l & 15)) * 128 + ((((s << 2) + (l >> 4)) ^ (l & 7)) << 4);
#pragma unroll
  for (int nj = 0; nj < 2; ++nj)
#pragma unroll
    for (int s = 0; s < 2; ++s)
      offB[nj][s] = wn * 4096 + (nj * 16 + (l & 15)) * 128 + ((((s << 2) + (l >> 4)) ^ (l & 7)) << 4);

  const int NT = kext >> 6;   // even (all call sites: 16)
  f32x4 acc[8][4] = {};

  // prologue: tile0 all 4 half-tiles (buf0) + tile1 first 3 (buf1)
  STGA(A0h0, 0, 0, 0); STGA(A0h0, 0, 1, 0);
  STGB(B0h0, 0, 0, 0); STGB(B0h0, 0, 1, 0);
  STGB(B0h1, 1, 0, 0); STGB(B0h1, 1, 1, 0);
  STGA(A0h1, 1, 0, 0); STGA(A0h1, 1, 1, 0);
  if (NT > 1) {
    STGA(A1h0, 0, 0, 1); STGA(A1h0, 0, 1, 1);
    STGB(B1h0, 0, 0, 1); STGB(B1h0, 0, 1, 1);
    STGB(B1h1, 1, 0, 1); STGB(B1h1, 1, 1, 1);
    asm volatile("s_waitcnt vmcnt(6)" ::: "memory");
  } else {
    asm volatile("s_waitcnt vmcnt(0)" ::: "memory");
  }
  BARRIER();

#define ITER(TT, CA0, CA1, CB0, CB1, NA1)                                        \
  {                                                                              \
    bhalf8 af[4][2], p0[2][2], p1[2][2];                                         \
    /* ph1: read A-h0 + B-h0 ; stage A-h1(TT+1) -> other buf */                  \
    _Pragma("unroll") for (int mi = 0; mi < 4; ++mi)                             \
      _Pragma("unroll") for (int s = 0; s < 2; ++s)                              \
        LDSRD(af[mi][s], CA0, offA[mi][s]);                                      \
    _Pragma("unroll") for (int nj = 0; nj < 2; ++nj)                             \
      _Pragma("unroll") for (int s = 0; s < 2; ++s)                              \
        LDSRD(p0[nj][s], CB0, offB[nj][s]);                                      \
    if ((TT) + 1 < NT) { STGA(NA1, 1, 0, (TT) + 1); STGA(NA1, 1, 1, (TT) + 1); } \
    BARRIER();                                                                   \
    asm volatile("s_waitcnt lgkmcnt(0)" ::: "memory");                           \
    __builtin_amdgcn_sched_barrier(0);                                           \
    __builtin_amdgcn_s_setprio(1);                                               \
    _Pragma("unroll") for (int mi = 0; mi < 4; ++mi)                             \
      _Pragma("unroll") for (int nj = 0; nj < 2; ++nj) {                         \
        acc[mi][nj] = MFMA_BF16(af[mi][0], p0[nj][0], acc[mi][nj]);              \
        acc[mi][nj] = MFMA_BF16(af[mi][1], p0[nj][1], acc[mi][nj]);              \
      }                                                                          \
    __builtin_amdgcn_s_setprio(0);                                               \
    BARRIER();                                                                   \
    /* ph2: read B-h1 ; stage A-h0(TT+2) -> current buf */                       \
    _Pragma("unroll") for (int nj = 0; nj < 2; ++nj)                             \
      _Pragma("unroll") for (int s = 0; s < 2; ++s)                              \
        LDSRD(p1[nj][s], CB1, offB[nj][s]);                                      \
    if ((TT) + 2 < NT) { STGA(CA0, 0, 0, (TT) + 2); STGA(CA0, 0, 1, (TT) + 2); } \
    BARRIER();                                                                   \
    asm volatile("s_waitcnt lgkmcnt(0)" ::: "memory");                           \
    __builtin_amdgcn_sched_barrier(0);                                           \
    __builtin_amdgcn_s_setprio(1);                                               \
    _Pragma("unroll") for (int mi = 0; mi < 4; ++mi)                             \
      _Pragma("unroll") for (int nj = 0; nj < 2; ++nj) {                         \
        acc[mi][2 + nj] = MFMA_BF16(af[mi][0], p1[nj][0], acc[mi][2 + nj]);      \
        acc[mi][2 + nj] = MFMA_BF16(af[mi][1], p1[nj][1], acc[mi][2 + nj]);      \
      }                                                                          \
    __builtin_amdgcn_s_setprio(0);                                               \
    BARRIER();                                                                   \
    /* ph3: read A-h1 ; stage B-h0(TT+2) -> current buf */                       \
    _Pragma("unroll") for (int mi = 0; mi < 4; ++mi)                             \
      _Pragma("unroll") for (int s = 0; s < 2; ++s)                              \
        LDSRD(af[mi][s], CA1, offA[mi][s]);                                      \
    if ((TT) + 2 < NT) { STGB(CB0, 0, 0, (TT) + 2); STGB(CB0, 0, 1, (TT) + 2); } \
    BARRIER();                                                                   \
    asm volatile("s_waitcnt lgkmcnt(0)" ::: "memory");                           \
    __builtin_amdgcn_sched_barrier(0);                                           \
    __builtin_amdgcn_s_setprio(1);                                               \
    _Pragma("unroll") for (int mi = 0; mi < 4; ++mi)                             \
      _Pragma("unroll") for (int nj = 0; nj < 2; ++nj) {                         \
        acc[4 + mi][2 + nj] = MFMA_BF16(af[mi][0], p1[nj][0], acc[4 + mi][2 + nj]); \
        acc[4 + mi][2 + nj] = MFMA_BF16(af[mi][1], p1[nj][1], acc[4 + mi][2 + nj]); \
      }                                                                          \
    __builtin_amdgcn_s_setprio(0);                                               \
    BARRIER();                                                                   \
    /* ph4: stage B-h1(TT+2) ; boundary counted vmcnt */                         \
    if ((TT) + 2 < NT) { STGB(CB1, 1, 0, (TT) + 2); STGB(CB1, 1, 1, (TT) + 2); } \
    BARRIER();                                                                   \
    __builtin_amdgcn_s_setprio(1);                                               \
    _Pragma("unroll") for (int mi = 0; mi < 4; ++mi)                             \
      _Pragma("unroll") for (int nj = 0; nj < 2; ++nj) {                         \
        acc[4 + mi][nj] = MFMA_BF16(af[mi][0], p0[nj][0], acc[4 + mi][nj]);      \
        acc[4 + mi][nj] = MFMA_BF16(af[mi][1], p0[nj][1], acc[4 + mi][nj]);      \
      }                                                                          \
    __builtin_amdgcn_s_setprio(0);                                               \
    if ((TT) < NT - 2)       asm volatile("s_waitcnt vmcnt(6)" ::: "memory");    \
    else if ((TT) == NT - 2) asm volatile("s_waitcnt vmcnt(0)" ::: "memory");    \
    BARRIER();                                                                   \
  }

  for (int tt = 0; tt < NT; tt += 2) {
    ITER(tt,     A0h0, A0h1, B0h0, B0h1, A1h1);
    ITER(tt + 1, A1h0, A1h1, B1h0, B1h1, A0h1);
  }
#undef ITER
#undef STGA
#undef STGB

  const int lr = (l >> 4) << 2, lcc = l & 15;
  if (ATOMIC) {
#pragma unroll
    for (int nj = 0; nj < 4; ++nj) {
      int col = n0 + wn * 64 + nj * 16 + lcc;
#pragma unroll
      for (int mi = 0; mi < 8; ++mi) {
#pragma unroll
        for (int r = 0; r < 4; ++r) {
          int row = m0 + wm * 128 + mi * 16 + lr + r;
          float vo = acc[mi][nj][r];
          float vn = __shfl_xor(vo, 1, 64);
          if (!(l & 1)) {
            unsigned int pk = (unsigned int)f2bf(vo) | ((unsigned int)f2bf(vn) << 16);
            atom_pk_bf16((void*)(C + (size_t)row * N + col), pk);
          }
        }
      }
    }
  } else {
#pragma unroll
    for (int nj = 0; nj < 4; ++nj) {
      int col = n0 + wn * 64 + nj * 16 + lcc;
      float bb = bias[col];
#pragma unroll
      for (int mi = 0; mi < 8; ++mi) {
#pragma unroll
        for (int r = 0; r < 4; ++r) {
          int row = m0 + wm * 128 + mi * 16 + lr + r;
          float v = acc[mi][nj][r] + bb;
          if (RELU) v = fmaxf(v, 0.0f);
          C[(size_t)row * N + col] = f2bf(v);
        }
      }
    }
  }
}

// ---------------------------------------------------------------------------
// GEMM (B^T input), m97-style 128x128: proven workhorse at >=3 blocks/CU.
// ---------------------------------------------------------------------------
template<int RELU>
__global__ __launch_bounds__(512) void gemm_bt(
    const u16* __restrict__ A, const u16* __restrict__ BT0,
    const float* __restrict__ b0, const float* __restrict__ b1, const float* __restrict__ b2,
    u16* __restrict__ C0, int M, int N, int K, long sBT, long sC)
{
  __shared__ __align__(16) u16 ldsA[128 * 32];
  __shared__ __align__(16) u16 ldsB[128 * 32];

  const int t = threadIdx.x;
  const int wv = t >> 6, l = t & 63;
  const int wm = wv >> 2, wn = wv & 3;
  const int m0 = blockIdx.y * 128, n0 = blockIdx.x * 128;
  const int z = blockIdx.z;

  const u16* BT = BT0 + (long)z * sBT;
  const float* bias = (z == 0) ? b0 : (z == 1 ? b1 : b2);
  u16* C = C0 + (long)z * sC;

  const int mm_s = t >> 2, kc_s = (t & 3) ^ ((t >> 4) & 3);
  const u16* agp = A + (size_t)(m0 + mm_s) * K + kc_s * 8;
  const u16* bgp = BT + (size_t)(n0 + mm_s) * K + kc_s * 8;
  char* la = (char*)ldsA + wv * 1024;
  char* lb = (char*)ldsB + wv * 1024;

  int a_off[4], b_off[2];
#pragma unroll
  for (int i = 0; i < 4; ++i) {
    int mm = wm * 64 + i * 16 + (l & 15);
    a_off[i] = (mm * 4 + ((l >> 4) ^ ((mm >> 2) & 3))) * 8;
  }
#pragma unroll
  for (int j = 0; j < 2; ++j) {
    int nn = wn * 32 + j * 16 + (l & 15);
    b_off[j] = (nn * 4 + ((l >> 4) ^ ((nn >> 2) & 3))) * 8;
  }

  f32x4 acc[4][2] = {};

  for (int kt = 0; kt < K; kt += 32) {
    __syncthreads();
    async16(agp + kt, la);
    async16(bgp + kt, lb);
    __syncthreads();

    bhalf8 af[4], bfr[2];
#pragma unroll
    for (int i = 0; i < 4; ++i) af[i] = *(const bhalf8*)(ldsA + a_off[i]);
#pragma unroll
    for (int j = 0; j < 2; ++j) bfr[j] = *(const bhalf8*)(ldsB + b_off[j]);
#pragma unroll
    for (int mi = 0; mi < 4; ++mi)
#pragma unroll
      for (int nj = 0; nj < 2; ++nj)
        acc[mi][nj] = __builtin_amdgcn_mfma_f32_16x16x32_bf16(af[mi], bfr[nj], acc[mi][nj], 0, 0, 0);
  }

  const int lr = (l >> 4) << 2, lc = l & 15;
#pragma unroll
  for (int nj = 0; nj < 2; ++nj) {
    int col = n0 + wn * 32 + nj * 16 + lc;
    float bb = bias[col];
#pragma unroll
    for (int mi = 0; mi < 4; ++mi) {
#pragma unroll
      for (int r = 0; r < 4; ++r) {
        int row = m0 + wm * 64 + mi * 16 + lr + r;
        float v = acc[mi][nj][r] + bb;
        if (RELU) v = fmaxf(v, 0.0f);
        C[(size_t)row * N + col] = f2bf(v);
      }
    }
  }
}

// ---------------------------------------------------------------------------
// split-K gemm_bt: blockIdx.z = K-split index (window z*kext..), ldk = row
// stride of A and BT. C pre-filled with bias (bias_init); epilogue is
// packed-bf16 atomic accumulate. Gets 4 blocks/CU for 1-blk/CU shapes.
// ---------------------------------------------------------------------------
__global__ __launch_bounds__(512) void gemm_bt_splitk(
    const u16* __restrict__ A, const u16* __restrict__ BT,
    u16* __restrict__ C, int M, int N, int ldk, int kext)
{
  __shared__ __align__(16) u16 ldsA[128 * 32];
  __shared__ __align__(16) u16 ldsB[128 * 32];

  const int t = threadIdx.x;
  const int wv = t >> 6, l = t & 63;
  const int wm = wv >> 2, wn = wv & 3;
  const int m0 = blockIdx.y * 128, n0 = blockIdx.x * 128;
  const int koff = blockIdx.z * kext;

  const int mm_s = t >> 2, kc_s = (t & 3) ^ ((t >> 4) & 3);
  const u16* agp = A + (size_t)(m0 + mm_s) * ldk + koff + kc_s * 8;
  const u16* bgp = BT + (size_t)(n0 + mm_s) * ldk + koff + kc_s * 8;
  char* la = (char*)ldsA + wv * 1024;
  char* lb = (char*)ldsB + wv * 1024;

  int a_off[4], b_off[2];
#pragma unroll
  for (int i = 0; i < 4; ++i) {
    int mm = wm * 64 + i * 16 + (l & 15);
    a_off[i] = (mm * 4 + ((l >> 4) ^ ((mm >> 2) & 3))) * 8;
  }
#pragma unroll
  for (int j = 0; j < 2; ++j) {
    int nn = wn * 32 + j * 16 + (l & 15);
    b_off[j] = (nn * 4 + ((l >> 4) ^ ((nn >> 2) & 3))) * 8;
  }

  f32x4 acc[4][2] = {};

  for (int kt = 0; kt < kext; kt += 32) {
    __syncthreads();
    async16(agp + kt, la);
    async16(bgp + kt, lb);
    __syncthreads();

    bhalf8 af[4], bfr[2];
#pragma unroll
    for (int i = 0; i < 4; ++i) af[i] = *(const bhalf8*)(ldsA + a_off[i]);
#pragma unroll
    for (int j = 0; j < 2; ++j) bfr[j] = *(const bhalf8*)(ldsB + b_off[j]);
#pragma unroll
    for (int mi = 0; mi < 4; ++mi)
#pragma unroll
      for (int nj = 0; nj < 2; ++nj)
        acc[mi][nj] = __builtin_amdgcn_mfma_f32_16x16x32_bf16(af[mi], bfr[nj], acc[mi][nj], 0, 0, 0);
  }

  const int lr = (l >> 4) << 2, lc = l & 15;
#pragma unroll
  for (int nj = 0; nj < 2; ++nj) {
    int col = n0 + wn * 32 + nj * 16 + lc;
#pragma unroll
    for (int mi = 0; mi < 4; ++mi) {
#pragma unroll
      for (int r = 0; r < 4; ++r) {
        int row = m0 + wm * 64 + mi * 16 + lr + r;
        float vo = acc[mi][nj][r];
        float vn = __shfl_xor(vo, 1, 64);
        if (!(l & 1)) {
          unsigned int pk = (unsigned int)f2bf(vo) | ((unsigned int)f2bf(vn) << 16);
          atom_pk_bf16((void*)(C + (size_t)row * N + col), pk);
        }
      }
    }
  }
}

// ---------------------------------------------------------------------------
// FALLBACK GEMM (natural raw B): C = A[M,K] @ B[K,N] + bias. (R5-proven.)
// ---------------------------------------------------------------------------
template<int RELU>
__global__ __launch_bounds__(256) void gemm_bn(
    const u16* __restrict__ A, const void* __restrict__ B,
    const float* __restrict__ bias, u16* __restrict__ C, int M, int N, int K,
    const int* __restrict__ flag)
{
  __shared__ __align__(16) u16 ldsA[128][40];
  __shared__ __align__(16) u16 ldsB[128][40];

  const int isbf = *flag;
  const int t = threadIdx.x;
  const int wv = t >> 6, l = t & 63;
  const int wm = wv & 1, wn = wv >> 1;
  const int m0 = blockIdx.y * 128, n0 = blockIdx.x * 128;

  const int srow = t >> 1, scol = (t & 1) * 16;
  const u16* agp = A + (size_t)(m0 + srow) * K + scol;

  const int kk = t >> 3;
  const int nn = (t & 7) * 16;

  f32x4 acc[4][4] = {};

  for (int kt = 0; kt < K; kt += 32) {
    bhalf8 a0 = *(const bhalf8*)(agp + kt);
    bhalf8 a1 = *(const bhalf8*)(agp + kt + 8);
    size_t e0 = (size_t)(kt + kk) * N + n0 + nn;
    bhalf8 b0v = load8B(B, e0, isbf);
    bhalf8 b1v = load8B(B, e0 + 8, isbf);
    __syncthreads();
    *(bhalf8*)(&ldsA[srow][scol])     = a0;
    *(bhalf8*)(&ldsA[srow][scol + 8]) = a1;
#pragma unroll
    for (int j = 0; j < 8; ++j) ldsB[nn + j][kk]     = (u16)b0v[j];
#pragma unroll
    for (int j = 0; j < 8; ++j) ldsB[nn + 8 + j][kk] = (u16)b1v[j];
    __syncthreads();

    bhalf8 af[4], bfr[4];
#pragma unroll
    for (int i = 0; i < 4; ++i)
      af[i] = *(const bhalf8*)(&ldsA[wm * 64 + i * 16 + (l & 15)][(l >> 4) * 8]);
#pragma unroll
    for (int i = 0; i < 4; ++i)
      bfr[i] = *(const bhalf8*)(&ldsB[wn * 64 + i * 16 + (l & 15)][(l >> 4) * 8]);
#pragma unroll
    for (int mi = 0; mi < 4; ++mi)
#pragma unroll
      for (int ni = 0; ni < 4; ++ni)
        acc[mi][ni] = __builtin_amdgcn_mfma_f32_16x16x32_bf16(af[mi], bfr[ni], acc[mi][ni], 0, 0, 0);
  }

  const int lr = (l >> 4) << 2, lc = l & 15;
#pragma unroll
  for (int ni = 0; ni < 4; ++ni) {
    int col = n0 + wn * 64 + ni * 16 + lc;
    float bb = bias[col];
#pragma unroll
    for (int mi = 0; mi < 4; ++mi) {
#pragma unroll
      for (int r = 0; r < 4; ++r) {
        int row = m0 + wm * 64 + mi * 16 + lr + r;
        float v = acc[mi][ni][r] + bb;
        if (RELU) v = fmaxf(v, 0.0f);
        C[(size_t)row * N + col] = f2bf(v);
      }
    }
  }
}

// ---------------------------------------------------------------------------
// T5 bias LUT, pre-scaled for max-free softmax:
// lut = (bias - 12) * log2(e); softmax shift-invariance cancels the -12.
// ---------------------------------------------------------------------------
__global__ __launch_bounds__(256) void lut_kernel(const float* __restrict__ rbc, float* __restrict__ lut) {
  int idx = blockIdx.x * 256 + threadIdx.x;
  if (idx >= 16 * 2047) return;
  int h = idx / 2047;
  int dp = idx - h * 2047;
  int delta = dp - 1023;      // rel_pos = i - j
  int n = -delta;
  int ret = 0;
  if (n < 0) { ret = 16; n = -n; }
  int bkt;
  if (n < 8) bkt = n;
  else {
    float v = logf((float)n * 0.125f) / logf(16.0f) * 8.0f;
    bkt = 8 + (int)v;
    if (bkt > 15) bkt = 15;
  }
  lut[idx] = (rbc[(ret + bkt) * 16 + h] - 12.0f) * 1.44269504f;
}

// ---------------------------------------------------------------------------
// Flash attention, max-free softmax: p = 2^(score*log2e + lut' + pad'),
// per-lane partial row sums, one shuffle reduction at block end.
// ---------------------------------------------------------------------------
__global__ __launch_bounds__(256) void attn_fused(
    const u16* __restrict__ q, const u16* __restrict__ k, const u16* __restrict__ vt,
    const int* __restrict__ mask, const float* __restrict__ lut, u16* __restrict__ att)
{
  __shared__ __align__(16) u16 ldsQ[64][72];
  __shared__ __align__(16) u16 ldsK[64][72];
  __shared__ __align__(16) u16 ldsV[64][72];   // row = head-dim e, col = seq j
  __shared__ __align__(16) u16 ldsP[4][16][72];
  __shared__ float ldsLut[2047];
  __shared__ float ldsPad[64];

  const int t = threadIdx.x;
  const int wv = t >> 6, l = t & 63;
  const int bh = blockIdx.x, qt = blockIdx.y;
  const int b = bh >> 4, h = bh & 15;
  const size_t base = (size_t)bh * 65536;
  const int q0 = qt * 64;

  for (int i = t; i < 2047; i += 256) ldsLut[i] = lut[h * 2047 + i];

  const int sr = t >> 2, sc = (t & 3) * 16;
  {
    bhalf8 q0v = *(const bhalf8*)(q + base + (size_t)(q0 + sr) * 64 + sc);
    bhalf8 q1v = *(const bhalf8*)(q + base + (size_t)(q0 + sr) * 64 + sc + 8);
    *(bhalf8*)(&ldsQ[sr][sc])     = q0v;
    *(bhalf8*)(&ldsQ[sr][sc + 8]) = q1v;
  }
  __syncthreads();

  bhalf8 qf[2];
  {
    int mm = wv * 16 + (l & 15);
#pragma unroll
    for (int s = 0; s < 2; ++s)
      qf[s] = *(const bhalf8*)(&ldsQ[mm][s * 32 + (l >> 4) * 8]);
  }

  float ls_part[4] = {0.0f, 0.0f, 0.0f, 0.0f};
  f32x4 acc_o[4] = {};

  const int* mrow = mask + b * 1024;

  for (int kt = 0; kt < 16; ++kt) {
    const int k0 = kt * 64;
    bhalf8 k0v = *(const bhalf8*)(k + base + (size_t)(k0 + sr) * 64 + sc);
    bhalf8 k1v = *(const bhalf8*)(k + base + (size_t)(k0 + sr) * 64 + sc + 8);
    bhalf8 v0v = *(const bhalf8*)(vt + base + (size_t)sr * 1024 + k0 + sc);
    bhalf8 v1v = *(const bhalf8*)(vt + base + (size_t)sr * 1024 + k0 + sc + 8);
    __syncthreads();
    *(bhalf8*)(&ldsK[sr][sc])     = k0v;
    *(bhalf8*)(&ldsK[sr][sc + 8]) = k1v;
    *(bhalf8*)(&ldsV[sr][sc])     = v0v;
    *(bhalf8*)(&ldsV[sr][sc + 8]) = v1v;
    if (t < 64) {
      int mv = mrow[k0 + t];
      ldsPad[t] = (mv > 0) ? __log2f((float)mv) : -1e30f;
    }
    __syncthreads();

    // S = Q K^T  (16x64 per wave)
    f32x4 accS[4] = {};
#pragma unroll
    for (int s = 0; s < 2; ++s) {
#pragma unroll
      for (int ni = 0; ni < 4; ++ni) {
        int nnj = ni * 16 + (l & 15);
        bhalf8 kf = *(const bhalf8*)(&ldsK[nnj][s * 32 + (l >> 4) * 8]);
        accS[ni] = __builtin_amdgcn_mfma_f32_16x16x32_bf16(qf[s], kf, accS[ni], 0, 0, 0);
      }
    }

    // max-free softmax: p = 2^(s*log2e + lut' + pad')
    float padv[4];
#pragma unroll
    for (int ni = 0; ni < 4; ++ni) padv[ni] = ldsPad[ni * 16 + (l & 15)];
    const int ib = q0 + wv * 16 + ((l >> 4) << 2);
#pragma unroll
    for (int r = 0; r < 4; ++r) {
      int i_l = ((l >> 4) << 2) + r;
#pragma unroll
      for (int ni = 0; ni < 4; ++ni) {
        int j_l = ni * 16 + (l & 15);
        float s = fmaf(accS[ni][r], 1.44269504f, ldsLut[(ib + r) - (k0 + j_l) + 1023]) + padv[ni];
        float p = exp2f(s);
        ls_part[r] += p;
        ldsP[wv][i_l][j_l] = f2bf(p);
      }
    }

    // O += P V (per-wave LDS round-trip: C-layout -> A-layout)
#pragma unroll
    for (int s = 0; s < 2; ++s) {
      int mm = l & 15;
      bhalf8 pf = *(const bhalf8*)(&ldsP[wv][mm][s * 32 + (l >> 4) * 8]);
#pragma unroll
      for (int ni = 0; ni < 4; ++ni) {
        int e = ni * 16 + (l & 15);
        bhalf8 vf = *(const bhalf8*)(&ldsV[e][s * 32 + (l >> 4) * 8]);
        acc_o[ni] = __builtin_amdgcn_mfma_f32_16x16x32_bf16(pf, vf, acc_o[ni], 0, 0, 0);
      }
    }
  }

  // row-sum reduction across the 16 lanes of each quad-row group
#pragma unroll
  for (int r = 0; r < 4; ++r) {
#pragma unroll
    for (int off = 1; off < 16; off <<= 1) ls_part[r] += __shfl_xor(ls_part[r], off, 64);
    ls_part[r] = 1.0f / ls_part[r];
  }

#pragma unroll
  for (int ni = 0; ni < 4; ++ni) {
#pragma unroll
    for (int r = 0; r < 4; ++r) {
      int i = q0 + wv * 16 + ((l >> 4) << 2) + r;
      int e = ni * 16 + (l & 15);
      att[base + (size_t)i * 64 + e] = f2bf(acc_o[ni][r] * ls_part[r]);
    }
  }
}

// ---------------------------------------------------------------------------
// LayerNorm(x + res) * g + b. LAST=1 writes d_out as fp32/bf16 per flag.
// ---------------------------------------------------------------------------
template<int LAST>
__global__ __launch_bounds__(256) void ln_kernel(
    const u16* __restrict__ x, const u16* __restrict__ res,
    const float* __restrict__ g, const float* __restrict__ b,
    void* __restrict__ out, const int* __restrict__ flag)
{
  const int row = blockIdx.x, t = threadIdx.x;
  const size_t off = (size_t)row * 1024 + t * 4;
  ushort4 xv = *(const ushort4*)(x + off);
  ushort4 rv = *(const ushort4*)(res + off);
  float v0 = bf2f(xv.x) + bf2f(rv.x);
  float v1 = bf2f(xv.y) + bf2f(rv.y);
  float v2 = bf2f(xv.z) + bf2f(rv.z);
  float v3 = bf2f(xv.w) + bf2f(rv.w);
  float s = v0 + v1 + v2 + v3;
  float sq = v0 * v0 + v1 * v1 + v2 * v2 + v3 * v3;
#pragma unroll
  for (int o = 1; o < 64; o <<= 1) { s += __shfl_xor(s, o, 64); sq += __shfl_xor(sq, o, 64); }
  __shared__ float red[8];
  const int wv = t >> 6, l = t & 63;
  if (l == 0) { red[wv] = s; red[4 + wv] = sq; }
  __syncthreads();
  s = red[0] + red[1] + red[2] + red[3];
  sq = red[4] + red[5] + red[6] + red[7];
  float mu = s * 0.0009765625f;
  float var = sq * 0.0009765625f - mu * mu;
  float rstd = rsqrtf(var + 1e-5f);
  float4 gv = *(const float4*)(g + t * 4);
  float4 bv = *(const float4*)(b + t * 4);
  float o0 = gv.x * (v0 - mu) * rstd + bv.x;
  float o1 = gv.y * (v1 - mu) * rstd + bv.y;
  float o2 = gv.z * (v2 - mu) * rstd + bv.z;
  float o3 = gv.w * (v3 - mu) * rstd + bv.w;
  if (!LAST) {
    ushort4 ov; ov.x = f2bf(o0); ov.y = f2bf(o1); ov.z = f2bf(o2); ov.w = f2bf(o3);
    *(ushort4*)((u16*)out + off) = ov;
  } else {
    if (*flag) {
      ushort4 ov; ov.x = f2bf(o0); ov.y = f2bf(o1); ov.z = f2bf(o2); ov.w = f2bf(o3);
      *(ushort4*)((u16*)out + off) = ov;
    } else {
      float4 ov; ov.x = o0; ov.y = o1; ov.z = o2; ov.w = o3;
      *(float4*)((float*)out + off) = ov;
    }
  }
}

// ---------------------------------------------------------------------------
extern "C" void kernel_launch(void* const* d_in, const int* in_sizes, int n_in,
                              void* d_out, int out_size, void* d_ws, size_t ws_size,
                              hipStream_t stream) {
  const void* x  = d_in[0];
  const int* mask = (const int*)d_in[1];
  const void* Wq = d_in[2];  const void* bq = d_in[3];
  const void* Wk = d_in[4];  const void* bk = d_in[5];
  const void* Wv = d_in[6];  const void* bv = d_in[7];
  const void* Wo = d_in[8];  const void* bo = d_in[9];
  const void* rb = d_in[10];
  const void* g1 = d_in[11]; const void* be1 = d_in[12];
  const void* W1 = d_in[13]; const void* b1 = d_in[14];
  const void* W2 = d_in[15]; const void* b2 = d_in[16];
  const void* g2 = d_in[17]; const void* be2 = d_in[18];

  char* ws = (char*)d_ws;
  const size_t MB = 1024 * 1024;
  const bool FAST = (ws_size >= 57 * MB);

  const size_t TAIL = FAST ? 56 * MB : 48 * MB;
  float* smalls = (float*)(ws + TAIL);
  float* lut    = (float*)(ws + TAIL + 56 * 1024);
  int*   flag   = (int*)(ws + TAIL + 192 * 1024);

  float* bqc  = smalls + 0;
  float* bkc  = smalls + 1024;
  float* bvc  = smalls + 2048;
  float* boc  = smalls + 3072;
  float* rbc  = smalls + 4096;
  float* g1c  = smalls + 4608;
  float* be1c = smalls + 5632;
  float* b1c  = smalls + 6656;
  float* b2c  = smalls + 10752;
  float* g2c  = smalls + 11776;
  float* be2c = smalls + 12800;

  detect_kernel<<<1, 64, 0, stream>>>((const unsigned int*)x, flag);
  Ptr11 sml;
  sml.p[0] = bq; sml.p[1] = bk; sml.p[2] = bv; sml.p[3] = bo; sml.p[4] = rb;
  sml.p[5] = g1; sml.p[6] = be1; sml.p[7] = b1; sml.p[8] = b2; sml.p[9] = g2; sml.p[10] = be2;
  convert_small<<<1, 256, 0, stream>>>(sml, smalls, flag);
  lut_kernel<<<dim3(128), 256, 0, stream>>>(rbc, lut);

  if (FAST) {
    u16* xc   = (u16*)(ws + 0 * MB);
    u16* WqT  = (u16*)(ws + 8 * MB);
    u16* WkT  = WqT + 1048576;
    u16* WvT  = WqT + 2 * 1048576;
    u16* WoT  = WqT + 3 * 1048576;
    u16* qb   = (u16*)(ws + 16 * MB);
    u16* kb   = (u16*)(ws + 24 * MB);
    u16* vb   = (u16*)(ws + 32 * MB);
    u16* vtb  = (u16*)(ws + 40 * MB);
    u16* attb = (u16*)(ws + 32 * MB);
    u16* xo   = (u16*)(ws + 16 * MB);
    u16* hb   = (u16*)(ws + 48 * MB);
    u16* W1T  = (u16*)(ws + 8 * MB);
    u16* W2T  = (u16*)(ws + 0 * MB);
    u16* ff1  = (u16*)(ws + 16 * MB);
    u16* ff2o = (u16*)(ws + 8 * MB);

    convert_x<<<4096, 256, 0, stream>>>(x, xc, flag);
    TC4 tw; tw.in[0] = Wq; tw.in[1] = Wk; tw.in[2] = Wv; tw.in[3] = Wo;
    tw.out[0] = WqT; tw.out[1] = WkT; tw.out[2] = WvT; tw.out[3] = WoT;
    tconv_w4<<<dim3(16, 16, 4), 256, 0, stream>>>(tw, flag);

    // QKV: 128^2 tiles, 768 blocks = 3/CU (proven)
    gemm_bt<0><<<dim3(8, 32, 3), 512, 0, stream>>>(xc, WqT, bqc, bkc, bvc, qb,
                                                   4096, 1024, 1024, 1048576L, 4194304L);
    transpose_generic<<<dim3(1, 16, 64), 256, 0, stream>>>(vb, vtb, 1024, 64);
    attn_fused<<<dim3(64, 16), 256, 0, stream>>>(qb, kb, vtb, mask, lut, attb);
    // Wo: split-K=4 gemm_bt -> 1024 blocks = 4/CU; pk-atomic into
    // bias-prefilled xo (xo aliases qb: prefill only after attn read qb).
    bias_init<<<dim3(4096), 256, 0, stream>>>(boc, xo);
    gemm_bt_splitk<<<dim3(8, 32, 4), 512, 0, stream>>>(attb, WoT, xo,
                                                       4096, 1024, 1024, 256);
    tconv_generic<<<dim3(64, 16), 256, 0, stream>>>(W1, W1T, 1024, 4096, flag);
    ln_kernel<0><<<dim3(4096), 256, 0, stream>>>(xo, xc, g1c, be1c, hb, flag);
    tconv_generic<<<dim3(16, 64), 256, 0, stream>>>(W2, W2T, 4096, 1024, flag);
    // FF1: 8-phase 256^2 asm-barrier (A/B-proven: -21 us vs gemm_bt)
    gemm256<1, 0><<<dim3(16, 16, 1), 512, 0, stream>>>(hb, W1T, b1c, b1c, b1c, ff1,
                                                       4096, 4096, 1024, 1024, 0L, 0L);
    // FF2: split-K=4 on 8-phase asm-barrier gemm256 (FF1-shaped per split);
    // bias-prefilled ff2o (aliases W1T: prefill only after FF1 read W1T).
    bias_init<<<dim3(4096), 256, 0, stream>>>(b2c, ff2o);
    gemm256<0, 1><<<dim3(4, 16, 4), 512, 0, stream>>>(ff1, W2T, b2c, b2c, b2c, ff2o,
                                                      4096, 1024, 4096, 1024, 0L, 0L);
    ln_kernel<1><<<dim3(4096), 256, 0, stream>>>(ff2o, hb, g2c, be2c, d_out, flag);
  } else {
    u16* xc   = (u16*)(ws + 0 * MB);
    u16* WqT  = (u16*)(ws + 8 * MB);
    u16* WkT  = WqT + 1048576;
    u16* WvT  = WqT + 2 * 1048576;
    u16* WoT  = WqT + 3 * 1048576;
    u16* qb   = (u16*)(ws + 16 * MB);
    u16* kb   = (u16*)(ws + 24 * MB);
    u16* vb   = (u16*)(ws + 32 * MB);
    u16* vtb  = (u16*)(ws + 40 * MB);
    u16* attb = (u16*)(ws + 32 * MB);
    u16* xo   = (u16*)(ws + 16 * MB);
    u16* hb   = (u16*)(ws + 40 * MB);
    u16* ff1  = (u16*)(ws + 0 * MB);
    u16* ff2o = (u16*)(ws + 32 * MB);

    convert_x<<<4096, 256, 0, stream>>>(x, xc, flag);
    TC4 tw; tw.in[0] = Wq; tw.in[1] = Wk; tw.in[2] = Wv; tw.in[3] = Wo;
    tw.out[0] = WqT; tw.out[1] = WkT; tw.out[2] = WvT; tw.out[3] = WoT;
    tconv_w4<<<dim3(16, 16, 4), 256, 0, stream>>>(tw, flag);

    gemm_bt<0><<<dim3(8, 32, 3), 512, 0, stream>>>(xc, WqT, bqc, bkc, bvc, qb,
                                                   4096, 1024, 1024, 1048576L, 4194304L);
    transpose_generic<<<dim3(1, 16, 64), 256, 0, stream>>>(vb, vtb, 1024, 64);
    attn_fused<<<dim3(64, 16), 256, 0, stream>>>(qb, kb, vtb, mask, lut, attb);
    gemm_bt<0><<<dim3(8, 32, 1), 512, 0, stream>>>(attb, WoT, boc, boc, boc, xo,
                                                   4096, 1024, 1024, 0L, 0L);
    ln_kernel<0><<<dim3(4096), 256, 0, stream>>>(xo, xc, g1c, be1c, hb, flag);
    gemm_bn<1><<<dim3(32, 32), 256, 0, stream>>>(hb, W1, b1c, ff1, 4096, 4096, 1024, flag);
    gemm_bn<0><<<dim3(8, 32), 256, 0, stream>>>(ff1, W2, b2c, ff2o, 4096, 1024, 4096, flag);
    ln_kernel<1><<<dim3(4096), 256, 0, stream>>>(ff2o, hb, g2c, be2c, d_out, flag);
  }
}

// Round 7
// 432.229 us; speedup vs baseline: 1.1029x; 1.1029x over previous
//
#include <hip/hip_runtime.h>
#include <hip/hip_bf16.h>

typedef unsigned short u16;
typedef __attribute__((ext_vector_type(8))) short bhalf8;   // 8 bf16 = 16 B
typedef __attribute__((ext_vector_type(4))) float f32x4;
typedef __attribute__((address_space(3))) const char* LDSP;

#define DEV __device__ __forceinline__

DEV float bf2f(u16 u) { union { unsigned int i; float f; } c; c.i = ((unsigned int)u) << 16; return c.f; }
DEV u16 f2bf(float f) {
  union { float f; unsigned int i; } c; c.f = f;
  unsigned int x = c.i;
  x += 0x7fffu + ((x >> 16) & 1u);   // RNE
  return (u16)(x >> 16);
}

// async 16B global->LDS (wave-uniform LDS base + lane*16)
DEV void async16(const void* g, void* l) {
  __builtin_amdgcn_global_load_lds((__attribute__((address_space(1))) void*)g,
                                   (__attribute__((address_space(3))) void*)l, 16, 0, 0);
}

// opaque ds_read_b128 (no IR-visible LDS read -> no auto waits on it)
#define LDSRD(dst, base, off) \
  asm volatile("ds_read_b128 %0, %1" : "=v"(dst) : "v"((LDSP)((const char*)(base) + (off))))

// RAW barrier, invisible to SIInsertWaitcnts' barrier handling. The builtin
// barrier gets a forced vmcnt flush when LDS-DMA writes are pending; the raw
// asm barrier avoids that. A/B-proven: R0 vs R5 = -21 us on FF1.
#define BARRIER() asm volatile("s_barrier" ::: "memory")

// packed bf16x2 atomic add (gfx940+/gfx950). NOTE (R6 post-mortem): the
// atomic split-K strategy measured ~40-60 us of epilogue cost (8.4M atomics,
// 4-way cacheline contention) — kept only for reference, NOT used.
DEV void atom_pk_bf16(void* p, unsigned int v) {
  asm volatile("global_atomic_pk_add_bf16 %0, %1, off" :: "v"(p), "v"(v) : "memory");
}

struct Ptr11 { const void* p[11]; };
struct TC4 { const void* in[4]; u16* out[4]; };

// ---------------------------------------------------------------------------
// dtype detector: bf16 -> low u16 of word is plausible bf16; fp32 -> mantissa.
// ---------------------------------------------------------------------------
__global__ void detect_kernel(const unsigned int* __restrict__ x, int* __restrict__ flag) {
  int t = threadIdx.x;
  int cnt = 0;
  for (int i = t; i < 256; i += 64) {
    unsigned int w = x[i];
    int e = (w >> 7) & 0xFF;
    if (e >= 96 && e <= 134) cnt++;
  }
#pragma unroll
  for (int o = 1; o < 64; o <<= 1) cnt += __shfl_xor(cnt, o, 64);
  if (t == 0) *flag = (cnt >= 192) ? 1 : 0;
}

DEV bhalf8 load8B(const void* base, size_t e, int isbf) {
  if (isbf) return *(const bhalf8*)((const u16*)base + e);
  const float* f = (const float*)base + e;
  float4 a = *(const float4*)f;
  float4 b = *(const float4*)(f + 4);
  bhalf8 r;
  r[0] = (short)f2bf(a.x); r[1] = (short)f2bf(a.y); r[2] = (short)f2bf(a.z); r[3] = (short)f2bf(a.w);
  r[4] = (short)f2bf(b.x); r[5] = (short)f2bf(b.y); r[6] = (short)f2bf(b.z); r[7] = (short)f2bf(b.w);
  return r;
}

__global__ __launch_bounds__(256) void convert_x(const void* __restrict__ x,
                                                 u16* __restrict__ dst,
                                                 const int* __restrict__ flag) {
  int c = blockIdx.x * 256 + threadIdx.x;
  u16* d = dst + (size_t)c * 4;
  if (*flag) {
    *(ushort4*)d = ((const ushort4*)x)[c];
  } else {
    float4 v = ((const float4*)x)[c];
    d[0] = f2bf(v.x); d[1] = f2bf(v.y); d[2] = f2bf(v.z); d[3] = f2bf(v.w);
  }
}

__global__ __launch_bounds__(256) void convert_small(Ptr11 s, float* __restrict__ dst,
                                                     const int* __restrict__ flag) {
  const int isbf = *flag;
  const int SZ[11] = {1024,1024,1024,1024,512,1024,1024,4096,1024,1024,1024};
  for (int i = threadIdx.x; i < 13824; i += 256) {
    int acc = 0, seg = -1, off = 0;
#pragma unroll
    for (int s2 = 0; s2 < 11; ++s2) {
      if (seg < 0 && i < acc + SZ[s2]) { seg = s2; off = i - acc; }
      acc += SZ[s2];
    }
    dst[i] = isbf ? bf2f(((const u16*)s.p[seg])[off]) : ((const float*)s.p[seg])[off];
  }
}

// ---------------------------------------------------------------------------
// transpose+convert: out[C,R] (bf16) = in[R,C]^T (raw dtype per flag)
// ---------------------------------------------------------------------------
DEV void tconv_tile(const void* in, u16* out, int R, int C, int isbf) {
  __shared__ __align__(16) u16 tile[64][72];
  const int t = threadIdx.x;
  const int c0 = blockIdx.x * 64, r0 = blockIdx.y * 64;
#pragma unroll
  for (int r = 0; r < 2; ++r) {
    int idx = r * 256 + t;
    int ri = idx >> 3, cc = (idx & 7) * 8;
    bhalf8 v = load8B(in, (size_t)(r0 + ri) * C + c0 + cc, isbf);
    *(bhalf8*)(&tile[ri][cc]) = v;
  }
  __syncthreads();
#pragma unroll
  for (int r = 0; r < 2; ++r) {
    int idx = r * 256 + t;
    int co = idx >> 3, rc = (idx & 7) * 8;
    bhalf8 v;
#pragma unroll
    for (int ii = 0; ii < 8; ++ii) v[ii] = (short)tile[rc + ii][co];
    *(bhalf8*)(out + (size_t)(c0 + co) * R + r0 + rc) = v;
  }
}

__global__ __launch_bounds__(256) void tconv_w4(TC4 p, const int* __restrict__ flag) {
  int z = blockIdx.z;
  tconv_tile(p.in[z], p.out[z], 1024, 1024, *flag);
}

__global__ __launch_bounds__(256) void tconv_generic(const void* in, u16* out, int R, int C,
                                                     const int* __restrict__ flag) {
  tconv_tile(in, out, R, C, *flag);
}

__global__ __launch_bounds__(256) void transpose_generic(const u16* in, u16* out, int R, int C) {
  __shared__ __align__(16) u16 tile[64][72];
  const int t = threadIdx.x;
  const int c0 = blockIdx.x * 64, r0 = blockIdx.y * 64;
  size_t bs = (size_t)R * C * blockIdx.z;
#pragma unroll
  for (int r = 0; r < 2; ++r) {
    int idx = r * 256 + t;
    int ri = idx >> 3, cc = (idx & 7) * 8;
    *(bhalf8*)(&tile[ri][cc]) = *(const bhalf8*)(in + bs + (size_t)(r0 + ri) * C + c0 + cc);
  }
  __syncthreads();
#pragma unroll
  for (int r = 0; r < 2; ++r) {
    int idx = r * 256 + t;
    int co = idx >> 3, rc = (idx & 7) * 8;
    bhalf8 v;
#pragma unroll
    for (int ii = 0; ii < 8; ++ii) v[ii] = (short)tile[rc + ii][co];
    *(bhalf8*)(out + bs + (size_t)(c0 + co) * R + r0 + rc) = v;
  }
}

// ---------------------------------------------------------------------------
// 8-phase 256x256 GEMM (B^T input), asm-barrier variant (R0-vs-R5 A/B:
// -21 us vs gemm_bt(32,32) on FF1). Manual wait discipline per phase:
// {asm ds_reads ; stage next DMA ; s_barrier ; lgkmcnt(0) ; sched_barrier ;
// setprio(1) ; 16 MFMA ; setprio(0) ; s_barrier}. Counted vmcnt(6) only at
// the K-tile boundary; vmcnt(0) once, entering the last tile.
// blockIdx.z selects the (BT, bias, C) triple (QKV batching).
// ---------------------------------------------------------------------------
#define MFMA_BF16(a, b, c) __builtin_amdgcn_mfma_f32_16x16x32_bf16(a, b, c, 0, 0, 0)

template<int RELU>
__global__ __launch_bounds__(512) void gemm256(
    const u16* __restrict__ A, const u16* __restrict__ BT0,
    const float* __restrict__ b0, const float* __restrict__ b1, const float* __restrict__ b2,
    u16* __restrict__ C0, int M, int N, int ldk, int kext, long sBT, long sC)
{
  __shared__ __align__(16) u16 A0h0[8192], A0h1[8192], A1h0[8192], A1h1[8192];
  __shared__ __align__(16) u16 B0h0[8192], B0h1[8192], B1h0[8192], B1h1[8192];
  (void)M;

  const int t = threadIdx.x;
  const int wv = t >> 6, l = t & 63;
  const int wm = wv >> 2, wn = wv & 3;
  const int m0 = blockIdx.y * 256, n0 = blockIdx.x * 256;
  const int z = blockIdx.z;

  const u16* BT = BT0 + (long)z * sBT;
  const float* bias = (z == 0) ? b0 : (z == 1 ? b1 : b2);
  u16* C = C0 + (long)z * sC;

  const int ri = t >> 3;
  const int slc8 = (((t & 7) ^ (ri & 7)) << 3);
  const u16* agp = A + (size_t)(m0 + ri) * ldk + slc8;
  const int rB = ((ri >> 5) << 6) | (ri & 31);
  const u16* bgp = BT + (size_t)(n0 + rB) * ldk + slc8;

#define STGA(ARR, h, j, kt) async16(agp + (size_t)((j) * 128 + (h) * 64) * ldk + (size_t)(kt) * 64, \
                                    (char*)(ARR) + (j) * 8192 + wv * 1024)
#define STGB(ARR, h, j, kt) async16(bgp + (size_t)((j) * 128 + (h) * 32) * ldk + (size_t)(kt) * 64, \
                                    (char*)(ARR) + (j) * 8192 + wv * 1024)

  int offA[4][2], offB[2][2];
#pragma unroll
  for (int mi = 0; mi < 4; ++mi)
#pragma unroll
    for (int s = 0; s < 2; ++s)
      offA[mi][s] = wm * 8192 + (mi * 16 + (l & 15)) * 128 + ((((s << 2) + (l >> 4)) ^ (l & 7)) << 4);
#pragma unroll
  for (int nj = 0; nj < 2; ++nj)
#pragma unroll
    for (int s = 0; s < 2; ++s)
      offB[nj][s] = wn * 4096 + (nj * 16 + (l & 15)) * 128 + ((((s << 2) + (l >> 4)) ^ (l & 7)) << 4);

  const int NT = kext >> 6;   // even (all call sites: 16)
  f32x4 acc[8][4] = {};

  // prologue: tile0 all 4 half-tiles (buf0) + tile1 first 3 (buf1)
  STGA(A0h0, 0, 0, 0); STGA(A0h0, 0, 1, 0);
  STGB(B0h0, 0, 0, 0); STGB(B0h0, 0, 1, 0);
  STGB(B0h1, 1, 0, 0); STGB(B0h1, 1, 1, 0);
  STGA(A0h1, 1, 0, 0); STGA(A0h1, 1, 1, 0);
  if (NT > 1) {
    STGA(A1h0, 0, 0, 1); STGA(A1h0, 0, 1, 1);
    STGB(B1h0, 0, 0, 1); STGB(B1h0, 0, 1, 1);
    STGB(B1h1, 1, 0, 1); STGB(B1h1, 1, 1, 1);
    asm volatile("s_waitcnt vmcnt(6)" ::: "memory");
  } else {
    asm volatile("s_waitcnt vmcnt(0)" ::: "memory");
  }
  BARRIER();

#define ITER(TT, CA0, CA1, CB0, CB1, NA1)                                        \
  {                                                                              \
    bhalf8 af[4][2], p0[2][2], p1[2][2];                                         \
    /* ph1: read A-h0 + B-h0 ; stage A-h1(TT+1) -> other buf */                  \
    _Pragma("unroll") for (int mi = 0; mi < 4; ++mi)                             \
      _Pragma("unroll") for (int s = 0; s < 2; ++s)                              \
        LDSRD(af[mi][s], CA0, offA[mi][s]);                                      \
    _Pragma("unroll") for (int nj = 0; nj < 2; ++nj)                             \
      _Pragma("unroll") for (int s = 0; s < 2; ++s)                              \
        LDSRD(p0[nj][s], CB0, offB[nj][s]);                                      \
    if ((TT) + 1 < NT) { STGA(NA1, 1, 0, (TT) + 1); STGA(NA1, 1, 1, (TT) + 1); } \
    BARRIER();                                                                   \
    asm volatile("s_waitcnt lgkmcnt(0)" ::: "memory");                           \
    __builtin_amdgcn_sched_barrier(0);                                           \
    __builtin_amdgcn_s_setprio(1);                                               \
    _Pragma("unroll") for (int mi = 0; mi < 4; ++mi)                             \
      _Pragma("unroll") for (int nj = 0; nj < 2; ++nj) {                         \
        acc[mi][nj] = MFMA_BF16(af[mi][0], p0[nj][0], acc[mi][nj]);              \
        acc[mi][nj] = MFMA_BF16(af[mi][1], p0[nj][1], acc[mi][nj]);              \
      }                                                                          \
    __builtin_amdgcn_s_setprio(0);                                               \
    BARRIER();                                                                   \
    /* ph2: read B-h1 ; stage A-h0(TT+2) -> current buf */                       \
    _Pragma("unroll") for (int nj = 0; nj < 2; ++nj)                             \
      _Pragma("unroll") for (int s = 0; s < 2; ++s)                              \
        LDSRD(p1[nj][s], CB1, offB[nj][s]);                                      \
    if ((TT) + 2 < NT) { STGA(CA0, 0, 0, (TT) + 2); STGA(CA0, 0, 1, (TT) + 2); } \
    BARRIER();                                                                   \
    asm volatile("s_waitcnt lgkmcnt(0)" ::: "memory");                           \
    __builtin_amdgcn_sched_barrier(0);                                           \
    __builtin_amdgcn_s_setprio(1);                                               \
    _Pragma("unroll") for (int mi = 0; mi < 4; ++mi)                             \
      _Pragma("unroll") for (int nj = 0; nj < 2; ++nj) {                         \
        acc[mi][2 + nj] = MFMA_BF16(af[mi][0], p1[nj][0], acc[mi][2 + nj]);      \
        acc[mi][2 + nj] = MFMA_BF16(af[mi][1], p1[nj][1], acc[mi][2 + nj]);      \
      }                                                                          \
    __builtin_amdgcn_s_setprio(0);                                               \
    BARRIER();                                                                   \
    /* ph3: read A-h1 ; stage B-h0(TT+2) -> current buf */                       \
    _Pragma("unroll") for (int mi = 0; mi < 4; ++mi)                             \
      _Pragma("unroll") for (int s = 0; s < 2; ++s)                              \
        LDSRD(af[mi][s], CA1, offA[mi][s]);                                      \
    if ((TT) + 2 < NT) { STGB(CB0, 0, 0, (TT) + 2); STGB(CB0, 0, 1, (TT) + 2); } \
    BARRIER();                                                                   \
    asm volatile("s_waitcnt lgkmcnt(0)" ::: "memory");                           \
    __builtin_amdgcn_sched_barrier(0);                                           \
    __builtin_amdgcn_s_setprio(1);                                               \
    _Pragma("unroll") for (int mi = 0; mi < 4; ++mi)                             \
      _Pragma("unroll") for (int nj = 0; nj < 2; ++nj) {                         \
        acc[4 + mi][2 + nj] = MFMA_BF16(af[mi][0], p1[nj][0], acc[4 + mi][2 + nj]); \
        acc[4 + mi][2 + nj] = MFMA_BF16(af[mi][1], p1[nj][1], acc[4 + mi][2 + nj]); \
      }                                                                          \
    __builtin_amdgcn_s_setprio(0);                                               \
    BARRIER();                                                                   \
    /* ph4: stage B-h1(TT+2) ; boundary counted vmcnt */                         \
    if ((TT) + 2 < NT) { STGB(CB1, 1, 0, (TT) + 2); STGB(CB1, 1, 1, (TT) + 2); } \
    BARRIER();                                                                   \
    __builtin_amdgcn_s_setprio(1);                                               \
    _Pragma("unroll") for (int mi = 0; mi < 4; ++mi)                             \
      _Pragma("unroll") for (int nj = 0; nj < 2; ++nj) {                         \
        acc[4 + mi][nj] = MFMA_BF16(af[mi][0], p0[nj][0], acc[4 + mi][nj]);      \
        acc[4 + mi][nj] = MFMA_BF16(af[mi][1], p0[nj][1], acc[4 + mi][nj]);      \
      }                                                                          \
    __builtin_amdgcn_s_setprio(0);                                               \
    if ((TT) < NT - 2)       asm volatile("s_waitcnt vmcnt(6)" ::: "memory");    \
    else if ((TT) == NT - 2) asm volatile("s_waitcnt vmcnt(0)" ::: "memory");    \
    BARRIER();                                                                   \
  }

  for (int tt = 0; tt < NT; tt += 2) {
    ITER(tt,     A0h0, A0h1, B0h0, B0h1, A1h1);
    ITER(tt + 1, A1h0, A1h1, B1h0, B1h1, A0h1);
  }
#undef ITER
#undef STGA
#undef STGB

  const int lr = (l >> 4) << 2, lcc = l & 15;
#pragma unroll
  for (int nj = 0; nj < 4; ++nj) {
    int col = n0 + wn * 64 + nj * 16 + lcc;
    float bb = bias[col];
#pragma unroll
    for (int mi = 0; mi < 8; ++mi) {
#pragma unroll
      for (int r = 0; r < 4; ++r) {
        int row = m0 + wm * 128 + mi * 16 + lr + r;
        float v = acc[mi][nj][r] + bb;
        if (RELU) v = fmaxf(v, 0.0f);
        C[(size_t)row * N + col] = f2bf(v);
      }
    }
  }
}

// ---------------------------------------------------------------------------
// GEMM (B^T input), m97-style 128x128: proven workhorse. Used for Wo
// (1 blk/CU but only 21 us) and FF2 (81.5 us; structurally 1 blk/CU —
// split-K-atomic alternative measured WORSE, see R6 post-mortem).
// ---------------------------------------------------------------------------
template<int RELU>
__global__ __launch_bounds__(512) void gemm_bt(
    const u16* __restrict__ A, const u16* __restrict__ BT0,
    const float* __restrict__ b0, const float* __restrict__ b1, const float* __restrict__ b2,
    u16* __restrict__ C0, int M, int N, int K, long sBT, long sC)
{
  __shared__ __align__(16) u16 ldsA[128 * 32];
  __shared__ __align__(16) u16 ldsB[128 * 32];

  const int t = threadIdx.x;
  const int wv = t >> 6, l = t & 63;
  const int wm = wv >> 2, wn = wv & 3;
  const int m0 = blockIdx.y * 128, n0 = blockIdx.x * 128;
  const int z = blockIdx.z;

  const u16* BT = BT0 + (long)z * sBT;
  const float* bias = (z == 0) ? b0 : (z == 1 ? b1 : b2);
  u16* C = C0 + (long)z * sC;

  const int mm_s = t >> 2, kc_s = (t & 3) ^ ((t >> 4) & 3);
  const u16* agp = A + (size_t)(m0 + mm_s) * K + kc_s * 8;
  const u16* bgp = BT + (size_t)(n0 + mm_s) * K + kc_s * 8;
  char* la = (char*)ldsA + wv * 1024;
  char* lb = (char*)ldsB + wv * 1024;

  int a_off[4], b_off[2];
#pragma unroll
  for (int i = 0; i < 4; ++i) {
    int mm = wm * 64 + i * 16 + (l & 15);
    a_off[i] = (mm * 4 + ((l >> 4) ^ ((mm >> 2) & 3))) * 8;
  }
#pragma unroll
  for (int j = 0; j < 2; ++j) {
    int nn = wn * 32 + j * 16 + (l & 15);
    b_off[j] = (nn * 4 + ((l >> 4) ^ ((nn >> 2) & 3))) * 8;
  }

  f32x4 acc[4][2] = {};

  for (int kt = 0; kt < K; kt += 32) {
    __syncthreads();
    async16(agp + kt, la);
    async16(bgp + kt, lb);
    __syncthreads();

    bhalf8 af[4], bfr[2];
#pragma unroll
    for (int i = 0; i < 4; ++i) af[i] = *(const bhalf8*)(ldsA + a_off[i]);
#pragma unroll
    for (int j = 0; j < 2; ++j) bfr[j] = *(const bhalf8*)(ldsB + b_off[j]);
#pragma unroll
    for (int mi = 0; mi < 4; ++mi)
#pragma unroll
      for (int nj = 0; nj < 2; ++nj)
        acc[mi][nj] = __builtin_amdgcn_mfma_f32_16x16x32_bf16(af[mi], bfr[nj], acc[mi][nj], 0, 0, 0);
  }

  const int lr = (l >> 4) << 2, lc = l & 15;
#pragma unroll
  for (int nj = 0; nj < 2; ++nj) {
    int col = n0 + wn * 32 + nj * 16 + lc;
    float bb = bias[col];
#pragma unroll
    for (int mi = 0; mi < 4; ++mi) {
#pragma unroll
      for (int r = 0; r < 4; ++r) {
        int row = m0 + wm * 64 + mi * 16 + lr + r;
        float v = acc[mi][nj][r] + bb;
        if (RELU) v = fmaxf(v, 0.0f);
        C[(size_t)row * N + col] = f2bf(v);
      }
    }
  }
}

// ---------------------------------------------------------------------------
// FALLBACK GEMM (natural raw B): C = A[M,K] @ B[K,N] + bias. (R5-proven.)
// ---------------------------------------------------------------------------
template<int RELU>
__global__ __launch_bounds__(256) void gemm_bn(
    const u16* __restrict__ A, const void* __restrict__ B,
    const float* __restrict__ bias, u16* __restrict__ C, int M, int N, int K,
    const int* __restrict__ flag)
{
  __shared__ __align__(16) u16 ldsA[128][40];
  __shared__ __align__(16) u16 ldsB[128][40];

  const int isbf = *flag;
  const int t = threadIdx.x;
  const int wv = t >> 6, l = t & 63;
  const int wm = wv & 1, wn = wv >> 1;
  const int m0 = blockIdx.y * 128, n0 = blockIdx.x * 128;

  const int srow = t >> 1, scol = (t & 1) * 16;
  const u16* agp = A + (size_t)(m0 + srow) * K + scol;

  const int kk = t >> 3;
  const int nn = (t & 7) * 16;

  f32x4 acc[4][4] = {};

  for (int kt = 0; kt < K; kt += 32) {
    bhalf8 a0 = *(const bhalf8*)(agp + kt);
    bhalf8 a1 = *(const bhalf8*)(agp + kt + 8);
    size_t e0 = (size_t)(kt + kk) * N + n0 + nn;
    bhalf8 b0v = load8B(B, e0, isbf);
    bhalf8 b1v = load8B(B, e0 + 8, isbf);
    __syncthreads();
    *(bhalf8*)(&ldsA[srow][scol])     = a0;
    *(bhalf8*)(&ldsA[srow][scol + 8]) = a1;
#pragma unroll
    for (int j = 0; j < 8; ++j) ldsB[nn + j][kk]     = (u16)b0v[j];
#pragma unroll
    for (int j = 0; j < 8; ++j) ldsB[nn + 8 + j][kk] = (u16)b1v[j];
    __syncthreads();

    bhalf8 af[4], bfr[4];
#pragma unroll
    for (int i = 0; i < 4; ++i)
      af[i] = *(const bhalf8*)(&ldsA[wm * 64 + i * 16 + (l & 15)][(l >> 4) * 8]);
#pragma unroll
    for (int i = 0; i < 4; ++i)
      bfr[i] = *(const bhalf8*)(&ldsB[wn * 64 + i * 16 + (l & 15)][(l >> 4) * 8]);
#pragma unroll
    for (int mi = 0; mi < 4; ++mi)
#pragma unroll
      for (int ni = 0; ni < 4; ++ni)
        acc[mi][ni] = __builtin_amdgcn_mfma_f32_16x16x32_bf16(af[mi], bfr[ni], acc[mi][ni], 0, 0, 0);
  }

  const int lr = (l >> 4) << 2, lc = l & 15;
#pragma unroll
  for (int ni = 0; ni < 4; ++ni) {
    int col = n0 + wn * 64 + ni * 16 + lc;
    float bb = bias[col];
#pragma unroll
    for (int mi = 0; mi < 4; ++mi) {
#pragma unroll
      for (int r = 0; r < 4; ++r) {
        int row = m0 + wm * 64 + mi * 16 + lr + r;
        float v = acc[mi][ni][r] + bb;
        if (RELU) v = fmaxf(v, 0.0f);
        C[(size_t)row * N + col] = f2bf(v);
      }
    }
  }
}

// ---------------------------------------------------------------------------
// T5 bias LUT, pre-scaled for max-free softmax:
// lut = (bias - 12) * log2(e); softmax shift-invariance cancels the -12.
// ---------------------------------------------------------------------------
__global__ __launch_bounds__(256) void lut_kernel(const float* __restrict__ rbc, float* __restrict__ lut) {
  int idx = blockIdx.x * 256 + threadIdx.x;
  if (idx >= 16 * 2047) return;
  int h = idx / 2047;
  int dp = idx - h * 2047;
  int delta = dp - 1023;      // rel_pos = i - j
  int n = -delta;
  int ret = 0;
  if (n < 0) { ret = 16; n = -n; }
  int bkt;
  if (n < 8) bkt = n;
  else {
    float v = logf((float)n * 0.125f) / logf(16.0f) * 8.0f;
    bkt = 8 + (int)v;
    if (bkt > 15) bkt = 15;
  }
  lut[idx] = (rbc[(ret + bkt) * 16 + h] - 12.0f) * 1.44269504f;
}

// ---------------------------------------------------------------------------
// Flash attention, max-free softmax: p = 2^(score*log2e + lut' + pad'),
// per-lane partial row sums, one shuffle reduction at block end.
// ---------------------------------------------------------------------------
__global__ __launch_bounds__(256) void attn_fused(
    const u16* __restrict__ q, const u16* __restrict__ k, const u16* __restrict__ vt,
    const int* __restrict__ mask, const float* __restrict__ lut, u16* __restrict__ att)
{
  __shared__ __align__(16) u16 ldsQ[64][72];
  __shared__ __align__(16) u16 ldsK[64][72];
  __shared__ __align__(16) u16 ldsV[64][72];   // row = head-dim e, col = seq j
  __shared__ __align__(16) u16 ldsP[4][16][72];
  __shared__ float ldsLut[2047];
  __shared__ float ldsPad[64];

  const int t = threadIdx.x;
  const int wv = t >> 6, l = t & 63;
  const int bh = blockIdx.x, qt = blockIdx.y;
  const int b = bh >> 4, h = bh & 15;
  const size_t base = (size_t)bh * 65536;
  const int q0 = qt * 64;

  for (int i = t; i < 2047; i += 256) ldsLut[i] = lut[h * 2047 + i];

  const int sr = t >> 2, sc = (t & 3) * 16;
  {
    bhalf8 q0v = *(const bhalf8*)(q + base + (size_t)(q0 + sr) * 64 + sc);
    bhalf8 q1v = *(const bhalf8*)(q + base + (size_t)(q0 + sr) * 64 + sc + 8);
    *(bhalf8*)(&ldsQ[sr][sc])     = q0v;
    *(bhalf8*)(&ldsQ[sr][sc + 8]) = q1v;
  }
  __syncthreads();

  bhalf8 qf[2];
  {
    int mm = wv * 16 + (l & 15);
#pragma unroll
    for (int s = 0; s < 2; ++s)
      qf[s] = *(const bhalf8*)(&ldsQ[mm][s * 32 + (l >> 4) * 8]);
  }

  float ls_part[4] = {0.0f, 0.0f, 0.0f, 0.0f};
  f32x4 acc_o[4] = {};

  const int* mrow = mask + b * 1024;

  for (int kt = 0; kt < 16; ++kt) {
    const int k0 = kt * 64;
    bhalf8 k0v = *(const bhalf8*)(k + base + (size_t)(k0 + sr) * 64 + sc);
    bhalf8 k1v = *(const bhalf8*)(k + base + (size_t)(k0 + sr) * 64 + sc + 8);
    bhalf8 v0v = *(const bhalf8*)(vt + base + (size_t)sr * 1024 + k0 + sc);
    bhalf8 v1v = *(const bhalf8*)(vt + base + (size_t)sr * 1024 + k0 + sc + 8);
    __syncthreads();
    *(bhalf8*)(&ldsK[sr][sc])     = k0v;
    *(bhalf8*)(&ldsK[sr][sc + 8]) = k1v;
    *(bhalf8*)(&ldsV[sr][sc])     = v0v;
    *(bhalf8*)(&ldsV[sr][sc + 8]) = v1v;
    if (t < 64) {
      int mv = mrow[k0 + t];
      ldsPad[t] = (mv > 0) ? __log2f((float)mv) : -1e30f;
    }
    __syncthreads();

    // S = Q K^T  (16x64 per wave)
    f32x4 accS[4] = {};
#pragma unroll
    for (int s = 0; s < 2; ++s) {
#pragma unroll
      for (int ni = 0; ni < 4; ++ni) {
        int nnj = ni * 16 + (l & 15);
        bhalf8 kf = *(const bhalf8*)(&ldsK[nnj][s * 32 + (l >> 4) * 8]);
        accS[ni] = __builtin_amdgcn_mfma_f32_16x16x32_bf16(qf[s], kf, accS[ni], 0, 0, 0);
      }
    }

    // max-free softmax: p = 2^(s*log2e + lut' + pad')
    float padv[4];
#pragma unroll
    for (int ni = 0; ni < 4; ++ni) padv[ni] = ldsPad[ni * 16 + (l & 15)];
    const int ib = q0 + wv * 16 + ((l >> 4) << 2);
#pragma unroll
    for (int r = 0; r < 4; ++r) {
      int i_l = ((l >> 4) << 2) + r;
#pragma unroll
      for (int ni = 0; ni < 4; ++ni) {
        int j_l = ni * 16 + (l & 15);
        float s = fmaf(accS[ni][r], 1.44269504f, ldsLut[(ib + r) - (k0 + j_l) + 1023]) + padv[ni];
        float p = exp2f(s);
        ls_part[r] += p;
        ldsP[wv][i_l][j_l] = f2bf(p);
      }
    }

    // O += P V (per-wave LDS round-trip: C-layout -> A-layout)
#pragma unroll
    for (int s = 0; s < 2; ++s) {
      int mm = l & 15;
      bhalf8 pf = *(const bhalf8*)(&ldsP[wv][mm][s * 32 + (l >> 4) * 8]);
#pragma unroll
      for (int ni = 0; ni < 4; ++ni) {
        int e = ni * 16 + (l & 15);
        bhalf8 vf = *(const bhalf8*)(&ldsV[e][s * 32 + (l >> 4) * 8]);
        acc_o[ni] = __builtin_amdgcn_mfma_f32_16x16x32_bf16(pf, vf, acc_o[ni], 0, 0, 0);
      }
    }
  }

  // row-sum reduction across the 16 lanes of each quad-row group
#pragma unroll
  for (int r = 0; r < 4; ++r) {
#pragma unroll
    for (int off = 1; off < 16; off <<= 1) ls_part[r] += __shfl_xor(ls_part[r], off, 64);
    ls_part[r] = 1.0f / ls_part[r];
  }

#pragma unroll
  for (int ni = 0; ni < 4; ++ni) {
#pragma unroll
    for (int r = 0; r < 4; ++r) {
      int i = q0 + wv * 16 + ((l >> 4) << 2) + r;
      int e = ni * 16 + (l & 15);
      att[base + (size_t)i * 64 + e] = f2bf(acc_o[ni][r] * ls_part[r]);
    }
  }
}

// ---------------------------------------------------------------------------
// LayerNorm(x + res) * g + b. LAST=1 writes d_out as fp32/bf16 per flag.
// ---------------------------------------------------------------------------
template<int LAST>
__global__ __launch_bounds__(256) void ln_kernel(
    const u16* __restrict__ x, const u16* __restrict__ res,
    const float* __restrict__ g, const float* __restrict__ b,
    void* __restrict__ out, const int* __restrict__ flag)
{
  const int row = blockIdx.x, t = threadIdx.x;
  const size_t off = (size_t)row * 1024 + t * 4;
  ushort4 xv = *(const ushort4*)(x + off);
  ushort4 rv = *(const ushort4*)(res + off);
  float v0 = bf2f(xv.x) + bf2f(rv.x);
  float v1 = bf2f(xv.y) + bf2f(rv.y);
  float v2 = bf2f(xv.z) + bf2f(rv.z);
  float v3 = bf2f(xv.w) + bf2f(rv.w);
  float s = v0 + v1 + v2 + v3;
  float sq = v0 * v0 + v1 * v1 + v2 * v2 + v3 * v3;
#pragma unroll
  for (int o = 1; o < 64; o <<= 1) { s += __shfl_xor(s, o, 64); sq += __shfl_xor(sq, o, 64); }
  __shared__ float red[8];
  const int wv = t >> 6, l = t & 63;
  if (l == 0) { red[wv] = s; red[4 + wv] = sq; }
  __syncthreads();
  s = red[0] + red[1] + red[2] + red[3];
  sq = red[4] + red[5] + red[6] + red[7];
  float mu = s * 0.0009765625f;
  float var = sq * 0.0009765625f - mu * mu;
  float rstd = rsqrtf(var + 1e-5f);
  float4 gv = *(const float4*)(g + t * 4);
  float4 bv = *(const float4*)(b + t * 4);
  float o0 = gv.x * (v0 - mu) * rstd + bv.x;
  float o1 = gv.y * (v1 - mu) * rstd + bv.y;
  float o2 = gv.z * (v2 - mu) * rstd + bv.z;
  float o3 = gv.w * (v3 - mu) * rstd + bv.w;
  if (!LAST) {
    ushort4 ov; ov.x = f2bf(o0); ov.y = f2bf(o1); ov.z = f2bf(o2); ov.w = f2bf(o3);
    *(ushort4*)((u16*)out + off) = ov;
  } else {
    if (*flag) {
      ushort4 ov; ov.x = f2bf(o0); ov.y = f2bf(o1); ov.z = f2bf(o2); ov.w = f2bf(o3);
      *(ushort4*)((u16*)out + off) = ov;
    } else {
      float4 ov; ov.x = o0; ov.y = o1; ov.z = o2; ov.w = o3;
      *(float4*)((float*)out + off) = ov;
    }
  }
}

// ---------------------------------------------------------------------------
extern "C" void kernel_launch(void* const* d_in, const int* in_sizes, int n_in,
                              void* d_out, int out_size, void* d_ws, size_t ws_size,
                              hipStream_t stream) {
  const void* x  = d_in[0];
  const int* mask = (const int*)d_in[1];
  const void* Wq = d_in[2];  const void* bq = d_in[3];
  const void* Wk = d_in[4];  const void* bk = d_in[5];
  const void* Wv = d_in[6];  const void* bv = d_in[7];
  const void* Wo = d_in[8];  const void* bo = d_in[9];
  const void* rb = d_in[10];
  const void* g1 = d_in[11]; const void* be1 = d_in[12];
  const void* W1 = d_in[13]; const void* b1 = d_in[14];
  const void* W2 = d_in[15]; const void* b2 = d_in[16];
  const void* g2 = d_in[17]; const void* be2 = d_in[18];

  char* ws = (char*)d_ws;
  const size_t MB = 1024 * 1024;
  const bool FAST = (ws_size >= 57 * MB);

  const size_t TAIL = FAST ? 56 * MB : 48 * MB;
  float* smalls = (float*)(ws + TAIL);
  float* lut    = (float*)(ws + TAIL + 56 * 1024);
  int*   flag   = (int*)(ws + TAIL + 192 * 1024);

  float* bqc  = smalls + 0;
  float* bkc  = smalls + 1024;
  float* bvc  = smalls + 2048;
  float* boc  = smalls + 3072;
  float* rbc  = smalls + 4096;
  float* g1c  = smalls + 4608;
  float* be1c = smalls + 5632;
  float* b1c  = smalls + 6656;
  float* b2c  = smalls + 10752;
  float* g2c  = smalls + 11776;
  float* be2c = smalls + 12800;

  detect_kernel<<<1, 64, 0, stream>>>((const unsigned int*)x, flag);
  Ptr11 sml;
  sml.p[0] = bq; sml.p[1] = bk; sml.p[2] = bv; sml.p[3] = bo; sml.p[4] = rb;
  sml.p[5] = g1; sml.p[6] = be1; sml.p[7] = b1; sml.p[8] = b2; sml.p[9] = g2; sml.p[10] = be2;
  convert_small<<<1, 256, 0, stream>>>(sml, smalls, flag);
  lut_kernel<<<dim3(128), 256, 0, stream>>>(rbc, lut);

  if (FAST) {
    u16* xc   = (u16*)(ws + 0 * MB);
    u16* WqT  = (u16*)(ws + 8 * MB);
    u16* WkT  = WqT + 1048576;
    u16* WvT  = WqT + 2 * 1048576;
    u16* WoT  = WqT + 3 * 1048576;
    u16* qb   = (u16*)(ws + 16 * MB);
    u16* kb   = (u16*)(ws + 24 * MB);
    u16* vb   = (u16*)(ws + 32 * MB);
    u16* vtb  = (u16*)(ws + 40 * MB);
    u16* attb = (u16*)(ws + 32 * MB);
    u16* xo   = (u16*)(ws + 16 * MB);
    u16* hb   = (u16*)(ws + 48 * MB);
    u16* W1T  = (u16*)(ws + 8 * MB);
    u16* W2T  = (u16*)(ws + 0 * MB);
    u16* ff1  = (u16*)(ws + 16 * MB);
    u16* ff2o = (u16*)(ws + 8 * MB);

    convert_x<<<4096, 256, 0, stream>>>(x, xc, flag);
    TC4 tw; tw.in[0] = Wq; tw.in[1] = Wk; tw.in[2] = Wv; tw.in[3] = Wo;
    tw.out[0] = WqT; tw.out[1] = WkT; tw.out[2] = WvT; tw.out[3] = WoT;
    tconv_w4<<<dim3(16, 16, 4), 256, 0, stream>>>(tw, flag);

    // QKV: 8-phase 256^2 asm-barrier, grid 4x16x3 = 192 blocks
    // (z-batching validated R1; asm-barrier kernel validated R5/R6)
    gemm256<0><<<dim3(4, 16, 3), 512, 0, stream>>>(xc, WqT, bqc, bkc, bvc, qb,
                                                   4096, 1024, 1024, 1024, 1048576L, 4194304L);
    transpose_generic<<<dim3(1, 16, 64), 256, 0, stream>>>(vb, vtb, 1024, 64);
    attn_fused<<<dim3(64, 16), 256, 0, stream>>>(qb, kb, vtb, mask, lut, attb);
    // Wo: plain gemm_bt (21 us; split-K atomic measured ~65 us — R6)
    gemm_bt<0><<<dim3(8, 32, 1), 512, 0, stream>>>(attb, WoT, boc, boc, boc, xo,
                                                   4096, 1024, 1024, 0L, 0L);
    tconv_generic<<<dim3(64, 16), 256, 0, stream>>>(W1, W1T, 1024, 4096, flag);
    ln_kernel<0><<<dim3(4096), 256, 0, stream>>>(xo, xc, g1c, be1c, hb, flag);
    tconv_generic<<<dim3(16, 64), 256, 0, stream>>>(W2, W2T, 4096, 1024, flag);
    // FF1: 8-phase 256^2 asm-barrier (A/B-proven: -21 us vs gemm_bt 32x32)
    gemm256<1><<<dim3(16, 16, 1), 512, 0, stream>>>(hb, W1T, b1c, b1c, b1c, ff1,
                                                    4096, 4096, 1024, 1024, 0L, 0L);
    // FF2: plain gemm_bt (81.5 us; atomic split-K measured >= 83 us — R2/R6)
    gemm_bt<0><<<dim3(8, 32, 1), 512, 0, stream>>>(ff1, W2T, b2c, b2c, b2c, ff2o,
                                                   4096, 1024, 4096, 0L, 0L);
    ln_kernel<1><<<dim3(4096), 256, 0, stream>>>(ff2o, hb, g2c, be2c, d_out, flag);
  } else {
    u16* xc   = (u16*)(ws + 0 * MB);
    u16* WqT  = (u16*)(ws + 8 * MB);
    u16* WkT  = WqT + 1048576;
    u16* WvT  = WqT + 2 * 1048576;
    u16* WoT  = WqT + 3 * 1048576;
    u16* qb   = (u16*)(ws + 16 * MB);
    u16* kb   = (u16*)(ws + 24 * MB);
    u16* vb   = (u16*)(ws + 32 * MB);
    u16* vtb  = (u16*)(ws + 40 * MB);
    u16* attb = (u16*)(ws + 32 * MB);
    u16* xo   = (u16*)(ws + 16 * MB);
    u16* hb   = (u16*)(ws + 40 * MB);
    u16* ff1  = (u16*)(ws + 0 * MB);
    u16* ff2o = (u16*)(ws + 32 * MB);

    convert_x<<<4096, 256, 0, stream>>>(x, xc, flag);
    TC4 tw; tw.in[0] = Wq; tw.in[1] = Wk; tw.in[2] = Wv; tw.in[3] = Wo;
    tw.out[0] = WqT; tw.out[1] = WkT; tw.out[2] = WvT; tw.out[3] = WoT;
    tconv_w4<<<dim3(16, 16, 4), 256, 0, stream>>>(tw, flag);

    gemm_bt<0><<<dim3(8, 32, 3), 512, 0, stream>>>(xc, WqT, bqc, bkc, bvc, qb,
                                                   4096, 1024, 1024, 1048576L, 4194304L);
    transpose_generic<<<dim3(1, 16, 64), 256, 0, stream>>>(vb, vtb, 1024, 64);
    attn_fused<<<dim3(64, 16), 256, 0, stream>>>(qb, kb, vtb, mask, lut, attb);
    gemm_bt<0><<<dim3(8, 32, 1), 512, 0, stream>>>(attb, WoT, boc, boc, boc, xo,
                                                   4096, 1024, 1024, 0L, 0L);
    ln_kernel<0><<<dim3(4096), 256, 0, stream>>>(xo, xc, g1c, be1c, hb, flag);
    gemm_bn<1><<<dim3(32, 32), 256, 0, stream>>>(hb, W1, b1c, ff1, 4096, 4096, 1024, flag);
    gemm_bn<0><<<dim3(8, 32), 256, 0, stream>>>(ff1, W2, b2c, ff2o, 4096, 1024, 4096, flag);
    ln_kernel<1><<<dim3(4096), 256, 0, stream>>>(ff2o, hb, g2c, be2c, d_out, flag);
  }
}

// Round 8
// 430.093 us; speedup vs baseline: 1.1084x; 1.0050x over previous
//
#include <hip/hip_runtime.h>
#include <hip/hip_bf16.h>

typedef unsigned short u16;
typedef __attribute__((ext_vector_type(8))) short bhalf8;   // 8 bf16 = 16 B
typedef __attribute__((ext_vector_type(4))) float f32x4;
typedef __attribute__((address_space(3))) const char* LDSP;

#define DEV __device__ __forceinline__

DEV float bf2f(u16 u) { union { unsigned int i; float f; } c; c.i = ((unsigned int)u) << 16; return c.f; }
DEV u16 f2bf(float f) {
  union { float f; unsigned int i; } c; c.f = f;
  unsigned int x = c.i;
  x += 0x7fffu + ((x >> 16) & 1u);   // RNE
  return (u16)(x >> 16);
}

// async 16B global->LDS (wave-uniform LDS base + lane*16)
DEV void async16(const void* g, void* l) {
  __builtin_amdgcn_global_load_lds((__attribute__((address_space(1))) void*)g,
                                   (__attribute__((address_space(3))) void*)l, 16, 0, 0);
}

// opaque ds_read_b128 (no IR-visible LDS read -> no auto waits on it)
#define LDSRD(dst, base, off) \
  asm volatile("ds_read_b128 %0, %1" : "=v"(dst) : "v"((LDSP)((const char*)(base) + (off))))

// RAW barrier, invisible to SIInsertWaitcnts' barrier handling. The builtin
// barrier gets a forced vmcnt flush when LDS-DMA writes are pending; the raw
// asm barrier avoids that. A/B-proven: gemm256 builtin 85us -> asm 62us.
#define BARRIER() asm volatile("s_barrier" ::: "memory")

// packed bf16x2 atomic add — R6 post-mortem: atomic split-K costs 40-60us of
// epilogue (contended). Kept for reference, NOT used.
DEV void atom_pk_bf16(void* p, unsigned int v) {
  asm volatile("global_atomic_pk_add_bf16 %0, %1, off" :: "v"(p), "v"(v) : "memory");
}

struct Ptr11 { const void* p[11]; };
struct TC4 { const void* in[4]; u16* out[4]; };

// ---------------------------------------------------------------------------
// dtype detector: bf16 -> low u16 of word is plausible bf16; fp32 -> mantissa.
// ---------------------------------------------------------------------------
__global__ void detect_kernel(const unsigned int* __restrict__ x, int* __restrict__ flag) {
  int t = threadIdx.x;
  int cnt = 0;
  for (int i = t; i < 256; i += 64) {
    unsigned int w = x[i];
    int e = (w >> 7) & 0xFF;
    if (e >= 96 && e <= 134) cnt++;
  }
#pragma unroll
  for (int o = 1; o < 64; o <<= 1) cnt += __shfl_xor(cnt, o, 64);
  if (t == 0) *flag = (cnt >= 192) ? 1 : 0;
}

DEV bhalf8 load8B(const void* base, size_t e, int isbf) {
  if (isbf) return *(const bhalf8*)((const u16*)base + e);
  const float* f = (const float*)base + e;
  float4 a = *(const float4*)f;
  float4 b = *(const float4*)(f + 4);
  bhalf8 r;
  r[0] = (short)f2bf(a.x); r[1] = (short)f2bf(a.y); r[2] = (short)f2bf(a.z); r[3] = (short)f2bf(a.w);
  r[4] = (short)f2bf(b.x); r[5] = (short)f2bf(b.y); r[6] = (short)f2bf(b.z); r[7] = (short)f2bf(b.w);
  return r;
}

__global__ __launch_bounds__(256) void convert_x(const void* __restrict__ x,
                                                 u16* __restrict__ dst,
                                                 const int* __restrict__ flag) {
  int c = blockIdx.x * 256 + threadIdx.x;
  u16* d = dst + (size_t)c * 4;
  if (*flag) {
    *(ushort4*)d = ((const ushort4*)x)[c];
  } else {
    float4 v = ((const float4*)x)[c];
    d[0] = f2bf(v.x); d[1] = f2bf(v.y); d[2] = f2bf(v.z); d[3] = f2bf(v.w);
  }
}

__global__ __launch_bounds__(256) void convert_small(Ptr11 s, float* __restrict__ dst,
                                                     const int* __restrict__ flag) {
  const int isbf = *flag;
  const int SZ[11] = {1024,1024,1024,1024,512,1024,1024,4096,1024,1024,1024};
  for (int i = threadIdx.x; i < 13824; i += 256) {
    int acc = 0, seg = -1, off = 0;
#pragma unroll
    for (int s2 = 0; s2 < 11; ++s2) {
      if (seg < 0 && i < acc + SZ[s2]) { seg = s2; off = i - acc; }
      acc += SZ[s2];
    }
    dst[i] = isbf ? bf2f(((const u16*)s.p[seg])[off]) : ((const float*)s.p[seg])[off];
  }
}

// ---------------------------------------------------------------------------
// transpose+convert: out[C,R] (bf16) = in[R,C]^T (raw dtype per flag)
// ---------------------------------------------------------------------------
DEV void tconv_tile(const void* in, u16* out, int R, int C, int isbf) {
  __shared__ __align__(16) u16 tile[64][72];
  const int t = threadIdx.x;
  const int c0 = blockIdx.x * 64, r0 = blockIdx.y * 64;
#pragma unroll
  for (int r = 0; r < 2; ++r) {
    int idx = r * 256 + t;
    int ri = idx >> 3, cc = (idx & 7) * 8;
    bhalf8 v = load8B(in, (size_t)(r0 + ri) * C + c0 + cc, isbf);
    *(bhalf8*)(&tile[ri][cc]) = v;
  }
  __syncthreads();
#pragma unroll
  for (int r = 0; r < 2; ++r) {
    int idx = r * 256 + t;
    int co = idx >> 3, rc = (idx & 7) * 8;
    bhalf8 v;
#pragma unroll
    for (int ii = 0; ii < 8; ++ii) v[ii] = (short)tile[rc + ii][co];
    *(bhalf8*)(out + (size_t)(c0 + co) * R + r0 + rc) = v;
  }
}

__global__ __launch_bounds__(256) void tconv_w4(TC4 p, const int* __restrict__ flag) {
  int z = blockIdx.z;
  tconv_tile(p.in[z], p.out[z], 1024, 1024, *flag);
}

__global__ __launch_bounds__(256) void tconv_generic(const void* in, u16* out, int R, int C,
                                                     const int* __restrict__ flag) {
  tconv_tile(in, out, R, C, *flag);
}

__global__ __launch_bounds__(256) void transpose_generic(const u16* in, u16* out, int R, int C) {
  __shared__ __align__(16) u16 tile[64][72];
  const int t = threadIdx.x;
  const int c0 = blockIdx.x * 64, r0 = blockIdx.y * 64;
  size_t bs = (size_t)R * C * blockIdx.z;
#pragma unroll
  for (int r = 0; r < 2; ++r) {
    int idx = r * 256 + t;
    int ri = idx >> 3, cc = (idx & 7) * 8;
    *(bhalf8*)(&tile[ri][cc]) = *(const bhalf8*)(in + bs + (size_t)(r0 + ri) * C + c0 + cc);
  }
  __syncthreads();
#pragma unroll
  for (int r = 0; r < 2; ++r) {
    int idx = r * 256 + t;
    int co = idx >> 3, rc = (idx & 7) * 8;
    bhalf8 v;
#pragma unroll
    for (int ii = 0; ii < 8; ++ii) v[ii] = (short)tile[rc + ii][co];
    *(bhalf8*)(out + bs + (size_t)(c0 + co) * R + r0 + rc) = v;
  }
}

// ---------------------------------------------------------------------------
// 8-phase 256x256 GEMM (B^T input), asm-barrier, 4-barriers-per-K-tile (R8).
// R8 changes vs R7: (1) STAGE moved AFTER each phase's barrier+lgkm — every
// DMA into buffer X now transitively follows all waves' lgkm-drain of X's
// readers via a barrier (race-free by construction, not timing margin):
//   NA1: ph1-BAR => prior-tile ph3-lgkm passed by all waves
//   CA0: ph2-BAR => ph1-lgkm ;  CB0: ph3-BAR => ph1-lgkm
//   CB1: ph4 stage follows ph3-BAR => ph2-lgkm
// This lets the trailing barrier of each phase be DELETED (8 -> 4 barriers
// per K-tile; R7 measured ~350 cyc of skew per barrier-pair).
// (2) bijective XCD swizzle on the xy-plane (nwg%8==0 at all call sites).
// Counted vmcnt unchanged: 8 DMAs issued/tile, vmcnt(6) at boundary leaves
// exactly tile TT+2's 3 half-tiles in flight; vmcnt(0) once at TT==NT-2.
// blockIdx.z selects the (BT, bias, C) triple (QKV batching).
// ---------------------------------------------------------------------------
#define MFMA_BF16(a, b, c) __builtin_amdgcn_mfma_f32_16x16x32_bf16(a, b, c, 0, 0, 0)
#define SB0() __builtin_amdgcn_sched_barrier(0)

template<int RELU>
__global__ __launch_bounds__(512) void gemm256(
    const u16* __restrict__ A, const u16* __restrict__ BT0,
    const float* __restrict__ b0, const float* __restrict__ b1, const float* __restrict__ b2,
    u16* __restrict__ C0, int M, int N, int ldk, int kext, long sBT, long sC)
{
  __shared__ __align__(16) u16 A0h0[8192], A0h1[8192], A1h0[8192], A1h1[8192];
  __shared__ __align__(16) u16 B0h0[8192], B0h1[8192], B1h0[8192], B1h1[8192];
  (void)M;

  const int t = threadIdx.x;
  const int wv = t >> 6, l = t & 63;
  const int wm = wv >> 2, wn = wv & 3;
  const int z = blockIdx.z;

  // XCD-aware bijective swizzle within the xy-plane (T1). nwg%8==0 at all
  // call sites (64 or 256) -> simple chunked remap is bijective.
  const int gx = gridDim.x;
  const int nwg = gx * gridDim.y;
  int wgid = blockIdx.y * gx + blockIdx.x;
  wgid = (wgid & 7) * (nwg >> 3) + (wgid >> 3);
  const int m0 = (wgid / gx) * 256, n0 = (wgid % gx) * 256;

  const u16* BT = BT0 + (long)z * sBT;
  const float* bias = (z == 0) ? b0 : (z == 1 ? b1 : b2);
  u16* C = C0 + (long)z * sC;

  const int ri = t >> 3;
  const int slc8 = (((t & 7) ^ (ri & 7)) << 3);
  const u16* agp = A + (size_t)(m0 + ri) * ldk + slc8;
  const int rB = ((ri >> 5) << 6) | (ri & 31);
  const u16* bgp = BT + (size_t)(n0 + rB) * ldk + slc8;

#define STGA(ARR, h, j, kt) async16(agp + (size_t)((j) * 128 + (h) * 64) * ldk + (size_t)(kt) * 64, \
                                    (char*)(ARR) + (j) * 8192 + wv * 1024)
#define STGB(ARR, h, j, kt) async16(bgp + (size_t)((j) * 128 + (h) * 32) * ldk + (size_t)(kt) * 64, \
                                    (char*)(ARR) + (j) * 8192 + wv * 1024)

  int offA[4][2], offB[2][2];
#pragma unroll
  for (int mi = 0; mi < 4; ++mi)
#pragma unroll
    for (int s = 0; s < 2; ++s)
      offA[mi][s] = wm * 8192 + (mi * 16 + (l & 15)) * 128 + ((((s << 2) + (l >> 4)) ^ (l & 7)) << 4);
#pragma unroll
  for (int nj = 0; nj < 2; ++nj)
#pragma unroll
    for (int s = 0; s < 2; ++s)
      offB[nj][s] = wn * 4096 + (nj * 16 + (l & 15)) * 128 + ((((s << 2) + (l >> 4)) ^ (l & 7)) << 4);

  const int NT = kext >> 6;   // even (all call sites: 16)
  f32x4 acc[8][4] = {};

  // prologue: tile0 all 4 half-tiles (buf0) + tile1 first 3 (buf1)
  STGA(A0h0, 0, 0, 0); STGA(A0h0, 0, 1, 0);
  STGB(B0h0, 0, 0, 0); STGB(B0h0, 0, 1, 0);
  STGB(B0h1, 1, 0, 0); STGB(B0h1, 1, 1, 0);
  STGA(A0h1, 1, 0, 0); STGA(A0h1, 1, 1, 0);
  if (NT > 1) {
    STGA(A1h0, 0, 0, 1); STGA(A1h0, 0, 1, 1);
    STGB(B1h0, 0, 0, 1); STGB(B1h0, 0, 1, 1);
    STGB(B1h1, 1, 0, 1); STGB(B1h1, 1, 1, 1);
    asm volatile("s_waitcnt vmcnt(6)" ::: "memory");
  } else {
    asm volatile("s_waitcnt vmcnt(0)" ::: "memory");
  }
  BARRIER();

#define ITER(TT, CA0, CA1, CB0, CB1, NA1)                                        \
  {                                                                              \
    bhalf8 af[4][2], p0[2][2], p1[2][2];                                         \
    /* ph1: rd A-h0+B-h0 ; BAR ; lgkm ; stage O.A-h1(TT+1) ; MFMA q(0,0..1) */   \
    _Pragma("unroll") for (int mi = 0; mi < 4; ++mi)                             \
      _Pragma("unroll") for (int s = 0; s < 2; ++s)                              \
        LDSRD(af[mi][s], CA0, offA[mi][s]);                                      \
    _Pragma("unroll") for (int nj = 0; nj < 2; ++nj)                             \
      _Pragma("unroll") for (int s = 0; s < 2; ++s)                              \
        LDSRD(p0[nj][s], CB0, offB[nj][s]);                                      \
    BARRIER();                                                                   \
    asm volatile("s_waitcnt lgkmcnt(0)" ::: "memory");                           \
    SB0();                                                                       \
    if ((TT) + 1 < NT) { STGA(NA1, 1, 0, (TT) + 1); STGA(NA1, 1, 1, (TT) + 1); } \
    SB0();                                                                       \
    __builtin_amdgcn_s_setprio(1);                                               \
    _Pragma("unroll") for (int mi = 0; mi < 4; ++mi)                             \
      _Pragma("unroll") for (int nj = 0; nj < 2; ++nj) {                         \
        acc[mi][nj] = MFMA_BF16(af[mi][0], p0[nj][0], acc[mi][nj]);              \
        acc[mi][nj] = MFMA_BF16(af[mi][1], p0[nj][1], acc[mi][nj]);              \
      }                                                                          \
    __builtin_amdgcn_s_setprio(0);                                               \
    /* ph2: rd B-h1 ; BAR ; lgkm ; stage C.A-h0(TT+2) ; MFMA q(0,2..3) */        \
    _Pragma("unroll") for (int nj = 0; nj < 2; ++nj)                             \
      _Pragma("unroll") for (int s = 0; s < 2; ++s)                              \
        LDSRD(p1[nj][s], CB1, offB[nj][s]);                                      \
    BARRIER();                                                                   \
    asm volatile("s_waitcnt lgkmcnt(0)" ::: "memory");                           \
    SB0();                                                                       \
    if ((TT) + 2 < NT) { STGA(CA0, 0, 0, (TT) + 2); STGA(CA0, 0, 1, (TT) + 2); } \
    SB0();                                                                       \
    __builtin_amdgcn_s_setprio(1);                                               \
    _Pragma("unroll") for (int mi = 0; mi < 4; ++mi)                             \
      _Pragma("unroll") for (int nj = 0; nj < 2; ++nj) {                         \
        acc[mi][2 + nj] = MFMA_BF16(af[mi][0], p1[nj][0], acc[mi][2 + nj]);      \
        acc[mi][2 + nj] = MFMA_BF16(af[mi][1], p1[nj][1], acc[mi][2 + nj]);      \
      }                                                                          \
    __builtin_amdgcn_s_setprio(0);                                               \
    /* ph3: rd A-h1 ; BAR ; lgkm ; stage C.B-h0(TT+2) ; MFMA q(1,2..3) */        \
    _Pragma("unroll") for (int mi = 0; mi < 4; ++mi)                             \
      _Pragma("unroll") for (int s = 0; s < 2; ++s)                              \
        LDSRD(af[mi][s], CA1, offA[mi][s]);                                      \
    BARRIER();                                                                   \
    asm volatile("s_waitcnt lgkmcnt(0)" ::: "memory");                           \
    SB0();                                                                       \
    if ((TT) + 2 < NT) { STGB(CB0, 0, 0, (TT) + 2); STGB(CB0, 0, 1, (TT) + 2); } \
    SB0();                                                                       \
    __builtin_amdgcn_s_setprio(1);                                               \
    _Pragma("unroll") for (int mi = 0; mi < 4; ++mi)                             \
      _Pragma("unroll") for (int nj = 0; nj < 2; ++nj) {                         \
        acc[4 + mi][2 + nj] = MFMA_BF16(af[mi][0], p1[nj][0], acc[4 + mi][2 + nj]); \
        acc[4 + mi][2 + nj] = MFMA_BF16(af[mi][1], p1[nj][1], acc[4 + mi][2 + nj]); \
      }                                                                          \
    __builtin_amdgcn_s_setprio(0);                                               \
    /* ph4 (no barrier): stage C.B-h1(TT+2) ; MFMA q(1,0..1) ; boundary */       \
    if ((TT) + 2 < NT) { STGB(CB1, 1, 0, (TT) + 2); STGB(CB1, 1, 1, (TT) + 2); } \
    SB0();                                                                       \
    __builtin_amdgcn_s_setprio(1);                                               \
    _Pragma("unroll") for (int mi = 0; mi < 4; ++mi)                             \
      _Pragma("unroll") for (int nj = 0; nj < 2; ++nj) {                         \
        acc[4 + mi][nj] = MFMA_BF16(af[mi][0], p0[nj][0], acc[4 + mi][nj]);      \
        acc[4 + mi][nj] = MFMA_BF16(af[mi][1], p0[nj][1], acc[4 + mi][nj]);      \
      }                                                                          \
    __builtin_amdgcn_s_setprio(0);                                               \
    SB0();                                                                       \
    if ((TT) < NT - 2)       asm volatile("s_waitcnt vmcnt(6)" ::: "memory");    \
    else if ((TT) == NT - 2) asm volatile("s_waitcnt vmcnt(0)" ::: "memory");    \
    BARRIER();                                                                   \
  }

  for (int tt = 0; tt < NT; tt += 2) {
    ITER(tt,     A0h0, A0h1, B0h0, B0h1, A1h1);
    ITER(tt + 1, A1h0, A1h1, B1h0, B1h1, A0h1);
  }
#undef ITER
#undef STGA
#undef STGB

  const int lr = (l >> 4) << 2, lcc = l & 15;
#pragma unroll
  for (int nj = 0; nj < 4; ++nj) {
    int col = n0 + wn * 64 + nj * 16 + lcc;
    float bb = bias[col];
#pragma unroll
    for (int mi = 0; mi < 8; ++mi) {
#pragma unroll
      for (int r = 0; r < 4; ++r) {
        int row = m0 + wm * 128 + mi * 16 + lr + r;
        float v = acc[mi][nj][r] + bb;
        if (RELU) v = fmaxf(v, 0.0f);
        C[(size_t)row * N + col] = f2bf(v);
      }
    }
  }
}

// ---------------------------------------------------------------------------
// GEMM (B^T input), m97-style 128x128: proven workhorse. Used for Wo
// (21 us) and FF2 (81.5 us — at the per-CU VMEM-ingest ceiling; split-K
// atomic measured worse, R6).
// ---------------------------------------------------------------------------
template<int RELU>
__global__ __launch_bounds__(512) void gemm_bt(
    const u16* __restrict__ A, const u16* __restrict__ BT0,
    const float* __restrict__ b0, const float* __restrict__ b1, const float* __restrict__ b2,
    u16* __restrict__ C0, int M, int N, int K, long sBT, long sC)
{
  __shared__ __align__(16) u16 ldsA[128 * 32];
  __shared__ __align__(16) u16 ldsB[128 * 32];

  const int t = threadIdx.x;
  const int wv = t >> 6, l = t & 63;
  const int wm = wv >> 2, wn = wv & 3;
  const int m0 = blockIdx.y * 128, n0 = blockIdx.x * 128;
  const int z = blockIdx.z;

  const u16* BT = BT0 + (long)z * sBT;
  const float* bias = (z == 0) ? b0 : (z == 1 ? b1 : b2);
  u16* C = C0 + (long)z * sC;

  const int mm_s = t >> 2, kc_s = (t & 3) ^ ((t >> 4) & 3);
  const u16* agp = A + (size_t)(m0 + mm_s) * K + kc_s * 8;
  const u16* bgp = BT + (size_t)(n0 + mm_s) * K + kc_s * 8;
  char* la = (char*)ldsA + wv * 1024;
  char* lb = (char*)ldsB + wv * 1024;

  int a_off[4], b_off[2];
#pragma unroll
  for (int i = 0; i < 4; ++i) {
    int mm = wm * 64 + i * 16 + (l & 15);
    a_off[i] = (mm * 4 + ((l >> 4) ^ ((mm >> 2) & 3))) * 8;
  }
#pragma unroll
  for (int j = 0; j < 2; ++j) {
    int nn = wn * 32 + j * 16 + (l & 15);
    b_off[j] = (nn * 4 + ((l >> 4) ^ ((nn >> 2) & 3))) * 8;
  }

  f32x4 acc[4][2] = {};

  for (int kt = 0; kt < K; kt += 32) {
    __syncthreads();
    async16(agp + kt, la);
    async16(bgp + kt, lb);
    __syncthreads();

    bhalf8 af[4], bfr[2];
#pragma unroll
    for (int i = 0; i < 4; ++i) af[i] = *(const bhalf8*)(ldsA + a_off[i]);
#pragma unroll
    for (int j = 0; j < 2; ++j) bfr[j] = *(const bhalf8*)(ldsB + b_off[j]);
#pragma unroll
    for (int mi = 0; mi < 4; ++mi)
#pragma unroll
      for (int nj = 0; nj < 2; ++nj)
        acc[mi][nj] = __builtin_amdgcn_mfma_f32_16x16x32_bf16(af[mi], bfr[nj], acc[mi][nj], 0, 0, 0);
  }

  const int lr = (l >> 4) << 2, lc = l & 15;
#pragma unroll
  for (int nj = 0; nj < 2; ++nj) {
    int col = n0 + wn * 32 + nj * 16 + lc;
    float bb = bias[col];
#pragma unroll
    for (int mi = 0; mi < 4; ++mi) {
#pragma unroll
      for (int r = 0; r < 4; ++r) {
        int row = m0 + wm * 64 + mi * 16 + lr + r;
        float v = acc[mi][nj][r] + bb;
        if (RELU) v = fmaxf(v, 0.0f);
        C[(size_t)row * N + col] = f2bf(v);
      }
    }
  }
}

// ---------------------------------------------------------------------------
// FALLBACK GEMM (natural raw B): C = A[M,K] @ B[K,N] + bias. (R5-proven.)
// ---------------------------------------------------------------------------
template<int RELU>
__global__ __launch_bounds__(256) void gemm_bn(
    const u16* __restrict__ A, const void* __restrict__ B,
    const float* __restrict__ bias, u16* __restrict__ C, int M, int N, int K,
    const int* __restrict__ flag)
{
  __shared__ __align__(16) u16 ldsA[128][40];
  __shared__ __align__(16) u16 ldsB[128][40];

  const int isbf = *flag;
  const int t = threadIdx.x;
  const int wv = t >> 6, l = t & 63;
  const int wm = wv & 1, wn = wv >> 1;
  const int m0 = blockIdx.y * 128, n0 = blockIdx.x * 128;

  const int srow = t >> 1, scol = (t & 1) * 16;
  const u16* agp = A + (size_t)(m0 + srow) * K + scol;

  const int kk = t >> 3;
  const int nn = (t & 7) * 16;

  f32x4 acc[4][4] = {};

  for (int kt = 0; kt < K; kt += 32) {
    bhalf8 a0 = *(const bhalf8*)(agp + kt);
    bhalf8 a1 = *(const bhalf8*)(agp + kt + 8);
    size_t e0 = (size_t)(kt + kk) * N + n0 + nn;
    bhalf8 b0v = load8B(B, e0, isbf);
    bhalf8 b1v = load8B(B, e0 + 8, isbf);
    __syncthreads();
    *(bhalf8*)(&ldsA[srow][scol])     = a0;
    *(bhalf8*)(&ldsA[srow][scol + 8]) = a1;
#pragma unroll
    for (int j = 0; j < 8; ++j) ldsB[nn + j][kk]     = (u16)b0v[j];
#pragma unroll
    for (int j = 0; j < 8; ++j) ldsB[nn + 8 + j][kk] = (u16)b1v[j];
    __syncthreads();

    bhalf8 af[4], bfr[4];
#pragma unroll
    for (int i = 0; i < 4; ++i)
      af[i] = *(const bhalf8*)(&ldsA[wm * 64 + i * 16 + (l & 15)][(l >> 4) * 8]);
#pragma unroll
    for (int i = 0; i < 4; ++i)
      bfr[i] = *(const bhalf8*)(&ldsB[wn * 64 + i * 16 + (l & 15)][(l >> 4) * 8]);
#pragma unroll
    for (int mi = 0; mi < 4; ++mi)
#pragma unroll
      for (int ni = 0; ni < 4; ++ni)
        acc[mi][ni] = __builtin_amdgcn_mfma_f32_16x16x32_bf16(af[mi], bfr[ni], acc[mi][ni], 0, 0, 0);
  }

  const int lr = (l >> 4) << 2, lc = l & 15;
#pragma unroll
  for (int ni = 0; ni < 4; ++ni) {
    int col = n0 + wn * 64 + ni * 16 + lc;
    float bb = bias[col];
#pragma unroll
    for (int mi = 0; mi < 4; ++mi) {
#pragma unroll
      for (int r = 0; r < 4; ++r) {
        int row = m0 + wm * 64 + mi * 16 + lr + r;
        float v = acc[mi][ni][r] + bb;
        if (RELU) v = fmaxf(v, 0.0f);
        C[(size_t)row * N + col] = f2bf(v);
      }
    }
  }
}

// ---------------------------------------------------------------------------
// T5 bias LUT, pre-scaled for max-free softmax:
// lut = (bias - 12) * log2(e); softmax shift-invariance cancels the -12.
// ---------------------------------------------------------------------------
__global__ __launch_bounds__(256) void lut_kernel(const float* __restrict__ rbc, float* __restrict__ lut) {
  int idx = blockIdx.x * 256 + threadIdx.x;
  if (idx >= 16 * 2047) return;
  int h = idx / 2047;
  int dp = idx - h * 2047;
  int delta = dp - 1023;      // rel_pos = i - j
  int n = -delta;
  int ret = 0;
  if (n < 0) { ret = 16; n = -n; }
  int bkt;
  if (n < 8) bkt = n;
  else {
    float v = logf((float)n * 0.125f) / logf(16.0f) * 8.0f;
    bkt = 8 + (int)v;
    if (bkt > 15) bkt = 15;
  }
  lut[idx] = (rbc[(ret + bkt) * 16 + h] - 12.0f) * 1.44269504f;
}

// ---------------------------------------------------------------------------
// Flash attention, max-free softmax: p = 2^(score*log2e + lut' + pad'),
// per-lane partial row sums, one shuffle reduction at block end.
// ---------------------------------------------------------------------------
__global__ __launch_bounds__(256) void attn_fused(
    const u16* __restrict__ q, const u16* __restrict__ k, const u16* __restrict__ vt,
    const int* __restrict__ mask, const float* __restrict__ lut, u16* __restrict__ att)
{
  __shared__ __align__(16) u16 ldsQ[64][72];
  __shared__ __align__(16) u16 ldsK[64][72];
  __shared__ __align__(16) u16 ldsV[64][72];   // row = head-dim e, col = seq j
  __shared__ __align__(16) u16 ldsP[4][16][72];
  __shared__ float ldsLut[2047];
  __shared__ float ldsPad[64];

  const int t = threadIdx.x;
  const int wv = t >> 6, l = t & 63;
  const int bh = blockIdx.x, qt = blockIdx.y;
  const int b = bh >> 4, h = bh & 15;
  const size_t base = (size_t)bh * 65536;
  const int q0 = qt * 64;

  for (int i = t; i < 2047; i += 256) ldsLut[i] = lut[h * 2047 + i];

  const int sr = t >> 2, sc = (t & 3) * 16;
  {
    bhalf8 q0v = *(const bhalf8*)(q + base + (size_t)(q0 + sr) * 64 + sc);
    bhalf8 q1v = *(const bhalf8*)(q + base + (size_t)(q0 + sr) * 64 + sc + 8);
    *(bhalf8*)(&ldsQ[sr][sc])     = q0v;
    *(bhalf8*)(&ldsQ[sr][sc + 8]) = q1v;
  }
  __syncthreads();

  bhalf8 qf[2];
  {
    int mm = wv * 16 + (l & 15);
#pragma unroll
    for (int s = 0; s < 2; ++s)
      qf[s] = *(const bhalf8*)(&ldsQ[mm][s * 32 + (l >> 4) * 8]);
  }

  float ls_part[4] = {0.0f, 0.0f, 0.0f, 0.0f};
  f32x4 acc_o[4] = {};

  const int* mrow = mask + b * 1024;

  for (int kt = 0; kt < 16; ++kt) {
    const int k0 = kt * 64;
    bhalf8 k0v = *(const bhalf8*)(k + base + (size_t)(k0 + sr) * 64 + sc);
    bhalf8 k1v = *(const bhalf8*)(k + base + (size_t)(k0 + sr) * 64 + sc + 8);
    bhalf8 v0v = *(const bhalf8*)(vt + base + (size_t)sr * 1024 + k0 + sc);
    bhalf8 v1v = *(const bhalf8*)(vt + base + (size_t)sr * 1024 + k0 + sc + 8);
    __syncthreads();
    *(bhalf8*)(&ldsK[sr][sc])     = k0v;
    *(bhalf8*)(&ldsK[sr][sc + 8]) = k1v;
    *(bhalf8*)(&ldsV[sr][sc])     = v0v;
    *(bhalf8*)(&ldsV[sr][sc + 8]) = v1v;
    if (t < 64) {
      int mv = mrow[k0 + t];
      ldsPad[t] = (mv > 0) ? __log2f((float)mv) : -1e30f;
    }
    __syncthreads();

    // S = Q K^T  (16x64 per wave)
    f32x4 accS[4] = {};
#pragma unroll
    for (int s = 0; s < 2; ++s) {
#pragma unroll
      for (int ni = 0; ni < 4; ++ni) {
        int nnj = ni * 16 + (l & 15);
        bhalf8 kf = *(const bhalf8*)(&ldsK[nnj][s * 32 + (l >> 4) * 8]);
        accS[ni] = __builtin_amdgcn_mfma_f32_16x16x32_bf16(qf[s], kf, accS[ni], 0, 0, 0);
      }
    }

    // max-free softmax: p = 2^(s*log2e + lut' + pad')
    float padv[4];
#pragma unroll
    for (int ni = 0; ni < 4; ++ni) padv[ni] = ldsPad[ni * 16 + (l & 15)];
    const int ib = q0 + wv * 16 + ((l >> 4) << 2);
#pragma unroll
    for (int r = 0; r < 4; ++r) {
      int i_l = ((l >> 4) << 2) + r;
#pragma unroll
      for (int ni = 0; ni < 4; ++ni) {
        int j_l = ni * 16 + (l & 15);
        float s = fmaf(accS[ni][r], 1.44269504f, ldsLut[(ib + r) - (k0 + j_l) + 1023]) + padv[ni];
        float p = exp2f(s);
        ls_part[r] += p;
        ldsP[wv][i_l][j_l] = f2bf(p);
      }
    }

    // O += P V (per-wave LDS round-trip: C-layout -> A-layout)
#pragma unroll
    for (int s = 0; s < 2; ++s) {
      int mm = l & 15;
      bhalf8 pf = *(const bhalf8*)(&ldsP[wv][mm][s * 32 + (l >> 4) * 8]);
#pragma unroll
      for (int ni = 0; ni < 4; ++ni) {
        int e = ni * 16 + (l & 15);
        bhalf8 vf = *(const bhalf8*)(&ldsV[e][s * 32 + (l >> 4) * 8]);
        acc_o[ni] = __builtin_amdgcn_mfma_f32_16x16x32_bf16(pf, vf, acc_o[ni], 0, 0, 0);
      }
    }
  }

  // row-sum reduction across the 16 lanes of each quad-row group
#pragma unroll
  for (int r = 0; r < 4; ++r) {
#pragma unroll
    for (int off = 1; off < 16; off <<= 1) ls_part[r] += __shfl_xor(ls_part[r], off, 64);
    ls_part[r] = 1.0f / ls_part[r];
  }

#pragma unroll
  for (int ni = 0; ni < 4; ++ni) {
#pragma unroll
    for (int r = 0; r < 4; ++r) {
      int i = q0 + wv * 16 + ((l >> 4) << 2) + r;
      int e = ni * 16 + (l & 15);
      att[base + (size_t)i * 64 + e] = f2bf(acc_o[ni][r] * ls_part[r]);
    }
  }
}

// ---------------------------------------------------------------------------
// LayerNorm(x + res) * g + b. LAST=1 writes d_out as fp32/bf16 per flag.
// ---------------------------------------------------------------------------
template<int LAST>
__global__ __launch_bounds__(256) void ln_kernel(
    const u16* __restrict__ x, const u16* __restrict__ res,
    const float* __restrict__ g, const float* __restrict__ b,
    void* __restrict__ out, const int* __restrict__ flag)
{
  const int row = blockIdx.x, t = threadIdx.x;
  const size_t off = (size_t)row * 1024 + t * 4;
  ushort4 xv = *(const ushort4*)(x + off);
  ushort4 rv = *(const ushort4*)(res + off);
  float v0 = bf2f(xv.x) + bf2f(rv.x);
  float v1 = bf2f(xv.y) + bf2f(rv.y);
  float v2 = bf2f(xv.z) + bf2f(rv.z);
  float v3 = bf2f(xv.w) + bf2f(rv.w);
  float s = v0 + v1 + v2 + v3;
  float sq = v0 * v0 + v1 * v1 + v2 * v2 + v3 * v3;
#pragma unroll
  for (int o = 1; o < 64; o <<= 1) { s += __shfl_xor(s, o, 64); sq += __shfl_xor(sq, o, 64); }
  __shared__ float red[8];
  const int wv = t >> 6, l = t & 63;
  if (l == 0) { red[wv] = s; red[4 + wv] = sq; }
  __syncthreads();
  s = red[0] + red[1] + red[2] + red[3];
  sq = red[4] + red[5] + red[6] + red[7];
  float mu = s * 0.0009765625f;
  float var = sq * 0.0009765625f - mu * mu;
  float rstd = rsqrtf(var + 1e-5f);
  float4 gv = *(const float4*)(g + t * 4);
  float4 bv = *(const float4*)(b + t * 4);
  float o0 = gv.x * (v0 - mu) * rstd + bv.x;
  float o1 = gv.y * (v1 - mu) * rstd + bv.y;
  float o2 = gv.z * (v2 - mu) * rstd + bv.z;
  float o3 = gv.w * (v3 - mu) * rstd + bv.w;
  if (!LAST) {
    ushort4 ov; ov.x = f2bf(o0); ov.y = f2bf(o1); ov.z = f2bf(o2); ov.w = f2bf(o3);
    *(ushort4*)((u16*)out + off) = ov;
  } else {
    if (*flag) {
      ushort4 ov; ov.x = f2bf(o0); ov.y = f2bf(o1); ov.z = f2bf(o2); ov.w = f2bf(o3);
      *(ushort4*)((u16*)out + off) = ov;
    } else {
      float4 ov; ov.x = o0; ov.y = o1; ov.z = o2; ov.w = o3;
      *(float4*)((float*)out + off) = ov;
    }
  }
}

// ---------------------------------------------------------------------------
extern "C" void kernel_launch(void* const* d_in, const int* in_sizes, int n_in,
                              void* d_out, int out_size, void* d_ws, size_t ws_size,
                              hipStream_t stream) {
  const void* x  = d_in[0];
  const int* mask = (const int*)d_in[1];
  const void* Wq = d_in[2];  const void* bq = d_in[3];
  const void* Wk = d_in[4];  const void* bk = d_in[5];
  const void* Wv = d_in[6];  const void* bv = d_in[7];
  const void* Wo = d_in[8];  const void* bo = d_in[9];
  const void* rb = d_in[10];
  const void* g1 = d_in[11]; const void* be1 = d_in[12];
  const void* W1 = d_in[13]; const void* b1 = d_in[14];
  const void* W2 = d_in[15]; const void* b2 = d_in[16];
  const void* g2 = d_in[17]; const void* be2 = d_in[18];

  char* ws = (char*)d_ws;
  const size_t MB = 1024 * 1024;
  const bool FAST = (ws_size >= 57 * MB);

  const size_t TAIL = FAST ? 56 * MB : 48 * MB;
  float* smalls = (float*)(ws + TAIL);
  float* lut    = (float*)(ws + TAIL + 56 * 1024);
  int*   flag   = (int*)(ws + TAIL + 192 * 1024);

  float* bqc  = smalls + 0;
  float* bkc  = smalls + 1024;
  float* bvc  = smalls + 2048;
  float* boc  = smalls + 3072;
  float* rbc  = smalls + 4096;
  float* g1c  = smalls + 4608;
  float* be1c = smalls + 5632;
  float* b1c  = smalls + 6656;
  float* b2c  = smalls + 10752;
  float* g2c  = smalls + 11776;
  float* be2c = smalls + 12800;

  detect_kernel<<<1, 64, 0, stream>>>((const unsigned int*)x, flag);
  Ptr11 sml;
  sml.p[0] = bq; sml.p[1] = bk; sml.p[2] = bv; sml.p[3] = bo; sml.p[4] = rb;
  sml.p[5] = g1; sml.p[6] = be1; sml.p[7] = b1; sml.p[8] = b2; sml.p[9] = g2; sml.p[10] = be2;
  convert_small<<<1, 256, 0, stream>>>(sml, smalls, flag);
  lut_kernel<<<dim3(128), 256, 0, stream>>>(rbc, lut);

  if (FAST) {
    u16* xc   = (u16*)(ws + 0 * MB);
    u16* WqT  = (u16*)(ws + 8 * MB);
    u16* WkT  = WqT + 1048576;
    u16* WvT  = WqT + 2 * 1048576;
    u16* WoT  = WqT + 3 * 1048576;
    u16* qb   = (u16*)(ws + 16 * MB);
    u16* kb   = (u16*)(ws + 24 * MB);
    u16* vb   = (u16*)(ws + 32 * MB);
    u16* vtb  = (u16*)(ws + 40 * MB);
    u16* attb = (u16*)(ws + 32 * MB);
    u16* xo   = (u16*)(ws + 16 * MB);
    u16* hb   = (u16*)(ws + 48 * MB);
    u16* W1T  = (u16*)(ws + 8 * MB);
    u16* W2T  = (u16*)(ws + 0 * MB);
    u16* ff1  = (u16*)(ws + 16 * MB);
    u16* ff2o = (u16*)(ws + 8 * MB);

    convert_x<<<4096, 256, 0, stream>>>(x, xc, flag);
    TC4 tw; tw.in[0] = Wq; tw.in[1] = Wk; tw.in[2] = Wv; tw.in[3] = Wo;
    tw.out[0] = WqT; tw.out[1] = WkT; tw.out[2] = WvT; tw.out[3] = WoT;
    tconv_w4<<<dim3(16, 16, 4), 256, 0, stream>>>(tw, flag);

    // QKV: 8-phase 256^2 asm-barrier (4-barrier R8 schedule), 192 blocks
    gemm256<0><<<dim3(4, 16, 3), 512, 0, stream>>>(xc, WqT, bqc, bkc, bvc, qb,
                                                   4096, 1024, 1024, 1024, 1048576L, 4194304L);
    transpose_generic<<<dim3(1, 16, 64), 256, 0, stream>>>(vb, vtb, 1024, 64);
    attn_fused<<<dim3(64, 16), 256, 0, stream>>>(qb, kb, vtb, mask, lut, attb);
    // Wo: plain gemm_bt (21 us)
    gemm_bt<0><<<dim3(8, 32, 1), 512, 0, stream>>>(attb, WoT, boc, boc, boc, xo,
                                                   4096, 1024, 1024, 0L, 0L);
    tconv_generic<<<dim3(64, 16), 256, 0, stream>>>(W1, W1T, 1024, 4096, flag);
    ln_kernel<0><<<dim3(4096), 256, 0, stream>>>(xo, xc, g1c, be1c, hb, flag);
    tconv_generic<<<dim3(16, 64), 256, 0, stream>>>(W2, W2T, 4096, 1024, flag);
    // FF1: 8-phase 256^2 asm-barrier (4-barrier R8 schedule), 256 blocks
    gemm256<1><<<dim3(16, 16, 1), 512, 0, stream>>>(hb, W1T, b1c, b1c, b1c, ff1,
                                                    4096, 4096, 1024, 1024, 0L, 0L);
    // FF2: plain gemm_bt (81.5 us; ingest-ceiling-bound at 1 blk/CU)
    gemm_bt<0><<<dim3(8, 32, 1), 512, 0, stream>>>(ff1, W2T, b2c, b2c, b2c, ff2o,
                                                   4096, 1024, 4096, 0L, 0L);
    ln_kernel<1><<<dim3(4096), 256, 0, stream>>>(ff2o, hb, g2c, be2c, d_out, flag);
  } else {
    u16* xc   = (u16*)(ws + 0 * MB);
    u16* WqT  = (u16*)(ws + 8 * MB);
    u16* WkT  = WqT + 1048576;
    u16* WvT  = WqT + 2 * 1048576;
    u16* WoT  = WqT + 3 * 1048576;
    u16* qb   = (u16*)(ws + 16 * MB);
    u16* kb   = (u16*)(ws + 24 * MB);
    u16* vb   = (u16*)(ws + 32 * MB);
    u16* vtb  = (u16*)(ws + 40 * MB);
    u16* attb = (u16*)(ws + 32 * MB);
    u16* xo   = (u16*)(ws + 16 * MB);
    u16* hb   = (u16*)(ws + 40 * MB);
    u16* ff1  = (u16*)(ws + 0 * MB);
    u16* ff2o = (u16*)(ws + 32 * MB);

    convert_x<<<4096, 256, 0, stream>>>(x, xc, flag);
    TC4 tw; tw.in[0] = Wq; tw.in[1] = Wk; tw.in[2] = Wv; tw.in[3] = Wo;
    tw.out[0] = WqT; tw.out[1] = WkT; tw.out[2] = WvT; tw.out[3] = WoT;
    tconv_w4<<<dim3(16, 16, 4), 256, 0, stream>>>(tw, flag);

    gemm_bt<0><<<dim3(8, 32, 3), 512, 0, stream>>>(xc, WqT, bqc, bkc, bvc, qb,
                                                   4096, 1024, 1024, 1048576L, 4194304L);
    transpose_generic<<<dim3(1, 16, 64), 256, 0, stream>>>(vb, vtb, 1024, 64);
    attn_fused<<<dim3(64, 16), 256, 0, stream>>>(qb, kb, vtb, mask, lut, attb);
    gemm_bt<0><<<dim3(8, 32, 1), 512, 0, stream>>>(attb, WoT, boc, boc, boc, xo,
                                                   4096, 1024, 1024, 0L, 0L);
    ln_kernel<0><<<dim3(4096), 256, 0, stream>>>(xo, xc, g1c, be1c, hb, flag);
    gemm_bn<1><<<dim3(32, 32), 256, 0, stream>>>(hb, W1, b1c, ff1, 4096, 4096, 1024, flag);
    gemm_bn<0><<<dim3(8, 32), 256, 0, stream>>>(ff1, W2, b2c, ff2o, 4096, 1024, 4096, flag);
    ln_kernel<1><<<dim3(4096), 256, 0, stream>>>(ff2o, hb, g2c, be2c, d_out, flag);
  }
}

// Round 10
// 408.017 us; speedup vs baseline: 1.1684x; 1.0541x over previous
//
#include <hip/hip_runtime.h>
#include <hip/hip_bf16.h>

typedef unsigned short u16;
typedef __attribute__((ext_vector_type(8))) short bhalf8;   // 8 bf16 = 16 B
typedef __attribute__((ext_vector_type(4))) float f32x4;
typedef __attribute__((address_space(3))) const char* LDSP;

#define DEV __device__ __forceinline__

DEV float bf2f(u16 u) { union { unsigned int i; float f; } c; c.i = ((unsigned int)u) << 16; return c.f; }
DEV u16 f2bf(float f) {
  union { float f; unsigned int i; } c; c.f = f;
  unsigned int x = c.i;
  x += 0x7fffu + ((x >> 16) & 1u);   // RNE
  return (u16)(x >> 16);
}

// async 16B global->LDS (wave-uniform LDS base + lane*16)
DEV void async16(const void* g, void* l) {
  __builtin_amdgcn_global_load_lds((__attribute__((address_space(1))) void*)g,
                                   (__attribute__((address_space(3))) void*)l, 16, 0, 0);
}

// opaque ds_read_b128 (no IR-visible LDS read -> no auto waits on it).
// NOTE: takes a BYTE offset.
#define LDSRD(dst, base, off) \
  asm volatile("ds_read_b128 %0, %1" : "=v"(dst) : "v"((LDSP)((const char*)(base) + (off))))

// RAW barrier, invisible to SIInsertWaitcnts' barrier handling. The builtin
// barrier gets a forced vmcnt flush when LDS-DMA writes are pending; the raw
// asm barrier avoids that. A/B-proven: gemm256 builtin 85us -> asm 62us.
#define BARRIER() asm volatile("s_barrier" ::: "memory")
#define SB0() __builtin_amdgcn_sched_barrier(0)

struct Ptr11 { const void* p[11]; };
struct TC4 { const void* in[4]; u16* out[4]; };

// ---------------------------------------------------------------------------
// dtype detector: bf16 -> low u16 of word is plausible bf16; fp32 -> mantissa.
// ---------------------------------------------------------------------------
__global__ void detect_kernel(const unsigned int* __restrict__ x, int* __restrict__ flag) {
  int t = threadIdx.x;
  int cnt = 0;
  for (int i = t; i < 256; i += 64) {
    unsigned int w = x[i];
    int e = (w >> 7) & 0xFF;
    if (e >= 96 && e <= 134) cnt++;
  }
#pragma unroll
  for (int o = 1; o < 64; o <<= 1) cnt += __shfl_xor(cnt, o, 64);
  if (t == 0) *flag = (cnt >= 192) ? 1 : 0;
}

DEV bhalf8 load8B(const void* base, size_t e, int isbf) {
  if (isbf) return *(const bhalf8*)((const u16*)base + e);
  const float* f = (const float*)base + e;
  float4 a = *(const float4*)f;
  float4 b = *(const float4*)(f + 4);
  bhalf8 r;
  r[0] = (short)f2bf(a.x); r[1] = (short)f2bf(a.y); r[2] = (short)f2bf(a.z); r[3] = (short)f2bf(a.w);
  r[4] = (short)f2bf(b.x); r[5] = (short)f2bf(b.y); r[6] = (short)f2bf(b.z); r[7] = (short)f2bf(b.w);
  return r;
}

__global__ __launch_bounds__(256) void convert_x(const void* __restrict__ x,
                                                 u16* __restrict__ dst,
                                                 const int* __restrict__ flag) {
  int c = blockIdx.x * 256 + threadIdx.x;
  u16* d = dst + (size_t)c * 4;
  if (*flag) {
    *(ushort4*)d = ((const ushort4*)x)[c];
  } else {
    float4 v = ((const float4*)x)[c];
    d[0] = f2bf(v.x); d[1] = f2bf(v.y); d[2] = f2bf(v.z); d[3] = f2bf(v.w);
  }
}

__global__ __launch_bounds__(256) void convert_small(Ptr11 s, float* __restrict__ dst,
                                                     const int* __restrict__ flag) {
  const int isbf = *flag;
  const int SZ[11] = {1024,1024,1024,1024,512,1024,1024,4096,1024,1024,1024};
  for (int i = threadIdx.x; i < 13824; i += 256) {
    int acc = 0, seg = -1, off = 0;
#pragma unroll
    for (int s2 = 0; s2 < 11; ++s2) {
      if (seg < 0 && i < acc + SZ[s2]) { seg = s2; off = i - acc; }
      acc += SZ[s2];
    }
    dst[i] = isbf ? bf2f(((const u16*)s.p[seg])[off]) : ((const float*)s.p[seg])[off];
  }
}

// ---------------------------------------------------------------------------
// transpose+convert: out[C,R] (bf16) = in[R,C]^T (raw dtype per flag)
// ---------------------------------------------------------------------------
DEV void tconv_tile(const void* in, u16* out, int R, int C, int isbf) {
  __shared__ __align__(16) u16 tile[64][72];
  const int t = threadIdx.x;
  const int c0 = blockIdx.x * 64, r0 = blockIdx.y * 64;
#pragma unroll
  for (int r = 0; r < 2; ++r) {
    int idx = r * 256 + t;
    int ri = idx >> 3, cc = (idx & 7) * 8;
    bhalf8 v = load8B(in, (size_t)(r0 + ri) * C + c0 + cc, isbf);
    *(bhalf8*)(&tile[ri][cc]) = v;
  }
  __syncthreads();
#pragma unroll
  for (int r = 0; r < 2; ++r) {
    int idx = r * 256 + t;
    int co = idx >> 3, rc = (idx & 7) * 8;
    bhalf8 v;
#pragma unroll
    for (int ii = 0; ii < 8; ++ii) v[ii] = (short)tile[rc + ii][co];
    *(bhalf8*)(out + (size_t)(c0 + co) * R + r0 + rc) = v;
  }
}

__global__ __launch_bounds__(256) void tconv_w4(TC4 p, const int* __restrict__ flag) {
  int z = blockIdx.z;
  tconv_tile(p.in[z], p.out[z], 1024, 1024, *flag);
}

__global__ __launch_bounds__(256) void tconv_generic(const void* in, u16* out, int R, int C,
                                                     const int* __restrict__ flag) {
  tconv_tile(in, out, R, C, *flag);
}

__global__ __launch_bounds__(256) void transpose_generic(const u16* in, u16* out, int R, int C) {
  __shared__ __align__(16) u16 tile[64][72];
  const int t = threadIdx.x;
  const int c0 = blockIdx.x * 64, r0 = blockIdx.y * 64;
  size_t bs = (size_t)R * C * blockIdx.z;
#pragma unroll
  for (int r = 0; r < 2; ++r) {
    int idx = r * 256 + t;
    int ri = idx >> 3, cc = (idx & 7) * 8;
    *(bhalf8*)(&tile[ri][cc]) = *(const bhalf8*)(in + bs + (size_t)(r0 + ri) * C + c0 + cc);
  }
  __syncthreads();
#pragma unroll
  for (int r = 0; r < 2; ++r) {
    int idx = r * 256 + t;
    int co = idx >> 3, rc = (idx & 7) * 8;
    bhalf8 v;
#pragma unroll
    for (int ii = 0; ii < 8; ++ii) v[ii] = (short)tile[rc + ii][co];
    *(bhalf8*)(out + bs + (size_t)(c0 + co) * R + r0 + rc) = v;
  }
}

// ---------------------------------------------------------------------------
// 8-phase 256x256 GEMM (B^T input), asm-barrier, 4-barriers-per-K-tile (R8
// schedule, verified R8). Counted vmcnt(6) at K-tile boundary only.
// blockIdx.z selects the (BT, bias, C) triple (QKV batching).
// ---------------------------------------------------------------------------
#define MFMA_BF16(a, b, c) __builtin_amdgcn_mfma_f32_16x16x32_bf16(a, b, c, 0, 0, 0)

template<int RELU>
__global__ __launch_bounds__(512) void gemm256(
    const u16* __restrict__ A, const u16* __restrict__ BT0,
    const float* __restrict__ b0, const float* __restrict__ b1, const float* __restrict__ b2,
    u16* __restrict__ C0, int M, int N, int ldk, int kext, long sBT, long sC)
{
  __shared__ __align__(16) u16 A0h0[8192], A0h1[8192], A1h0[8192], A1h1[8192];
  __shared__ __align__(16) u16 B0h0[8192], B0h1[8192], B1h0[8192], B1h1[8192];
  (void)M;

  const int t = threadIdx.x;
  const int wv = t >> 6, l = t & 63;
  const int wm = wv >> 2, wn = wv & 3;
  const int z = blockIdx.z;

  // XCD-aware bijective swizzle (nwg%8==0 at all call sites).
  const int gx = gridDim.x;
  const int nwg = gx * gridDim.y;
  int wgid = blockIdx.y * gx + blockIdx.x;
  wgid = (wgid & 7) * (nwg >> 3) + (wgid >> 3);
  const int m0 = (wgid / gx) * 256, n0 = (wgid % gx) * 256;

  const u16* BT = BT0 + (long)z * sBT;
  const float* bias = (z == 0) ? b0 : (z == 1 ? b1 : b2);
  u16* C = C0 + (long)z * sC;

  const int ri = t >> 3;
  const int slc8 = (((t & 7) ^ (ri & 7)) << 3);
  const u16* agp = A + (size_t)(m0 + ri) * ldk + slc8;
  const int rB = ((ri >> 5) << 6) | (ri & 31);
  const u16* bgp = BT + (size_t)(n0 + rB) * ldk + slc8;

#define STGA(ARR, h, j, kt) async16(agp + (size_t)((j) * 128 + (h) * 64) * ldk + (size_t)(kt) * 64, \
                                    (char*)(ARR) + (j) * 8192 + wv * 1024)
#define STGB(ARR, h, j, kt) async16(bgp + (size_t)((j) * 128 + (h) * 32) * ldk + (size_t)(kt) * 64, \
                                    (char*)(ARR) + (j) * 8192 + wv * 1024)

  int offA[4][2], offB[2][2];
#pragma unroll
  for (int mi = 0; mi < 4; ++mi)
#pragma unroll
    for (int s = 0; s < 2; ++s)
      offA[mi][s] = wm * 8192 + (mi * 16 + (l & 15)) * 128 + ((((s << 2) + (l >> 4)) ^ (l & 7)) << 4);
#pragma unroll
  for (int nj = 0; nj < 2; ++nj)
#pragma unroll
    for (int s = 0; s < 2; ++s)
      offB[nj][s] = wn * 4096 + (nj * 16 + (l & 15)) * 128 + ((((s << 2) + (l >> 4)) ^ (l & 7)) << 4);

  const int NT = kext >> 6;   // even (all call sites: 16)
  f32x4 acc[8][4] = {};

  // prologue: tile0 all 4 half-tiles (buf0) + tile1 first 3 (buf1)
  STGA(A0h0, 0, 0, 0); STGA(A0h0, 0, 1, 0);
  STGB(B0h0, 0, 0, 0); STGB(B0h0, 0, 1, 0);
  STGB(B0h1, 1, 0, 0); STGB(B0h1, 1, 1, 0);
  STGA(A0h1, 1, 0, 0); STGA(A0h1, 1, 1, 0);
  if (NT > 1) {
    STGA(A1h0, 0, 0, 1); STGA(A1h0, 0, 1, 1);
    STGB(B1h0, 0, 0, 1); STGB(B1h0, 0, 1, 1);
    STGB(B1h1, 1, 0, 1); STGB(B1h1, 1, 1, 1);
    asm volatile("s_waitcnt vmcnt(6)" ::: "memory");
  } else {
    asm volatile("s_waitcnt vmcnt(0)" ::: "memory");
  }
  BARRIER();

#define ITER(TT, CA0, CA1, CB0, CB1, NA1)                                        \
  {                                                                              \
    bhalf8 af[4][2], p0[2][2], p1[2][2];                                         \
    _Pragma("unroll") for (int mi = 0; mi < 4; ++mi)                             \
      _Pragma("unroll") for (int s = 0; s < 2; ++s)                              \
        LDSRD(af[mi][s], CA0, offA[mi][s]);                                      \
    _Pragma("unroll") for (int nj = 0; nj < 2; ++nj)                             \
      _Pragma("unroll") for (int s = 0; s < 2; ++s)                              \
        LDSRD(p0[nj][s], CB0, offB[nj][s]);                                      \
    BARRIER();                                                                   \
    asm volatile("s_waitcnt lgkmcnt(0)" ::: "memory");                           \
    SB0();                                                                       \
    if ((TT) + 1 < NT) { STGA(NA1, 1, 0, (TT) + 1); STGA(NA1, 1, 1, (TT) + 1); } \
    SB0();                                                                       \
    __builtin_amdgcn_s_setprio(1);                                               \
    _Pragma("unroll") for (int mi = 0; mi < 4; ++mi)                             \
      _Pragma("unroll") for (int nj = 0; nj < 2; ++nj) {                         \
        acc[mi][nj] = MFMA_BF16(af[mi][0], p0[nj][0], acc[mi][nj]);              \
        acc[mi][nj] = MFMA_BF16(af[mi][1], p0[nj][1], acc[mi][nj]);              \
      }                                                                          \
    __builtin_amdgcn_s_setprio(0);                                               \
    _Pragma("unroll") for (int nj = 0; nj < 2; ++nj)                             \
      _Pragma("unroll") for (int s = 0; s < 2; ++s)                              \
        LDSRD(p1[nj][s], CB1, offB[nj][s]);                                      \
    BARRIER();                                                                   \
    asm volatile("s_waitcnt lgkmcnt(0)" ::: "memory");                           \
    SB0();                                                                       \
    if ((TT) + 2 < NT) { STGA(CA0, 0, 0, (TT) + 2); STGA(CA0, 0, 1, (TT) + 2); } \
    SB0();                                                                       \
    __builtin_amdgcn_s_setprio(1);                                               \
    _Pragma("unroll") for (int mi = 0; mi < 4; ++mi)                             \
      _Pragma("unroll") for (int nj = 0; nj < 2; ++nj) {                         \
        acc[mi][2 + nj] = MFMA_BF16(af[mi][0], p1[nj][0], acc[mi][2 + nj]);      \
        acc[mi][2 + nj] = MFMA_BF16(af[mi][1], p1[nj][1], acc[mi][2 + nj]);      \
      }                                                                          \
    __builtin_amdgcn_s_setprio(0);                                               \
    _Pragma("unroll") for (int mi = 0; mi < 4; ++mi)                             \
      _Pragma("unroll") for (int s = 0; s < 2; ++s)                              \
        LDSRD(af[mi][s], CA1, offA[mi][s]);                                      \
    BARRIER();                                                                   \
    asm volatile("s_waitcnt lgkmcnt(0)" ::: "memory");                           \
    SB0();                                                                       \
    if ((TT) + 2 < NT) { STGB(CB0, 0, 0, (TT) + 2); STGB(CB0, 0, 1, (TT) + 2); } \
    SB0();                                                                       \
    __builtin_amdgcn_s_setprio(1);                                               \
    _Pragma("unroll") for (int mi = 0; mi < 4; ++mi)                             \
      _Pragma("unroll") for (int nj = 0; nj < 2; ++nj) {                         \
        acc[4 + mi][2 + nj] = MFMA_BF16(af[mi][0], p1[nj][0], acc[4 + mi][2 + nj]); \
        acc[4 + mi][2 + nj] = MFMA_BF16(af[mi][1], p1[nj][1], acc[4 + mi][2 + nj]); \
      }                                                                          \
    __builtin_amdgcn_s_setprio(0);                                               \
    if ((TT) + 2 < NT) { STGB(CB1, 1, 0, (TT) + 2); STGB(CB1, 1, 1, (TT) + 2); } \
    SB0();                                                                       \
    __builtin_amdgcn_s_setprio(1);                                               \
    _Pragma("unroll") for (int mi = 0; mi < 4; ++mi)                             \
      _Pragma("unroll") for (int nj = 0; nj < 2; ++nj) {                         \
        acc[4 + mi][nj] = MFMA_BF16(af[mi][0], p0[nj][0], acc[4 + mi][nj]);      \
        acc[4 + mi][nj] = MFMA_BF16(af[mi][1], p0[nj][1], acc[4 + mi][nj]);      \
      }                                                                          \
    __builtin_amdgcn_s_setprio(0);                                               \
    SB0();                                                                       \
    if ((TT) < NT - 2)       asm volatile("s_waitcnt vmcnt(6)" ::: "memory");    \
    else if ((TT) == NT - 2) asm volatile("s_waitcnt vmcnt(0)" ::: "memory");    \
    BARRIER();                                                                   \
  }

  for (int tt = 0; tt < NT; tt += 2) {
    ITER(tt,     A0h0, A0h1, B0h0, B0h1, A1h1);
    ITER(tt + 1, A1h0, A1h1, B1h0, B1h1, A0h1);
  }
#undef ITER
#undef STGA
#undef STGB

  const int lr = (l >> 4) << 2, lcc = l & 15;
#pragma unroll
  for (int nj = 0; nj < 4; ++nj) {
    int col = n0 + wn * 64 + nj * 16 + lcc;
    float bb = bias[col];
#pragma unroll
    for (int mi = 0; mi < 8; ++mi) {
#pragma unroll
      for (int r = 0; r < 4; ++r) {
        int row = m0 + wm * 128 + mi * 16 + lr + r;
        float v = acc[mi][nj][r] + bb;
        if (RELU) v = fmaxf(v, 0.0f);
        C[(size_t)row * N + col] = f2bf(v);
      }
    }
  }
}

// ---------------------------------------------------------------------------
// R10: double-buffered 128x128 GEMM (B^T input), counted vmcnt(2).
// R9 FAILED from two porting bugs, both fixed here:
//   (a) wave staging base was wv*512; each wave writes 64 lanes x 16B =
//       1024 B -> must be wv*1024 (waves were overlap-writing).
//   (b) a_off/b_off were u16-ELEMENT offsets (gemm_bt adds them to a u16*),
//       but LDSRD takes BYTE offsets -> all reads hit half the address.
//       Now computed in bytes: (row*4 + physchunk) * 16.
// Sync design (re-audited, unchanged): step entry vmcnt(2)+BARRIER makes
// tile-KT DMAs of ALL waves visible; lgkm(0)+BARRIER after reads makes
// re-staging of this buffer WAR-safe; prologue issues tiles 0,1 (4 DMAs);
// steady state keeps 4 outstanding, vmcnt(2) retires the current tile;
// vmcnt(0) only on the last tile.
// ---------------------------------------------------------------------------
template<int RELU>
__global__ __launch_bounds__(512) void gemm_btdb(
    const u16* __restrict__ A, const u16* __restrict__ BT0,
    const float* __restrict__ b0, const float* __restrict__ b1, const float* __restrict__ b2,
    u16* __restrict__ C0, int M, int N, int K, long sBT, long sC)
{
  __shared__ __align__(16) u16 ldsA0[4096], ldsA1[4096];
  __shared__ __align__(16) u16 ldsB0[4096], ldsB1[4096];

  const int t = threadIdx.x;
  const int wv = t >> 6, l = t & 63;
  const int wm = wv >> 2, wn = wv & 3;
  const int m0 = blockIdx.y * 128, n0 = blockIdx.x * 128;
  const int z = blockIdx.z;

  const u16* BT = BT0 + (long)z * sBT;
  const float* bias = (z == 0) ? b0 : (z == 1 ? b1 : b2);
  u16* C = C0 + (long)z * sC;

  // staging: slot t -> (row t>>2, global chunk (t&3)^((t>>4)&3))
  const int mm_s = t >> 2, kc_s = (t & 3) ^ ((t >> 4) & 3);
  const u16* agp = A + (size_t)(m0 + mm_s) * K + kc_s * 8;
  const u16* bgp = BT + (size_t)(n0 + mm_s) * K + kc_s * 8;
  char* la0 = (char*)ldsA0 + wv * 1024;   // FIX (a): 1024 B per wave
  char* la1 = (char*)ldsA1 + wv * 1024;
  char* lb0 = (char*)ldsB0 + wv * 1024;
  char* lb1 = (char*)ldsB1 + wv * 1024;

  // BYTE offsets for LDSRD — FIX (b): x16, not x8
  int a_off[4], b_off[2];
#pragma unroll
  for (int i = 0; i < 4; ++i) {
    int mm = wm * 64 + i * 16 + (l & 15);
    a_off[i] = (mm * 4 + ((l >> 4) ^ ((mm >> 2) & 3))) * 16;
  }
#pragma unroll
  for (int j = 0; j < 2; ++j) {
    int nn = wn * 32 + j * 16 + (l & 15);
    b_off[j] = (nn * 4 + ((l >> 4) ^ ((nn >> 2) & 3))) * 16;
  }

  f32x4 acc[4][2] = {};

  // prologue: tiles 0 (buf0) and 1 (buf1). K is a multiple of 64 (1024/4096).
  async16(agp + 0, la0);  async16(bgp + 0, lb0);
  async16(agp + 32, la1); async16(bgp + 32, lb1);

#define DBITER(KT, CA, CB, LA, LB)                                               \
  {                                                                              \
    if ((KT) + 32 >= K) asm volatile("s_waitcnt vmcnt(0)" ::: "memory");         \
    else                asm volatile("s_waitcnt vmcnt(2)" ::: "memory");         \
    BARRIER();                                                                   \
    bhalf8 af[4], bfr[2];                                                        \
    _Pragma("unroll") for (int i = 0; i < 4; ++i) LDSRD(af[i], CA, a_off[i]);    \
    _Pragma("unroll") for (int j = 0; j < 2; ++j) LDSRD(bfr[j], CB, b_off[j]);   \
    asm volatile("s_waitcnt lgkmcnt(0)" ::: "memory");                           \
    SB0();                                                                       \
    BARRIER();                                                                   \
    if ((KT) + 64 < K) { async16(agp + (KT) + 64, LA); async16(bgp + (KT) + 64, LB); } \
    SB0();                                                                       \
    __builtin_amdgcn_s_setprio(1);                                               \
    _Pragma("unroll") for (int mi = 0; mi < 4; ++mi)                             \
      _Pragma("unroll") for (int nj = 0; nj < 2; ++nj)                           \
        acc[mi][nj] = MFMA_BF16(af[mi], bfr[nj], acc[mi][nj]);                   \
    __builtin_amdgcn_s_setprio(0);                                               \
  }

  for (int kt = 0; kt < K; kt += 64) {
    DBITER(kt,      ldsA0, ldsB0, la0, lb0);
    DBITER(kt + 32, ldsA1, ldsB1, la1, lb1);
  }
#undef DBITER

  const int lr = (l >> 4) << 2, lc = l & 15;
#pragma unroll
  for (int nj = 0; nj < 2; ++nj) {
    int col = n0 + wn * 32 + nj * 16 + lc;
    float bb = bias[col];
#pragma unroll
    for (int mi = 0; mi < 4; ++mi) {
#pragma unroll
      for (int r = 0; r < 4; ++r) {
        int row = m0 + wm * 64 + mi * 16 + lr + r;
        float v = acc[mi][nj][r] + bb;
        if (RELU) v = fmaxf(v, 0.0f);
        C[(size_t)row * N + col] = f2bf(v);
      }
    }
  }
}

// ---------------------------------------------------------------------------
// GEMM (B^T input), m97-style 128x128 2-phase: proven fallback.
// ---------------------------------------------------------------------------
template<int RELU>
__global__ __launch_bounds__(512) void gemm_bt(
    const u16* __restrict__ A, const u16* __restrict__ BT0,
    const float* __restrict__ b0, const float* __restrict__ b1, const float* __restrict__ b2,
    u16* __restrict__ C0, int M, int N, int K, long sBT, long sC)
{
  __shared__ __align__(16) u16 ldsA[128 * 32];
  __shared__ __align__(16) u16 ldsB[128 * 32];

  const int t = threadIdx.x;
  const int wv = t >> 6, l = t & 63;
  const int wm = wv >> 2, wn = wv & 3;
  const int m0 = blockIdx.y * 128, n0 = blockIdx.x * 128;
  const int z = blockIdx.z;

  const u16* BT = BT0 + (long)z * sBT;
  const float* bias = (z == 0) ? b0 : (z == 1 ? b1 : b2);
  u16* C = C0 + (long)z * sC;

  const int mm_s = t >> 2, kc_s = (t & 3) ^ ((t >> 4) & 3);
  const u16* agp = A + (size_t)(m0 + mm_s) * K + kc_s * 8;
  const u16* bgp = BT + (size_t)(n0 + mm_s) * K + kc_s * 8;
  char* la = (char*)ldsA + wv * 1024;
  char* lb = (char*)ldsB + wv * 1024;

  int a_off[4], b_off[2];
#pragma unroll
  for (int i = 0; i < 4; ++i) {
    int mm = wm * 64 + i * 16 + (l & 15);
    a_off[i] = (mm * 4 + ((l >> 4) ^ ((mm >> 2) & 3))) * 8;
  }
#pragma unroll
  for (int j = 0; j < 2; ++j) {
    int nn = wn * 32 + j * 16 + (l & 15);
    b_off[j] = (nn * 4 + ((l >> 4) ^ ((nn >> 2) & 3))) * 8;
  }

  f32x4 acc[4][2] = {};

  for (int kt = 0; kt < K; kt += 32) {
    __syncthreads();
    async16(agp + kt, la);
    async16(bgp + kt, lb);
    __syncthreads();

    bhalf8 af[4], bfr[2];
#pragma unroll
    for (int i = 0; i < 4; ++i) af[i] = *(const bhalf8*)(ldsA + a_off[i]);
#pragma unroll
    for (int j = 0; j < 2; ++j) bfr[j] = *(const bhalf8*)(ldsB + b_off[j]);
#pragma unroll
    for (int mi = 0; mi < 4; ++mi)
#pragma unroll
      for (int nj = 0; nj < 2; ++nj)
        acc[mi][nj] = __builtin_amdgcn_mfma_f32_16x16x32_bf16(af[mi], bfr[nj], acc[mi][nj], 0, 0, 0);
  }

  const int lr = (l >> 4) << 2, lc = l & 15;
#pragma unroll
  for (int nj = 0; nj < 2; ++nj) {
    int col = n0 + wn * 32 + nj * 16 + lc;
    float bb = bias[col];
#pragma unroll
    for (int mi = 0; mi < 4; ++mi) {
#pragma unroll
      for (int r = 0; r < 4; ++r) {
        int row = m0 + wm * 64 + mi * 16 + lr + r;
        float v = acc[mi][nj][r] + bb;
        if (RELU) v = fmaxf(v, 0.0f);
        C[(size_t)row * N + col] = f2bf(v);
      }
    }
  }
}

// ---------------------------------------------------------------------------
// FALLBACK GEMM (natural raw B): C = A[M,K] @ B[K,N] + bias. (R5-proven.)
// ---------------------------------------------------------------------------
template<int RELU>
__global__ __launch_bounds__(256) void gemm_bn(
    const u16* __restrict__ A, const void* __restrict__ B,
    const float* __restrict__ bias, u16* __restrict__ C, int M, int N, int K,
    const int* __restrict__ flag)
{
  __shared__ __align__(16) u16 ldsA[128][40];
  __shared__ __align__(16) u16 ldsB[128][40];

  const int isbf = *flag;
  const int t = threadIdx.x;
  const int wv = t >> 6, l = t & 63;
  const int wm = wv & 1, wn = wv >> 1;
  const int m0 = blockIdx.y * 128, n0 = blockIdx.x * 128;

  const int srow = t >> 1, scol = (t & 1) * 16;
  const u16* agp = A + (size_t)(m0 + srow) * K + scol;

  const int kk = t >> 3;
  const int nn = (t & 7) * 16;

  f32x4 acc[4][4] = {};

  for (int kt = 0; kt < K; kt += 32) {
    bhalf8 a0 = *(const bhalf8*)(agp + kt);
    bhalf8 a1 = *(const bhalf8*)(agp + kt + 8);
    size_t e0 = (size_t)(kt + kk) * N + n0 + nn;
    bhalf8 b0v = load8B(B, e0, isbf);
    bhalf8 b1v = load8B(B, e0 + 8, isbf);
    __syncthreads();
    *(bhalf8*)(&ldsA[srow][scol])     = a0;
    *(bhalf8*)(&ldsA[srow][scol + 8]) = a1;
#pragma unroll
    for (int j = 0; j < 8; ++j) ldsB[nn + j][kk]     = (u16)b0v[j];
#pragma unroll
    for (int j = 0; j < 8; ++j) ldsB[nn + 8 + j][kk] = (u16)b1v[j];
    __syncthreads();

    bhalf8 af[4], bfr[4];
#pragma unroll
    for (int i = 0; i < 4; ++i)
      af[i] = *(const bhalf8*)(&ldsA[wm * 64 + i * 16 + (l & 15)][(l >> 4) * 8]);
#pragma unroll
    for (int i = 0; i < 4; ++i)
      bfr[i] = *(const bhalf8*)(&ldsB[wn * 64 + i * 16 + (l & 15)][(l >> 4) * 8]);
#pragma unroll
    for (int mi = 0; mi < 4; ++mi)
#pragma unroll
      for (int ni = 0; ni < 4; ++ni)
        acc[mi][ni] = __builtin_amdgcn_mfma_f32_16x16x32_bf16(af[mi], bfr[ni], acc[mi][ni], 0, 0, 0);
  }

  const int lr = (l >> 4) << 2, lc = l & 15;
#pragma unroll
  for (int ni = 0; ni < 4; ++ni) {
    int col = n0 + wn * 64 + ni * 16 + lc;
    float bb = bias[col];
#pragma unroll
    for (int mi = 0; mi < 4; ++mi) {
#pragma unroll
      for (int r = 0; r < 4; ++r) {
        int row = m0 + wm * 64 + mi * 16 + lr + r;
        float v = acc[mi][ni][r] + bb;
        if (RELU) v = fmaxf(v, 0.0f);
        C[(size_t)row * N + col] = f2bf(v);
      }
    }
  }
}

// ---------------------------------------------------------------------------
// T5 bias LUT, pre-scaled for max-free softmax:
// lut = (bias - 12) * log2(e); softmax shift-invariance cancels the -12.
// ---------------------------------------------------------------------------
__global__ __launch_bounds__(256) void lut_kernel(const float* __restrict__ rbc, float* __restrict__ lut) {
  int idx = blockIdx.x * 256 + threadIdx.x;
  if (idx >= 16 * 2047) return;
  int h = idx / 2047;
  int dp = idx - h * 2047;
  int delta = dp - 1023;      // rel_pos = i - j
  int n = -delta;
  int ret = 0;
  if (n < 0) { ret = 16; n = -n; }
  int bkt;
  if (n < 8) bkt = n;
  else {
    float v = logf((float)n * 0.125f) / logf(16.0f) * 8.0f;
    bkt = 8 + (int)v;
    if (bkt > 15) bkt = 15;
  }
  lut[idx] = (rbc[(ret + bkt) * 16 + h] - 12.0f) * 1.44269504f;
}

// ---------------------------------------------------------------------------
// Flash attention, max-free softmax: p = 2^(score*log2e + lut' + pad'),
// per-lane partial row sums, one shuffle reduction at block end.
// ---------------------------------------------------------------------------
__global__ __launch_bounds__(256) void attn_fused(
    const u16* __restrict__ q, const u16* __restrict__ k, const u16* __restrict__ vt,
    const int* __restrict__ mask, const float* __restrict__ lut, u16* __restrict__ att)
{
  __shared__ __align__(16) u16 ldsQ[64][72];
  __shared__ __align__(16) u16 ldsK[64][72];
  __shared__ __align__(16) u16 ldsV[64][72];   // row = head-dim e, col = seq j
  __shared__ __align__(16) u16 ldsP[4][16][72];
  __shared__ float ldsLut[2047];
  __shared__ float ldsPad[64];

  const int t = threadIdx.x;
  const int wv = t >> 6, l = t & 63;
  const int bh = blockIdx.x, qt = blockIdx.y;
  const int b = bh >> 4, h = bh & 15;
  const size_t base = (size_t)bh * 65536;
  const int q0 = qt * 64;

  for (int i = t; i < 2047; i += 256) ldsLut[i] = lut[h * 2047 + i];

  const int sr = t >> 2, sc = (t & 3) * 16;
  {
    bhalf8 q0v = *(const bhalf8*)(q + base + (size_t)(q0 + sr) * 64 + sc);
    bhalf8 q1v = *(const bhalf8*)(q + base + (size_t)(q0 + sr) * 64 + sc + 8);
    *(bhalf8*)(&ldsQ[sr][sc])     = q0v;
    *(bhalf8*)(&ldsQ[sr][sc + 8]) = q1v;
  }
  __syncthreads();

  bhalf8 qf[2];
  {
    int mm = wv * 16 + (l & 15);
#pragma unroll
    for (int s = 0; s < 2; ++s)
      qf[s] = *(const bhalf8*)(&ldsQ[mm][s * 32 + (l >> 4) * 8]);
  }

  float ls_part[4] = {0.0f, 0.0f, 0.0f, 0.0f};
  f32x4 acc_o[4] = {};

  const int* mrow = mask + b * 1024;

  for (int kt = 0; kt < 16; ++kt) {
    const int k0 = kt * 64;
    bhalf8 k0v = *(const bhalf8*)(k + base + (size_t)(k0 + sr) * 64 + sc);
    bhalf8 k1v = *(const bhalf8*)(k + base + (size_t)(k0 + sr) * 64 + sc + 8);
    bhalf8 v0v = *(const bhalf8*)(vt + base + (size_t)sr * 1024 + k0 + sc);
    bhalf8 v1v = *(const bhalf8*)(vt + base + (size_t)sr * 1024 + k0 + sc + 8);
    __syncthreads();
    *(bhalf8*)(&ldsK[sr][sc])     = k0v;
    *(bhalf8*)(&ldsK[sr][sc + 8]) = k1v;
    *(bhalf8*)(&ldsV[sr][sc])     = v0v;
    *(bhalf8*)(&ldsV[sr][sc + 8]) = v1v;
    if (t < 64) {
      int mv = mrow[k0 + t];
      ldsPad[t] = (mv > 0) ? __log2f((float)mv) : -1e30f;
    }
    __syncthreads();

    // S = Q K^T  (16x64 per wave)
    f32x4 accS[4] = {};
#pragma unroll
    for (int s = 0; s < 2; ++s) {
#pragma unroll
      for (int ni = 0; ni < 4; ++ni) {
        int nnj = ni * 16 + (l & 15);
        bhalf8 kf = *(const bhalf8*)(&ldsK[nnj][s * 32 + (l >> 4) * 8]);
        accS[ni] = __builtin_amdgcn_mfma_f32_16x16x32_bf16(qf[s], kf, accS[ni], 0, 0, 0);
      }
    }

    // max-free softmax: p = 2^(s*log2e + lut' + pad')
    float padv[4];
#pragma unroll
    for (int ni = 0; ni < 4; ++ni) padv[ni] = ldsPad[ni * 16 + (l & 15)];
    const int ib = q0 + wv * 16 + ((l >> 4) << 2);
#pragma unroll
    for (int r = 0; r < 4; ++r) {
      int i_l = ((l >> 4) << 2) + r;
#pragma unroll
      for (int ni = 0; ni < 4; ++ni) {
        int j_l = ni * 16 + (l & 15);
        float s = fmaf(accS[ni][r], 1.44269504f, ldsLut[(ib + r) - (k0 + j_l) + 1023]) + padv[ni];
        float p = exp2f(s);
        ls_part[r] += p;
        ldsP[wv][i_l][j_l] = f2bf(p);
      }
    }

    // O += P V (per-wave LDS round-trip: C-layout -> A-layout)
#pragma unroll
    for (int s = 0; s < 2; ++s) {
      int mm = l & 15;
      bhalf8 pf = *(const bhalf8*)(&ldsP[wv][mm][s * 32 + (l >> 4) * 8]);
#pragma unroll
      for (int ni = 0; ni < 4; ++ni) {
        int e = ni * 16 + (l & 15);
        bhalf8 vf = *(const bhalf8*)(&ldsV[e][s * 32 + (l >> 4) * 8]);
        acc_o[ni] = __builtin_amdgcn_mfma_f32_16x16x32_bf16(pf, vf, acc_o[ni], 0, 0, 0);
      }
    }
  }

  // row-sum reduction across the 16 lanes of each quad-row group
#pragma unroll
  for (int r = 0; r < 4; ++r) {
#pragma unroll
    for (int off = 1; off < 16; off <<= 1) ls_part[r] += __shfl_xor(ls_part[r], off, 64);
    ls_part[r] = 1.0f / ls_part[r];
  }

#pragma unroll
  for (int ni = 0; ni < 4; ++ni) {
#pragma unroll
    for (int r = 0; r < 4; ++r) {
      int i = q0 + wv * 16 + ((l >> 4) << 2) + r;
      int e = ni * 16 + (l & 15);
      att[base + (size_t)i * 64 + e] = f2bf(acc_o[ni][r] * ls_part[r]);
    }
  }
}

// ---------------------------------------------------------------------------
// LayerNorm(x + res) * g + b. LAST=1 writes d_out as fp32/bf16 per flag.
// ---------------------------------------------------------------------------
template<int LAST>
__global__ __launch_bounds__(256) void ln_kernel(
    const u16* __restrict__ x, const u16* __restrict__ res,
    const float* __restrict__ g, const float* __restrict__ b,
    void* __restrict__ out, const int* __restrict__ flag)
{
  const int row = blockIdx.x, t = threadIdx.x;
  const size_t off = (size_t)row * 1024 + t * 4;
  ushort4 xv = *(const ushort4*)(x + off);
  ushort4 rv = *(const ushort4*)(res + off);
  float v0 = bf2f(xv.x) + bf2f(rv.x);
  float v1 = bf2f(xv.y) + bf2f(rv.y);
  float v2 = bf2f(xv.z) + bf2f(rv.z);
  float v3 = bf2f(xv.w) + bf2f(rv.w);
  float s = v0 + v1 + v2 + v3;
  float sq = v0 * v0 + v1 * v1 + v2 * v2 + v3 * v3;
#pragma unroll
  for (int o = 1; o < 64; o <<= 1) { s += __shfl_xor(s, o, 64); sq += __shfl_xor(sq, o, 64); }
  __shared__ float red[8];
  const int wv = t >> 6, l = t & 63;
  if (l == 0) { red[wv] = s; red[4 + wv] = sq; }
  __syncthreads();
  s = red[0] + red[1] + red[2] + red[3];
  sq = red[4] + red[5] + red[6] + red[7];
  float mu = s * 0.0009765625f;
  float var = sq * 0.0009765625f - mu * mu;
  float rstd = rsqrtf(var + 1e-5f);
  float4 gv = *(const float4*)(g + t * 4);
  float4 bv = *(const float4*)(b + t * 4);
  float o0 = gv.x * (v0 - mu) * rstd + bv.x;
  float o1 = gv.y * (v1 - mu) * rstd + bv.y;
  float o2 = gv.z * (v2 - mu) * rstd + bv.z;
  float o3 = gv.w * (v3 - mu) * rstd + bv.w;
  if (!LAST) {
    ushort4 ov; ov.x = f2bf(o0); ov.y = f2bf(o1); ov.z = f2bf(o2); ov.w = f2bf(o3);
    *(ushort4*)((u16*)out + off) = ov;
  } else {
    if (*flag) {
      ushort4 ov; ov.x = f2bf(o0); ov.y = f2bf(o1); ov.z = f2bf(o2); ov.w = f2bf(o3);
      *(ushort4*)((u16*)out + off) = ov;
    } else {
      float4 ov; ov.x = o0; ov.y = o1; ov.z = o2; ov.w = o3;
      *(float4*)((float*)out + off) = ov;
    }
  }
}

// ---------------------------------------------------------------------------
extern "C" void kernel_launch(void* const* d_in, const int* in_sizes, int n_in,
                              void* d_out, int out_size, void* d_ws, size_t ws_size,
                              hipStream_t stream) {
  const void* x  = d_in[0];
  const int* mask = (const int*)d_in[1];
  const void* Wq = d_in[2];  const void* bq = d_in[3];
  const void* Wk = d_in[4];  const void* bk = d_in[5];
  const void* Wv = d_in[6];  const void* bv = d_in[7];
  const void* Wo = d_in[8];  const void* bo = d_in[9];
  const void* rb = d_in[10];
  const void* g1 = d_in[11]; const void* be1 = d_in[12];
  const void* W1 = d_in[13]; const void* b1 = d_in[14];
  const void* W2 = d_in[15]; const void* b2 = d_in[16];
  const void* g2 = d_in[17]; const void* be2 = d_in[18];

  char* ws = (char*)d_ws;
  const size_t MB = 1024 * 1024;
  const bool FAST = (ws_size >= 57 * MB);

  const size_t TAIL = FAST ? 56 * MB : 48 * MB;
  float* smalls = (float*)(ws + TAIL);
  float* lut    = (float*)(ws + TAIL + 56 * 1024);
  int*   flag   = (int*)(ws + TAIL + 192 * 1024);

  float* bqc  = smalls + 0;
  float* bkc  = smalls + 1024;
  float* bvc  = smalls + 2048;
  float* boc  = smalls + 3072;
  float* rbc  = smalls + 4096;
  float* g1c  = smalls + 4608;
  float* be1c = smalls + 5632;
  float* b1c  = smalls + 6656;
  float* b2c  = smalls + 10752;
  float* g2c  = smalls + 11776;
  float* be2c = smalls + 12800;

  detect_kernel<<<1, 64, 0, stream>>>((const unsigned int*)x, flag);
  Ptr11 sml;
  sml.p[0] = bq; sml.p[1] = bk; sml.p[2] = bv; sml.p[3] = bo; sml.p[4] = rb;
  sml.p[5] = g1; sml.p[6] = be1; sml.p[7] = b1; sml.p[8] = b2; sml.p[9] = g2; sml.p[10] = be2;
  convert_small<<<1, 256, 0, stream>>>(sml, smalls, flag);
  lut_kernel<<<dim3(128), 256, 0, stream>>>(rbc, lut);

  if (FAST) {
    u16* xc   = (u16*)(ws + 0 * MB);
    u16* WqT  = (u16*)(ws + 8 * MB);
    u16* WkT  = WqT + 1048576;
    u16* WvT  = WqT + 2 * 1048576;
    u16* WoT  = WqT + 3 * 1048576;
    u16* qb   = (u16*)(ws + 16 * MB);
    u16* kb   = (u16*)(ws + 24 * MB);
    u16* vb   = (u16*)(ws + 32 * MB);
    u16* vtb  = (u16*)(ws + 40 * MB);
    u16* attb = (u16*)(ws + 32 * MB);
    u16* xo   = (u16*)(ws + 16 * MB);
    u16* hb   = (u16*)(ws + 48 * MB);
    u16* W1T  = (u16*)(ws + 8 * MB);
    u16* W2T  = (u16*)(ws + 0 * MB);
    u16* ff1  = (u16*)(ws + 16 * MB);
    u16* ff2o = (u16*)(ws + 8 * MB);

    convert_x<<<4096, 256, 0, stream>>>(x, xc, flag);
    TC4 tw; tw.in[0] = Wq; tw.in[1] = Wk; tw.in[2] = Wv; tw.in[3] = Wo;
    tw.out[0] = WqT; tw.out[1] = WkT; tw.out[2] = WvT; tw.out[3] = WoT;
    tconv_w4<<<dim3(16, 16, 4), 256, 0, stream>>>(tw, flag);

    // QKV: 8-phase 256^2 asm-barrier (R8 schedule), 192 blocks
    gemm256<0><<<dim3(4, 16, 3), 512, 0, stream>>>(xc, WqT, bqc, bkc, bvc, qb,
                                                   4096, 1024, 1024, 1024, 1048576L, 4194304L);
    transpose_generic<<<dim3(1, 16, 64), 256, 0, stream>>>(vb, vtb, 1024, 64);
    attn_fused<<<dim3(64, 16), 256, 0, stream>>>(qb, kb, vtb, mask, lut, attb);
    // Wo: double-buffered counted-vmcnt 128^2 (R10: R9 bugs fixed)
    gemm_btdb<0><<<dim3(8, 32, 1), 512, 0, stream>>>(attb, WoT, boc, boc, boc, xo,
                                                     4096, 1024, 1024, 0L, 0L);
    tconv_generic<<<dim3(64, 16), 256, 0, stream>>>(W1, W1T, 1024, 4096, flag);
    ln_kernel<0><<<dim3(4096), 256, 0, stream>>>(xo, xc, g1c, be1c, hb, flag);
    tconv_generic<<<dim3(16, 64), 256, 0, stream>>>(W2, W2T, 4096, 1024, flag);
    // FF1: 8-phase 256^2 asm-barrier (R8 schedule), 256 blocks
    gemm256<1><<<dim3(16, 16, 1), 512, 0, stream>>>(hb, W1T, b1c, b1c, b1c, ff1,
                                                    4096, 4096, 1024, 1024, 0L, 0L);
    // FF2: double-buffered counted-vmcnt 128^2 (R10: R9 bugs fixed; was
    // 81.5 us on the full-drain gemm_bt = the per-CU ingest wall)
    gemm_btdb<0><<<dim3(8, 32, 1), 512, 0, stream>>>(ff1, W2T, b2c, b2c, b2c, ff2o,
                                                     4096, 1024, 4096, 0L, 0L);
    ln_kernel<1><<<dim3(4096), 256, 0, stream>>>(ff2o, hb, g2c, be2c, d_out, flag);
  } else {
    u16* xc   = (u16*)(ws + 0 * MB);
    u16* WqT  = (u16*)(ws + 8 * MB);
    u16* WkT  = WqT + 1048576;
    u16* WvT  = WqT + 2 * 1048576;
    u16* WoT  = WqT + 3 * 1048576;
    u16* qb   = (u16*)(ws + 16 * MB);
    u16* kb   = (u16*)(ws + 24 * MB);
    u16* vb   = (u16*)(ws + 32 * MB);
    u16* vtb  = (u16*)(ws + 40 * MB);
    u16* attb = (u16*)(ws + 32 * MB);
    u16* xo   = (u16*)(ws + 16 * MB);
    u16* hb   = (u16*)(ws + 40 * MB);
    u16* ff1  = (u16*)(ws + 0 * MB);
    u16* ff2o = (u16*)(ws + 32 * MB);

    convert_x<<<4096, 256, 0, stream>>>(x, xc, flag);
    TC4 tw; tw.in[0] = Wq; tw.in[1] = Wk; tw.in[2] = Wv; tw.in[3] = Wo;
    tw.out[0] = WqT; tw.out[1] = WkT; tw.out[2] = WvT; tw.out[3] = WoT;
    tconv_w4<<<dim3(16, 16, 4), 256, 0, stream>>>(tw, flag);

    gemm_bt<0><<<dim3(8, 32, 3), 512, 0, stream>>>(xc, WqT, bqc, bkc, bvc, qb,
                                                   4096, 1024, 1024, 1048576L, 4194304L);
    transpose_generic<<<dim3(1, 16, 64), 256, 0, stream>>>(vb, vtb, 1024, 64);
    attn_fused<<<dim3(64, 16), 256, 0, stream>>>(qb, kb, vtb, mask, lut, attb);
    gemm_bt<0><<<dim3(8, 32, 1), 512, 0, stream>>>(attb, WoT, boc, boc, boc, xo,
                                                   4096, 1024, 1024, 0L, 0L);
    ln_kernel<0><<<dim3(4096), 256, 0, stream>>>(xo, xc, g1c, be1c, hb, flag);
    gemm_bn<1><<<dim3(32, 32), 256, 0, stream>>>(hb, W1, b1c, ff1, 4096, 4096, 1024, flag);
    gemm_bn<0><<<dim3(8, 32), 256, 0, stream>>>(ff1, W2, b2c, ff2o, 4096, 1024, 4096, flag);
    ln_kernel<1><<<dim3(4096), 256, 0, stream>>>(ff2o, hb, g2c, be2c, d_out, flag);
  }
}

// Round 11
// 395.323 us; speedup vs baseline: 1.2059x; 1.0321x over previous
//
#include <hip/hip_runtime.h>
#include <hip/hip_bf16.h>

typedef unsigned short u16;
typedef __attribute__((ext_vector_type(8))) short bhalf8;   // 8 bf16 = 16 B
typedef __attribute__((ext_vector_type(4))) float f32x4;
typedef __attribute__((address_space(3))) const char* LDSP;

#define DEV __device__ __forceinline__

DEV float bf2f(u16 u) { union { unsigned int i; float f; } c; c.i = ((unsigned int)u) << 16; return c.f; }
DEV u16 f2bf(float f) {
  union { float f; unsigned int i; } c; c.f = f;
  unsigned int x = c.i;
  x += 0x7fffu + ((x >> 16) & 1u);   // RNE
  return (u16)(x >> 16);
}

// async 16B global->LDS (wave-uniform LDS base + lane*16)
DEV void async16(const void* g, void* l) {
  __builtin_amdgcn_global_load_lds((__attribute__((address_space(1))) void*)g,
                                   (__attribute__((address_space(3))) void*)l, 16, 0, 0);
}

// opaque ds_read_b128 (no IR-visible LDS read -> no auto waits on it).
// NOTE: takes a BYTE offset.
#define LDSRD(dst, base, off) \
  asm volatile("ds_read_b128 %0, %1" : "=v"(dst) : "v"((LDSP)((const char*)(base) + (off))))

// RAW barrier, invisible to SIInsertWaitcnts' barrier handling. The builtin
// barrier gets a forced vmcnt flush when LDS-DMA writes are pending; the raw
// asm barrier avoids that. A/B-proven: gemm256 builtin 85us -> asm 62us.
#define BARRIER() asm volatile("s_barrier" ::: "memory")
#define SB0() __builtin_amdgcn_sched_barrier(0)

struct Ptr11 { const void* p[11]; };
struct TC4 { const void* in[4]; u16* out[4]; };

// ---------------------------------------------------------------------------
// dtype detector: bf16 -> low u16 of word is plausible bf16; fp32 -> mantissa.
// ---------------------------------------------------------------------------
__global__ void detect_kernel(const unsigned int* __restrict__ x, int* __restrict__ flag) {
  int t = threadIdx.x;
  int cnt = 0;
  for (int i = t; i < 256; i += 64) {
    unsigned int w = x[i];
    int e = (w >> 7) & 0xFF;
    if (e >= 96 && e <= 134) cnt++;
  }
#pragma unroll
  for (int o = 1; o < 64; o <<= 1) cnt += __shfl_xor(cnt, o, 64);
  if (t == 0) *flag = (cnt >= 192) ? 1 : 0;
}

DEV bhalf8 load8B(const void* base, size_t e, int isbf) {
  if (isbf) return *(const bhalf8*)((const u16*)base + e);
  const float* f = (const float*)base + e;
  float4 a = *(const float4*)f;
  float4 b = *(const float4*)(f + 4);
  bhalf8 r;
  r[0] = (short)f2bf(a.x); r[1] = (short)f2bf(a.y); r[2] = (short)f2bf(a.z); r[3] = (short)f2bf(a.w);
  r[4] = (short)f2bf(b.x); r[5] = (short)f2bf(b.y); r[6] = (short)f2bf(b.z); r[7] = (short)f2bf(b.w);
  return r;
}

__global__ __launch_bounds__(256) void convert_x(const void* __restrict__ x,
                                                 u16* __restrict__ dst,
                                                 const int* __restrict__ flag) {
  int c = blockIdx.x * 256 + threadIdx.x;
  u16* d = dst + (size_t)c * 4;
  if (*flag) {
    *(ushort4*)d = ((const ushort4*)x)[c];
  } else {
    float4 v = ((const float4*)x)[c];
    d[0] = f2bf(v.x); d[1] = f2bf(v.y); d[2] = f2bf(v.z); d[3] = f2bf(v.w);
  }
}

__global__ __launch_bounds__(256) void convert_small(Ptr11 s, float* __restrict__ dst,
                                                     const int* __restrict__ flag) {
  const int isbf = *flag;
  const int SZ[11] = {1024,1024,1024,1024,512,1024,1024,4096,1024,1024,1024};
  for (int i = threadIdx.x; i < 13824; i += 256) {
    int acc = 0, seg = -1, off = 0;
#pragma unroll
    for (int s2 = 0; s2 < 11; ++s2) {
      if (seg < 0 && i < acc + SZ[s2]) { seg = s2; off = i - acc; }
      acc += SZ[s2];
    }
    dst[i] = isbf ? bf2f(((const u16*)s.p[seg])[off]) : ((const float*)s.p[seg])[off];
  }
}

// ---------------------------------------------------------------------------
// transpose+convert: out[C,R] (bf16) = in[R,C]^T (raw dtype per flag)
// ---------------------------------------------------------------------------
DEV void tconv_tile(const void* in, u16* out, int R, int C, int isbf) {
  __shared__ __align__(16) u16 tile[64][72];
  const int t = threadIdx.x;
  const int c0 = blockIdx.x * 64, r0 = blockIdx.y * 64;
#pragma unroll
  for (int r = 0; r < 2; ++r) {
    int idx = r * 256 + t;
    int ri = idx >> 3, cc = (idx & 7) * 8;
    bhalf8 v = load8B(in, (size_t)(r0 + ri) * C + c0 + cc, isbf);
    *(bhalf8*)(&tile[ri][cc]) = v;
  }
  __syncthreads();
#pragma unroll
  for (int r = 0; r < 2; ++r) {
    int idx = r * 256 + t;
    int co = idx >> 3, rc = (idx & 7) * 8;
    bhalf8 v;
#pragma unroll
    for (int ii = 0; ii < 8; ++ii) v[ii] = (short)tile[rc + ii][co];
    *(bhalf8*)(out + (size_t)(c0 + co) * R + r0 + rc) = v;
  }
}

__global__ __launch_bounds__(256) void tconv_w4(TC4 p, const int* __restrict__ flag) {
  int z = blockIdx.z;
  tconv_tile(p.in[z], p.out[z], 1024, 1024, *flag);
}

__global__ __launch_bounds__(256) void tconv_generic(const void* in, u16* out, int R, int C,
                                                     const int* __restrict__ flag) {
  tconv_tile(in, out, R, C, *flag);
}

__global__ __launch_bounds__(256) void transpose_generic(const u16* in, u16* out, int R, int C) {
  __shared__ __align__(16) u16 tile[64][72];
  const int t = threadIdx.x;
  const int c0 = blockIdx.x * 64, r0 = blockIdx.y * 64;
  size_t bs = (size_t)R * C * blockIdx.z;
#pragma unroll
  for (int r = 0; r < 2; ++r) {
    int idx = r * 256 + t;
    int ri = idx >> 3, cc = (idx & 7) * 8;
    *(bhalf8*)(&tile[ri][cc]) = *(const bhalf8*)(in + bs + (size_t)(r0 + ri) * C + c0 + cc);
  }
  __syncthreads();
#pragma unroll
  for (int r = 0; r < 2; ++r) {
    int idx = r * 256 + t;
    int co = idx >> 3, rc = (idx & 7) * 8;
    bhalf8 v;
#pragma unroll
    for (int ii = 0; ii < 8; ++ii) v[ii] = (short)tile[rc + ii][co];
    *(bhalf8*)(out + bs + (size_t)(c0 + co) * R + r0 + rc) = v;
  }
}

// ---------------------------------------------------------------------------
// 8-phase 256x256 GEMM (B^T input), asm-barrier, 4-barriers-per-K-tile (R8
// schedule, verified R8). Counted vmcnt(6) at K-tile boundary only.
// blockIdx.z selects the (BT, bias, C) triple (QKV batching).
// ---------------------------------------------------------------------------
#define MFMA_BF16(a, b, c) __builtin_amdgcn_mfma_f32_16x16x32_bf16(a, b, c, 0, 0, 0)

template<int RELU>
__global__ __launch_bounds__(512) void gemm256(
    const u16* __restrict__ A, const u16* __restrict__ BT0,
    const float* __restrict__ b0, const float* __restrict__ b1, const float* __restrict__ b2,
    u16* __restrict__ C0, int M, int N, int ldk, int kext, long sBT, long sC)
{
  __shared__ __align__(16) u16 A0h0[8192], A0h1[8192], A1h0[8192], A1h1[8192];
  __shared__ __align__(16) u16 B0h0[8192], B0h1[8192], B1h0[8192], B1h1[8192];
  (void)M;

  const int t = threadIdx.x;
  const int wv = t >> 6, l = t & 63;
  const int wm = wv >> 2, wn = wv & 3;
  const int z = blockIdx.z;

  // XCD-aware bijective swizzle (nwg%8==0 at all call sites).
  const int gx = gridDim.x;
  const int nwg = gx * gridDim.y;
  int wgid = blockIdx.y * gx + blockIdx.x;
  wgid = (wgid & 7) * (nwg >> 3) + (wgid >> 3);
  const int m0 = (wgid / gx) * 256, n0 = (wgid % gx) * 256;

  const u16* BT = BT0 + (long)z * sBT;
  const float* bias = (z == 0) ? b0 : (z == 1 ? b1 : b2);
  u16* C = C0 + (long)z * sC;

  const int ri = t >> 3;
  const int slc8 = (((t & 7) ^ (ri & 7)) << 3);
  const u16* agp = A + (size_t)(m0 + ri) * ldk + slc8;
  const int rB = ((ri >> 5) << 6) | (ri & 31);
  const u16* bgp = BT + (size_t)(n0 + rB) * ldk + slc8;

#define STGA(ARR, h, j, kt) async16(agp + (size_t)((j) * 128 + (h) * 64) * ldk + (size_t)(kt) * 64, \
                                    (char*)(ARR) + (j) * 8192 + wv * 1024)
#define STGB(ARR, h, j, kt) async16(bgp + (size_t)((j) * 128 + (h) * 32) * ldk + (size_t)(kt) * 64, \
                                    (char*)(ARR) + (j) * 8192 + wv * 1024)

  int offA[4][2], offB[2][2];
#pragma unroll
  for (int mi = 0; mi < 4; ++mi)
#pragma unroll
    for (int s = 0; s < 2; ++s)
      offA[mi][s] = wm * 8192 + (mi * 16 + (l & 15)) * 128 + ((((s << 2) + (l >> 4)) ^ (l & 7)) << 4);
#pragma unroll
  for (int nj = 0; nj < 2; ++nj)
#pragma unroll
    for (int s = 0; s < 2; ++s)
      offB[nj][s] = wn * 4096 + (nj * 16 + (l & 15)) * 128 + ((((s << 2) + (l >> 4)) ^ (l & 7)) << 4);

  const int NT = kext >> 6;   // even (all call sites: 16)
  f32x4 acc[8][4] = {};

  // prologue: tile0 all 4 half-tiles (buf0) + tile1 first 3 (buf1)
  STGA(A0h0, 0, 0, 0); STGA(A0h0, 0, 1, 0);
  STGB(B0h0, 0, 0, 0); STGB(B0h0, 0, 1, 0);
  STGB(B0h1, 1, 0, 0); STGB(B0h1, 1, 1, 0);
  STGA(A0h1, 1, 0, 0); STGA(A0h1, 1, 1, 0);
  if (NT > 1) {
    STGA(A1h0, 0, 0, 1); STGA(A1h0, 0, 1, 1);
    STGB(B1h0, 0, 0, 1); STGB(B1h0, 0, 1, 1);
    STGB(B1h1, 1, 0, 1); STGB(B1h1, 1, 1, 1);
    asm volatile("s_waitcnt vmcnt(6)" ::: "memory");
  } else {
    asm volatile("s_waitcnt vmcnt(0)" ::: "memory");
  }
  BARRIER();

#define ITER(TT, CA0, CA1, CB0, CB1, NA1)                                        \
  {                                                                              \
    bhalf8 af[4][2], p0[2][2], p1[2][2];                                         \
    _Pragma("unroll") for (int mi = 0; mi < 4; ++mi)                             \
      _Pragma("unroll") for (int s = 0; s < 2; ++s)                              \
        LDSRD(af[mi][s], CA0, offA[mi][s]);                                      \
    _Pragma("unroll") for (int nj = 0; nj < 2; ++nj)                             \
      _Pragma("unroll") for (int s = 0; s < 2; ++s)                              \
        LDSRD(p0[nj][s], CB0, offB[nj][s]);                                      \
    BARRIER();                                                                   \
    asm volatile("s_waitcnt lgkmcnt(0)" ::: "memory");                           \
    SB0();                                                                       \
    if ((TT) + 1 < NT) { STGA(NA1, 1, 0, (TT) + 1); STGA(NA1, 1, 1, (TT) + 1); } \
    SB0();                                                                       \
    __builtin_amdgcn_s_setprio(1);                                               \
    _Pragma("unroll") for (int mi = 0; mi < 4; ++mi)                             \
      _Pragma("unroll") for (int nj = 0; nj < 2; ++nj) {                         \
        acc[mi][nj] = MFMA_BF16(af[mi][0], p0[nj][0], acc[mi][nj]);              \
        acc[mi][nj] = MFMA_BF16(af[mi][1], p0[nj][1], acc[mi][nj]);              \
      }                                                                          \
    __builtin_amdgcn_s_setprio(0);                                               \
    _Pragma("unroll") for (int nj = 0; nj < 2; ++nj)                             \
      _Pragma("unroll") for (int s = 0; s < 2; ++s)                              \
        LDSRD(p1[nj][s], CB1, offB[nj][s]);                                      \
    BARRIER();                                                                   \
    asm volatile("s_waitcnt lgkmcnt(0)" ::: "memory");                           \
    SB0();                                                                       \
    if ((TT) + 2 < NT) { STGA(CA0, 0, 0, (TT) + 2); STGA(CA0, 0, 1, (TT) + 2); } \
    SB0();                                                                       \
    __builtin_amdgcn_s_setprio(1);                                               \
    _Pragma("unroll") for (int mi = 0; mi < 4; ++mi)                             \
      _Pragma("unroll") for (int nj = 0; nj < 2; ++nj) {                         \
        acc[mi][2 + nj] = MFMA_BF16(af[mi][0], p1[nj][0], acc[mi][2 + nj]);      \
        acc[mi][2 + nj] = MFMA_BF16(af[mi][1], p1[nj][1], acc[mi][2 + nj]);      \
      }                                                                          \
    __builtin_amdgcn_s_setprio(0);                                               \
    _Pragma("unroll") for (int mi = 0; mi < 4; ++mi)                             \
      _Pragma("unroll") for (int s = 0; s < 2; ++s)                              \
        LDSRD(af[mi][s], CA1, offA[mi][s]);                                      \
    BARRIER();                                                                   \
    asm volatile("s_waitcnt lgkmcnt(0)" ::: "memory");                           \
    SB0();                                                                       \
    if ((TT) + 2 < NT) { STGB(CB0, 0, 0, (TT) + 2); STGB(CB0, 0, 1, (TT) + 2); } \
    SB0();                                                                       \
    __builtin_amdgcn_s_setprio(1);                                               \
    _Pragma("unroll") for (int mi = 0; mi < 4; ++mi)                             \
      _Pragma("unroll") for (int nj = 0; nj < 2; ++nj) {                         \
        acc[4 + mi][2 + nj] = MFMA_BF16(af[mi][0], p1[nj][0], acc[4 + mi][2 + nj]); \
        acc[4 + mi][2 + nj] = MFMA_BF16(af[mi][1], p1[nj][1], acc[4 + mi][2 + nj]); \
      }                                                                          \
    __builtin_amdgcn_s_setprio(0);                                               \
    if ((TT) + 2 < NT) { STGB(CB1, 1, 0, (TT) + 2); STGB(CB1, 1, 1, (TT) + 2); } \
    SB0();                                                                       \
    __builtin_amdgcn_s_setprio(1);                                               \
    _Pragma("unroll") for (int mi = 0; mi < 4; ++mi)                             \
      _Pragma("unroll") for (int nj = 0; nj < 2; ++nj) {                         \
        acc[4 + mi][nj] = MFMA_BF16(af[mi][0], p0[nj][0], acc[4 + mi][nj]);      \
        acc[4 + mi][nj] = MFMA_BF16(af[mi][1], p0[nj][1], acc[4 + mi][nj]);      \
      }                                                                          \
    __builtin_amdgcn_s_setprio(0);                                               \
    SB0();                                                                       \
    if ((TT) < NT - 2)       asm volatile("s_waitcnt vmcnt(6)" ::: "memory");    \
    else if ((TT) == NT - 2) asm volatile("s_waitcnt vmcnt(0)" ::: "memory");    \
    BARRIER();                                                                   \
  }

  for (int tt = 0; tt < NT; tt += 2) {
    ITER(tt,     A0h0, A0h1, B0h0, B0h1, A1h1);
    ITER(tt + 1, A1h0, A1h1, B1h0, B1h1, A0h1);
  }
#undef ITER
#undef STGA
#undef STGB

  const int lr = (l >> 4) << 2, lcc = l & 15;
#pragma unroll
  for (int nj = 0; nj < 4; ++nj) {
    int col = n0 + wn * 64 + nj * 16 + lcc;
    float bb = bias[col];
#pragma unroll
    for (int mi = 0; mi < 8; ++mi) {
#pragma unroll
      for (int r = 0; r < 4; ++r) {
        int row = m0 + wm * 128 + mi * 16 + lr + r;
        float v = acc[mi][nj][r] + bb;
        if (RELU) v = fmaxf(v, 0.0f);
        C[(size_t)row * N + col] = f2bf(v);
      }
    }
  }
}

// ---------------------------------------------------------------------------
// Double-buffered 128x128 GEMM (B^T input), counted vmcnt(2). R10-verified:
// broke the full-drain ingest wall (FF2 81.5 -> <69 us, Wo 21 -> ~12).
// ---------------------------------------------------------------------------
template<int RELU>
__global__ __launch_bounds__(512) void gemm_btdb(
    const u16* __restrict__ A, const u16* __restrict__ BT0,
    const float* __restrict__ b0, const float* __restrict__ b1, const float* __restrict__ b2,
    u16* __restrict__ C0, int M, int N, int K, long sBT, long sC)
{
  __shared__ __align__(16) u16 ldsA0[4096], ldsA1[4096];
  __shared__ __align__(16) u16 ldsB0[4096], ldsB1[4096];

  const int t = threadIdx.x;
  const int wv = t >> 6, l = t & 63;
  const int wm = wv >> 2, wn = wv & 3;
  const int m0 = blockIdx.y * 128, n0 = blockIdx.x * 128;
  const int z = blockIdx.z;

  const u16* BT = BT0 + (long)z * sBT;
  const float* bias = (z == 0) ? b0 : (z == 1 ? b1 : b2);
  u16* C = C0 + (long)z * sC;

  // staging: slot t -> (row t>>2, global chunk (t&3)^((t>>4)&3))
  const int mm_s = t >> 2, kc_s = (t & 3) ^ ((t >> 4) & 3);
  const u16* agp = A + (size_t)(m0 + mm_s) * K + kc_s * 8;
  const u16* bgp = BT + (size_t)(n0 + mm_s) * K + kc_s * 8;
  char* la0 = (char*)ldsA0 + wv * 1024;
  char* la1 = (char*)ldsA1 + wv * 1024;
  char* lb0 = (char*)ldsB0 + wv * 1024;
  char* lb1 = (char*)ldsB1 + wv * 1024;

  // BYTE offsets for LDSRD
  int a_off[4], b_off[2];
#pragma unroll
  for (int i = 0; i < 4; ++i) {
    int mm = wm * 64 + i * 16 + (l & 15);
    a_off[i] = (mm * 4 + ((l >> 4) ^ ((mm >> 2) & 3))) * 16;
  }
#pragma unroll
  for (int j = 0; j < 2; ++j) {
    int nn = wn * 32 + j * 16 + (l & 15);
    b_off[j] = (nn * 4 + ((l >> 4) ^ ((nn >> 2) & 3))) * 16;
  }

  f32x4 acc[4][2] = {};

  // prologue: tiles 0 (buf0) and 1 (buf1). K is a multiple of 64 (1024/4096).
  async16(agp + 0, la0);  async16(bgp + 0, lb0);
  async16(agp + 32, la1); async16(bgp + 32, lb1);

#define DBITER(KT, CA, CB, LA, LB)                                               \
  {                                                                              \
    if ((KT) + 32 >= K) asm volatile("s_waitcnt vmcnt(0)" ::: "memory");         \
    else                asm volatile("s_waitcnt vmcnt(2)" ::: "memory");         \
    BARRIER();                                                                   \
    bhalf8 af[4], bfr[2];                                                        \
    _Pragma("unroll") for (int i = 0; i < 4; ++i) LDSRD(af[i], CA, a_off[i]);    \
    _Pragma("unroll") for (int j = 0; j < 2; ++j) LDSRD(bfr[j], CB, b_off[j]);   \
    asm volatile("s_waitcnt lgkmcnt(0)" ::: "memory");                           \
    SB0();                                                                       \
    BARRIER();                                                                   \
    if ((KT) + 64 < K) { async16(agp + (KT) + 64, LA); async16(bgp + (KT) + 64, LB); } \
    SB0();                                                                       \
    __builtin_amdgcn_s_setprio(1);                                               \
    _Pragma("unroll") for (int mi = 0; mi < 4; ++mi)                             \
      _Pragma("unroll") for (int nj = 0; nj < 2; ++nj)                           \
        acc[mi][nj] = MFMA_BF16(af[mi], bfr[nj], acc[mi][nj]);                   \
    __builtin_amdgcn_s_setprio(0);                                               \
  }

  for (int kt = 0; kt < K; kt += 64) {
    DBITER(kt,      ldsA0, ldsB0, la0, lb0);
    DBITER(kt + 32, ldsA1, ldsB1, la1, lb1);
  }
#undef DBITER

  const int lr = (l >> 4) << 2, lc = l & 15;
#pragma unroll
  for (int nj = 0; nj < 2; ++nj) {
    int col = n0 + wn * 32 + nj * 16 + lc;
    float bb = bias[col];
#pragma unroll
    for (int mi = 0; mi < 4; ++mi) {
#pragma unroll
      for (int r = 0; r < 4; ++r) {
        int row = m0 + wm * 64 + mi * 16 + lr + r;
        float v = acc[mi][nj][r] + bb;
        if (RELU) v = fmaxf(v, 0.0f);
        C[(size_t)row * N + col] = f2bf(v);
      }
    }
  }
}

// ---------------------------------------------------------------------------
// GEMM (B^T input), m97-style 128x128 2-phase: proven fallback.
// ---------------------------------------------------------------------------
template<int RELU>
__global__ __launch_bounds__(512) void gemm_bt(
    const u16* __restrict__ A, const u16* __restrict__ BT0,
    const float* __restrict__ b0, const float* __restrict__ b1, const float* __restrict__ b2,
    u16* __restrict__ C0, int M, int N, int K, long sBT, long sC)
{
  __shared__ __align__(16) u16 ldsA[128 * 32];
  __shared__ __align__(16) u16 ldsB[128 * 32];

  const int t = threadIdx.x;
  const int wv = t >> 6, l = t & 63;
  const int wm = wv >> 2, wn = wv & 3;
  const int m0 = blockIdx.y * 128, n0 = blockIdx.x * 128;
  const int z = blockIdx.z;

  const u16* BT = BT0 + (long)z * sBT;
  const float* bias = (z == 0) ? b0 : (z == 1 ? b1 : b2);
  u16* C = C0 + (long)z * sC;

  const int mm_s = t >> 2, kc_s = (t & 3) ^ ((t >> 4) & 3);
  const u16* agp = A + (size_t)(m0 + mm_s) * K + kc_s * 8;
  const u16* bgp = BT + (size_t)(n0 + mm_s) * K + kc_s * 8;
  char* la = (char*)ldsA + wv * 1024;
  char* lb = (char*)ldsB + wv * 1024;

  int a_off[4], b_off[2];
#pragma unroll
  for (int i = 0; i < 4; ++i) {
    int mm = wm * 64 + i * 16 + (l & 15);
    a_off[i] = (mm * 4 + ((l >> 4) ^ ((mm >> 2) & 3))) * 8;
  }
#pragma unroll
  for (int j = 0; j < 2; ++j) {
    int nn = wn * 32 + j * 16 + (l & 15);
    b_off[j] = (nn * 4 + ((l >> 4) ^ ((nn >> 2) & 3))) * 8;
  }

  f32x4 acc[4][2] = {};

  for (int kt = 0; kt < K; kt += 32) {
    __syncthreads();
    async16(agp + kt, la);
    async16(bgp + kt, lb);
    __syncthreads();

    bhalf8 af[4], bfr[2];
#pragma unroll
    for (int i = 0; i < 4; ++i) af[i] = *(const bhalf8*)(ldsA + a_off[i]);
#pragma unroll
    for (int j = 0; j < 2; ++j) bfr[j] = *(const bhalf8*)(ldsB + b_off[j]);
#pragma unroll
    for (int mi = 0; mi < 4; ++mi)
#pragma unroll
      for (int nj = 0; nj < 2; ++nj)
        acc[mi][nj] = __builtin_amdgcn_mfma_f32_16x16x32_bf16(af[mi], bfr[nj], acc[mi][nj], 0, 0, 0);
  }

  const int lr = (l >> 4) << 2, lc = l & 15;
#pragma unroll
  for (int nj = 0; nj < 2; ++nj) {
    int col = n0 + wn * 32 + nj * 16 + lc;
    float bb = bias[col];
#pragma unroll
    for (int mi = 0; mi < 4; ++mi) {
#pragma unroll
      for (int r = 0; r < 4; ++r) {
        int row = m0 + wm * 64 + mi * 16 + lr + r;
        float v = acc[mi][nj][r] + bb;
        if (RELU) v = fmaxf(v, 0.0f);
        C[(size_t)row * N + col] = f2bf(v);
      }
    }
  }
}

// ---------------------------------------------------------------------------
// FALLBACK GEMM (natural raw B): C = A[M,K] @ B[K,N] + bias. (R5-proven.)
// ---------------------------------------------------------------------------
template<int RELU>
__global__ __launch_bounds__(256) void gemm_bn(
    const u16* __restrict__ A, const void* __restrict__ B,
    const float* __restrict__ bias, u16* __restrict__ C, int M, int N, int K,
    const int* __restrict__ flag)
{
  __shared__ __align__(16) u16 ldsA[128][40];
  __shared__ __align__(16) u16 ldsB[128][40];

  const int isbf = *flag;
  const int t = threadIdx.x;
  const int wv = t >> 6, l = t & 63;
  const int wm = wv & 1, wn = wv >> 1;
  const int m0 = blockIdx.y * 128, n0 = blockIdx.x * 128;

  const int srow = t >> 1, scol = (t & 1) * 16;
  const u16* agp = A + (size_t)(m0 + srow) * K + scol;

  const int kk = t >> 3;
  const int nn = (t & 7) * 16;

  f32x4 acc[4][4] = {};

  for (int kt = 0; kt < K; kt += 32) {
    bhalf8 a0 = *(const bhalf8*)(agp + kt);
    bhalf8 a1 = *(const bhalf8*)(agp + kt + 8);
    size_t e0 = (size_t)(kt + kk) * N + n0 + nn;
    bhalf8 b0v = load8B(B, e0, isbf);
    bhalf8 b1v = load8B(B, e0 + 8, isbf);
    __syncthreads();
    *(bhalf8*)(&ldsA[srow][scol])     = a0;
    *(bhalf8*)(&ldsA[srow][scol + 8]) = a1;
#pragma unroll
    for (int j = 0; j < 8; ++j) ldsB[nn + j][kk]     = (u16)b0v[j];
#pragma unroll
    for (int j = 0; j < 8; ++j) ldsB[nn + 8 + j][kk] = (u16)b1v[j];
    __syncthreads();

    bhalf8 af[4], bfr[4];
#pragma unroll
    for (int i = 0; i < 4; ++i)
      af[i] = *(const bhalf8*)(&ldsA[wm * 64 + i * 16 + (l & 15)][(l >> 4) * 8]);
#pragma unroll
    for (int i = 0; i < 4; ++i)
      bfr[i] = *(const bhalf8*)(&ldsB[wn * 64 + i * 16 + (l & 15)][(l >> 4) * 8]);
#pragma unroll
    for (int mi = 0; mi < 4; ++mi)
#pragma unroll
      for (int ni = 0; ni < 4; ++ni)
        acc[mi][ni] = __builtin_amdgcn_mfma_f32_16x16x32_bf16(af[mi], bfr[ni], acc[mi][ni], 0, 0, 0);
  }

  const int lr = (l >> 4) << 2, lc = l & 15;
#pragma unroll
  for (int ni = 0; ni < 4; ++ni) {
    int col = n0 + wn * 64 + ni * 16 + lc;
    float bb = bias[col];
#pragma unroll
    for (int mi = 0; mi < 4; ++mi) {
#pragma unroll
      for (int r = 0; r < 4; ++r) {
        int row = m0 + wm * 64 + mi * 16 + lr + r;
        float v = acc[mi][ni][r] + bb;
        if (RELU) v = fmaxf(v, 0.0f);
        C[(size_t)row * N + col] = f2bf(v);
      }
    }
  }
}

// ---------------------------------------------------------------------------
// T5 bias LUT, pre-scaled for max-free softmax:
// lut = (bias - 12) * log2(e); softmax shift-invariance cancels the -12.
// ---------------------------------------------------------------------------
__global__ __launch_bounds__(256) void lut_kernel(const float* __restrict__ rbc, float* __restrict__ lut) {
  int idx = blockIdx.x * 256 + threadIdx.x;
  if (idx >= 16 * 2047) return;
  int h = idx / 2047;
  int dp = idx - h * 2047;
  int delta = dp - 1023;      // rel_pos = i - j
  int n = -delta;
  int ret = 0;
  if (n < 0) { ret = 16; n = -n; }
  int bkt;
  if (n < 8) bkt = n;
  else {
    float v = logf((float)n * 0.125f) / logf(16.0f) * 8.0f;
    bkt = 8 + (int)v;
    if (bkt > 15) bkt = 15;
  }
  lut[idx] = (rbc[(ret + bkt) * 16 + h] - 12.0f) * 1.44269504f;
}

// ---------------------------------------------------------------------------
// Flash attention, max-free softmax: p = 2^(score*log2e + lut' + pad'),
// per-lane partial row sums, one shuffle reduction at block end.
// R11: Q-staging LDS and P-scratch LDS are ALIASED (both 64x72 u16 = 9216 B;
// Q region is dead after the pre-loop qf fragment loads). The extra
// __syncthreads after the qf reads (compiler emits lgkmcnt(0) before the
// barrier) guarantees every wave's Q reads completed before any wave's
// first P write. P rows [wv*16, wv*16+16) are wave-private (same wave
// writes then reads them; DS pipe is in-order per wave).
// LDS: 45568 -> 36352 B => 4 blocks/CU (was 3) on a 1024-block grid.
// ---------------------------------------------------------------------------
__global__ __launch_bounds__(256) void attn_fused(
    const u16* __restrict__ q, const u16* __restrict__ k, const u16* __restrict__ vt,
    const int* __restrict__ mask, const float* __restrict__ lut, u16* __restrict__ att)
{
  __shared__ __align__(16) u16 ldsQP[64][72];  // Q staging, then P scratch
  __shared__ __align__(16) u16 ldsK[64][72];
  __shared__ __align__(16) u16 ldsV[64][72];   // row = head-dim e, col = seq j
  __shared__ float ldsLut[2047];
  __shared__ float ldsPad[64];

  const int t = threadIdx.x;
  const int wv = t >> 6, l = t & 63;
  const int bh = blockIdx.x, qt = blockIdx.y;
  const int b = bh >> 4, h = bh & 15;
  const size_t base = (size_t)bh * 65536;
  const int q0 = qt * 64;

  for (int i = t; i < 2047; i += 256) ldsLut[i] = lut[h * 2047 + i];

  const int sr = t >> 2, sc = (t & 3) * 16;
  {
    bhalf8 q0v = *(const bhalf8*)(q + base + (size_t)(q0 + sr) * 64 + sc);
    bhalf8 q1v = *(const bhalf8*)(q + base + (size_t)(q0 + sr) * 64 + sc + 8);
    *(bhalf8*)(&ldsQP[sr][sc])     = q0v;
    *(bhalf8*)(&ldsQP[sr][sc + 8]) = q1v;
  }
  __syncthreads();

  bhalf8 qf[2];
  {
    int mm = wv * 16 + (l & 15);
#pragma unroll
    for (int s = 0; s < 2; ++s)
      qf[s] = *(const bhalf8*)(&ldsQP[mm][s * 32 + (l >> 4) * 8]);
  }
  __syncthreads();   // all waves' Q reads complete before P writes reuse buffer

  float ls_part[4] = {0.0f, 0.0f, 0.0f, 0.0f};
  f32x4 acc_o[4] = {};

  const int* mrow = mask + b * 1024;

  for (int kt = 0; kt < 16; ++kt) {
    const int k0 = kt * 64;
    bhalf8 k0v = *(const bhalf8*)(k + base + (size_t)(k0 + sr) * 64 + sc);
    bhalf8 k1v = *(const bhalf8*)(k + base + (size_t)(k0 + sr) * 64 + sc + 8);
    bhalf8 v0v = *(const bhalf8*)(vt + base + (size_t)sr * 1024 + k0 + sc);
    bhalf8 v1v = *(const bhalf8*)(vt + base + (size_t)sr * 1024 + k0 + sc + 8);
    __syncthreads();
    *(bhalf8*)(&ldsK[sr][sc])     = k0v;
    *(bhalf8*)(&ldsK[sr][sc + 8]) = k1v;
    *(bhalf8*)(&ldsV[sr][sc])     = v0v;
    *(bhalf8*)(&ldsV[sr][sc + 8]) = v1v;
    if (t < 64) {
      int mv = mrow[k0 + t];
      ldsPad[t] = (mv > 0) ? __log2f((float)mv) : -1e30f;
    }
    __syncthreads();

    // S = Q K^T  (16x64 per wave)
    f32x4 accS[4] = {};
#pragma unroll
    for (int s = 0; s < 2; ++s) {
#pragma unroll
      for (int ni = 0; ni < 4; ++ni) {
        int nnj = ni * 16 + (l & 15);
        bhalf8 kf = *(const bhalf8*)(&ldsK[nnj][s * 32 + (l >> 4) * 8]);
        accS[ni] = __builtin_amdgcn_mfma_f32_16x16x32_bf16(qf[s], kf, accS[ni], 0, 0, 0);
      }
    }

    // max-free softmax: p = 2^(s*log2e + lut' + pad')
    float padv[4];
#pragma unroll
    for (int ni = 0; ni < 4; ++ni) padv[ni] = ldsPad[ni * 16 + (l & 15)];
    const int ib = q0 + wv * 16 + ((l >> 4) << 2);
#pragma unroll
    for (int r = 0; r < 4; ++r) {
      int i_l = ((l >> 4) << 2) + r;
#pragma unroll
      for (int ni = 0; ni < 4; ++ni) {
        int j_l = ni * 16 + (l & 15);
        float s = fmaf(accS[ni][r], 1.44269504f, ldsLut[(ib + r) - (k0 + j_l) + 1023]) + padv[ni];
        float p = exp2f(s);
        ls_part[r] += p;
        ldsQP[wv * 16 + i_l][j_l] = f2bf(p);
      }
    }

    // O += P V (per-wave LDS round-trip: C-layout -> A-layout)
#pragma unroll
    for (int s = 0; s < 2; ++s) {
      int mm = l & 15;
      bhalf8 pf = *(const bhalf8*)(&ldsQP[wv * 16 + mm][s * 32 + (l >> 4) * 8]);
#pragma unroll
      for (int ni = 0; ni < 4; ++ni) {
        int e = ni * 16 + (l & 15);
        bhalf8 vf = *(const bhalf8*)(&ldsV[e][s * 32 + (l >> 4) * 8]);
        acc_o[ni] = __builtin_amdgcn_mfma_f32_16x16x32_bf16(pf, vf, acc_o[ni], 0, 0, 0);
      }
    }
  }

  // row-sum reduction across the 16 lanes of each quad-row group
#pragma unroll
  for (int r = 0; r < 4; ++r) {
#pragma unroll
    for (int off = 1; off < 16; off <<= 1) ls_part[r] += __shfl_xor(ls_part[r], off, 64);
    ls_part[r] = 1.0f / ls_part[r];
  }

#pragma unroll
  for (int ni = 0; ni < 4; ++ni) {
#pragma unroll
    for (int r = 0; r < 4; ++r) {
      int i = q0 + wv * 16 + ((l >> 4) << 2) + r;
      int e = ni * 16 + (l & 15);
      att[base + (size_t)i * 64 + e] = f2bf(acc_o[ni][r] * ls_part[r]);
    }
  }
}

// ---------------------------------------------------------------------------
// LayerNorm(x + res) * g + b. LAST=1 writes d_out as fp32/bf16 per flag.
// ---------------------------------------------------------------------------
template<int LAST>
__global__ __launch_bounds__(256) void ln_kernel(
    const u16* __restrict__ x, const u16* __restrict__ res,
    const float* __restrict__ g, const float* __restrict__ b,
    void* __restrict__ out, const int* __restrict__ flag)
{
  const int row = blockIdx.x, t = threadIdx.x;
  const size_t off = (size_t)row * 1024 + t * 4;
  ushort4 xv = *(const ushort4*)(x + off);
  ushort4 rv = *(const ushort4*)(res + off);
  float v0 = bf2f(xv.x) + bf2f(rv.x);
  float v1 = bf2f(xv.y) + bf2f(rv.y);
  float v2 = bf2f(xv.z) + bf2f(rv.z);
  float v3 = bf2f(xv.w) + bf2f(rv.w);
  float s = v0 + v1 + v2 + v3;
  float sq = v0 * v0 + v1 * v1 + v2 * v2 + v3 * v3;
#pragma unroll
  for (int o = 1; o < 64; o <<= 1) { s += __shfl_xor(s, o, 64); sq += __shfl_xor(sq, o, 64); }
  __shared__ float red[8];
  const int wv = t >> 6, l = t & 63;
  if (l == 0) { red[wv] = s; red[4 + wv] = sq; }
  __syncthreads();
  s = red[0] + red[1] + red[2] + red[3];
  sq = red[4] + red[5] + red[6] + red[7];
  float mu = s * 0.0009765625f;
  float var = sq * 0.0009765625f - mu * mu;
  float rstd = rsqrtf(var + 1e-5f);
  float4 gv = *(const float4*)(g + t * 4);
  float4 bv = *(const float4*)(b + t * 4);
  float o0 = gv.x * (v0 - mu) * rstd + bv.x;
  float o1 = gv.y * (v1 - mu) * rstd + bv.y;
  float o2 = gv.z * (v2 - mu) * rstd + bv.z;
  float o3 = gv.w * (v3 - mu) * rstd + bv.w;
  if (!LAST) {
    ushort4 ov; ov.x = f2bf(o0); ov.y = f2bf(o1); ov.z = f2bf(o2); ov.w = f2bf(o3);
    *(ushort4*)((u16*)out + off) = ov;
  } else {
    if (*flag) {
      ushort4 ov; ov.x = f2bf(o0); ov.y = f2bf(o1); ov.z = f2bf(o2); ov.w = f2bf(o3);
      *(ushort4*)((u16*)out + off) = ov;
    } else {
      float4 ov; ov.x = o0; ov.y = o1; ov.z = o2; ov.w = o3;
      *(float4*)((float*)out + off) = ov;
    }
  }
}

// ---------------------------------------------------------------------------
extern "C" void kernel_launch(void* const* d_in, const int* in_sizes, int n_in,
                              void* d_out, int out_size, void* d_ws, size_t ws_size,
                              hipStream_t stream) {
  const void* x  = d_in[0];
  const int* mask = (const int*)d_in[1];
  const void* Wq = d_in[2];  const void* bq = d_in[3];
  const void* Wk = d_in[4];  const void* bk = d_in[5];
  const void* Wv = d_in[6];  const void* bv = d_in[7];
  const void* Wo = d_in[8];  const void* bo = d_in[9];
  const void* rb = d_in[10];
  const void* g1 = d_in[11]; const void* be1 = d_in[12];
  const void* W1 = d_in[13]; const void* b1 = d_in[14];
  const void* W2 = d_in[15]; const void* b2 = d_in[16];
  const void* g2 = d_in[17]; const void* be2 = d_in[18];

  char* ws = (char*)d_ws;
  const size_t MB = 1024 * 1024;
  const bool FAST = (ws_size >= 57 * MB);

  const size_t TAIL = FAST ? 56 * MB : 48 * MB;
  float* smalls = (float*)(ws + TAIL);
  float* lut    = (float*)(ws + TAIL + 56 * 1024);
  int*   flag   = (int*)(ws + TAIL + 192 * 1024);

  float* bqc  = smalls + 0;
  float* bkc  = smalls + 1024;
  float* bvc  = smalls + 2048;
  float* boc  = smalls + 3072;
  float* rbc  = smalls + 4096;
  float* g1c  = smalls + 4608;
  float* be1c = smalls + 5632;
  float* b1c  = smalls + 6656;
  float* b2c  = smalls + 10752;
  float* g2c  = smalls + 11776;
  float* be2c = smalls + 12800;

  detect_kernel<<<1, 64, 0, stream>>>((const unsigned int*)x, flag);
  Ptr11 sml;
  sml.p[0] = bq; sml.p[1] = bk; sml.p[2] = bv; sml.p[3] = bo; sml.p[4] = rb;
  sml.p[5] = g1; sml.p[6] = be1; sml.p[7] = b1; sml.p[8] = b2; sml.p[9] = g2; sml.p[10] = be2;
  convert_small<<<1, 256, 0, stream>>>(sml, smalls, flag);
  lut_kernel<<<dim3(128), 256, 0, stream>>>(rbc, lut);

  if (FAST) {
    u16* xc   = (u16*)(ws + 0 * MB);
    u16* WqT  = (u16*)(ws + 8 * MB);
    u16* WkT  = WqT + 1048576;
    u16* WvT  = WqT + 2 * 1048576;
    u16* WoT  = WqT + 3 * 1048576;
    u16* qb   = (u16*)(ws + 16 * MB);
    u16* kb   = (u16*)(ws + 24 * MB);
    u16* vb   = (u16*)(ws + 32 * MB);
    u16* vtb  = (u16*)(ws + 40 * MB);
    u16* attb = (u16*)(ws + 32 * MB);
    u16* xo   = (u16*)(ws + 16 * MB);
    u16* hb   = (u16*)(ws + 48 * MB);
    u16* W1T  = (u16*)(ws + 8 * MB);
    u16* W2T  = (u16*)(ws + 0 * MB);
    u16* ff1  = (u16*)(ws + 16 * MB);
    u16* ff2o = (u16*)(ws + 8 * MB);

    convert_x<<<4096, 256, 0, stream>>>(x, xc, flag);
    TC4 tw; tw.in[0] = Wq; tw.in[1] = Wk; tw.in[2] = Wv; tw.in[3] = Wo;
    tw.out[0] = WqT; tw.out[1] = WkT; tw.out[2] = WvT; tw.out[3] = WoT;
    tconv_w4<<<dim3(16, 16, 4), 256, 0, stream>>>(tw, flag);

    // QKV: 8-phase 256^2 asm-barrier (R8 schedule), 192 blocks
    gemm256<0><<<dim3(4, 16, 3), 512, 0, stream>>>(xc, WqT, bqc, bkc, bvc, qb,
                                                   4096, 1024, 1024, 1024, 1048576L, 4194304L);
    transpose_generic<<<dim3(1, 16, 64), 256, 0, stream>>>(vb, vtb, 1024, 64);
    // attn: R11 Q/P LDS aliasing -> 36.4 KB/block -> 4 blocks/CU
    attn_fused<<<dim3(64, 16), 256, 0, stream>>>(qb, kb, vtb, mask, lut, attb);
    // Wo: double-buffered counted-vmcnt 128^2 (R10-proven)
    gemm_btdb<0><<<dim3(8, 32, 1), 512, 0, stream>>>(attb, WoT, boc, boc, boc, xo,
                                                     4096, 1024, 1024, 0L, 0L);
    tconv_generic<<<dim3(64, 16), 256, 0, stream>>>(W1, W1T, 1024, 4096, flag);
    ln_kernel<0><<<dim3(4096), 256, 0, stream>>>(xo, xc, g1c, be1c, hb, flag);
    tconv_generic<<<dim3(16, 64), 256, 0, stream>>>(W2, W2T, 4096, 1024, flag);
    // FF1: 8-phase 256^2 asm-barrier (R8 schedule), 256 blocks
    gemm256<1><<<dim3(16, 16, 1), 512, 0, stream>>>(hb, W1T, b1c, b1c, b1c, ff1,
                                                    4096, 4096, 1024, 1024, 0L, 0L);
    // FF2: double-buffered counted-vmcnt 128^2 (R10-proven)
    gemm_btdb<0><<<dim3(8, 32, 1), 512, 0, stream>>>(ff1, W2T, b2c, b2c, b2c, ff2o,
                                                     4096, 1024, 4096, 0L, 0L);
    ln_kernel<1><<<dim3(4096), 256, 0, stream>>>(ff2o, hb, g2c, be2c, d_out, flag);
  } else {
    u16* xc   = (u16*)(ws + 0 * MB);
    u16* WqT  = (u16*)(ws + 8 * MB);
    u16* WkT  = WqT + 1048576;
    u16* WvT  = WqT + 2 * 1048576;
    u16* WoT  = WqT + 3 * 1048576;
    u16* qb   = (u16*)(ws + 16 * MB);
    u16* kb   = (u16*)(ws + 24 * MB);
    u16* vb   = (u16*)(ws + 32 * MB);
    u16* vtb  = (u16*)(ws + 40 * MB);
    u16* attb = (u16*)(ws + 32 * MB);
    u16* xo   = (u16*)(ws + 16 * MB);
    u16* hb   = (u16*)(ws + 40 * MB);
    u16* ff1  = (u16*)(ws + 0 * MB);
    u16* ff2o = (u16*)(ws + 32 * MB);

    convert_x<<<4096, 256, 0, stream>>>(x, xc, flag);
    TC4 tw; tw.in[0] = Wq; tw.in[1] = Wk; tw.in[2] = Wv; tw.in[3] = Wo;
    tw.out[0] = WqT; tw.out[1] = WkT; tw.out[2] = WvT; tw.out[3] = WoT;
    tconv_w4<<<dim3(16, 16, 4), 256, 0, stream>>>(tw, flag);

    gemm_bt<0><<<dim3(8, 32, 3), 512, 0, stream>>>(xc, WqT, bqc, bkc, bvc, qb,
                                                   4096, 1024, 1024, 1048576L, 4194304L);
    transpose_generic<<<dim3(1, 16, 64), 256, 0, stream>>>(vb, vtb, 1024, 64);
    attn_fused<<<dim3(64, 16), 256, 0, stream>>>(qb, kb, vtb, mask, lut, attb);
    gemm_bt<0><<<dim3(8, 32, 1), 512, 0, stream>>>(attb, WoT, boc, boc, boc, xo,
                                                   4096, 1024, 1024, 0L, 0L);
    ln_kernel<0><<<dim3(4096), 256, 0, stream>>>(xo, xc, g1c, be1c, hb, flag);
    gemm_bn<1><<<dim3(32, 32), 256, 0, stream>>>(hb, W1, b1c, ff1, 4096, 4096, 1024, flag);
    gemm_bn<0><<<dim3(8, 32), 256, 0, stream>>>(ff1, W2, b2c, ff2o, 4096, 1024, 4096, flag);
    ln_kernel<1><<<dim3(4096), 256, 0, stream>>>(ff2o, hb, g2c, be2c, d_out, flag);
  }
}